// Round 2
// baseline (46827.908 us; speedup 1.0000x reference)
//
#include <hip/hip_runtime.h>
#include <math.h>

#define T_SEQ 365
#define HDIM 256
#define NHEADS 8
#define HD 32
#define BATCH 256
#define DDIM 16
#define FFDIM 1024
#define NST 10000
#define KNB 5
#define SDIM 64

__device__ __forceinline__ float gelu_f(float x) {
    return 0.5f * x * (1.f + erff(x * 0.70710678118654752f));
}

// block-wide (256 threads = 4 waves) sum; sred must be float[4] shared
__device__ __forceinline__ float block_sum256(float v, float* sred) {
    #pragma unroll
    for (int off = 32; off; off >>= 1) v += __shfl_xor(v, off);
    int wave = threadIdx.x >> 6;
    if ((threadIdx.x & 63) == 0) sred[wave] = v;
    __syncthreads();
    float s = sred[0] + sred[1] + sred[2] + sred[3];
    __syncthreads();
    return s;
}

// ---------------- top-K neighbor search ----------------
__global__ __launch_bounds__(256) void topk_kernel(
    const float* __restrict__ lat, const float* __restrict__ lon,
    const float* __restrict__ coords, int* __restrict__ nbr)
{
    __shared__ float hav[NST];
    __shared__ float rv[256];
    __shared__ int   ri[256];
    const float DEG = 0.017453292519943295f;
    int b = blockIdx.x, t = threadIdx.x;
    float lat_o = (lat[b] + 1.f) * 0.5f * 25.f + 24.f;
    float lon_o = (lon[b] + 1.f) * 0.5f * 58.5f - 125.f;
    float qlat = lat_o * DEG, qlon = lon_o * DEG;
    float cq = cosf(qlat);
    for (int i = t; i < NST; i += 256) {
        float slat = coords[2*i], slon = coords[2*i+1];
        float dlat = qlat - slat, dlon = qlon - slon;
        float s1 = sinf(dlat * 0.5f), s2 = sinf(dlon * 0.5f);
        hav[i] = s1*s1 + cq * cosf(slat) * s2*s2;
    }
    __syncthreads();
    for (int sel = 0; sel < KNB + 1; ++sel) {
        float bv = 1e30f; int bi = 0x7fffffff;
        for (int i = t; i < NST; i += 256) {
            float v = hav[i];
            if (v < bv || (v == bv && i < bi)) { bv = v; bi = i; }
        }
        rv[t] = bv; ri[t] = bi;
        __syncthreads();
        for (int s = 128; s > 0; s >>= 1) {
            if (t < s) {
                float ov = rv[t+s]; int oi = ri[t+s];
                if (ov < rv[t] || (ov == rv[t] && oi < ri[t])) { rv[t] = ov; ri[t] = oi; }
            }
            __syncthreads();
        }
        if (t == 0) {
            if (sel > 0) nbr[b*KNB + sel - 1] = ri[0];
            hav[ri[0]] = 1e30f;   // mask winner
        }
        __syncthreads();
    }
}

// ---------------- static-feature branch ----------------
__global__ __launch_bounds__(256) void sfeat_kernel(
    const float* __restrict__ stat, const float* __restrict__ all_st,
    const int* __restrict__ nbr, const float* __restrict__ W,
    const float* __restrict__ bias, const float* __restrict__ g,
    const float* __restrict__ be, float* __restrict__ sfeat)
{
    __shared__ float comb[(KNB+1)*SDIM]; // 384
    __shared__ float sred[4];
    int b = blockIdx.x, t = threadIdx.x;
    for (int i = t; i < (KNB+1)*SDIM; i += 256) {
        if (i < SDIM) comb[i] = stat[b*SDIM + i];
        else {
            int n = (i - SDIM) >> 6, d = (i - SDIM) & 63;
            comb[i] = all_st[(size_t)nbr[b*KNB + n] * SDIM + d];
        }
    }
    __syncthreads();
    float acc = bias[t];
    for (int j = 0; j < (KNB+1)*SDIM; ++j)
        acc = fmaf(comb[j], W[j*HDIM + t], acc);
    float mu  = block_sum256(acc, sred) * (1.f/256.f);
    float d   = acc - mu;
    float var = block_sum256(d*d, sred) * (1.f/256.f);
    float y = g[t] * d * rsqrtf(var + 1e-5f) + be[t];
    sfeat[(size_t)b*HDIM + t] = gelu_f(y);
}

// ---------------- dynamic embedding ----------------
__global__ __launch_bounds__(256) void dyn_kernel(
    const float* __restrict__ dynv, const float* __restrict__ W,
    const float* __restrict__ bias, const float* __restrict__ g,
    const float* __restrict__ be, const float* __restrict__ sfeat,
    float* __restrict__ x)
{
    __shared__ float w[DDIM*HDIM];
    __shared__ float drow[DDIM];
    __shared__ float sred[4];
    int row = blockIdx.x, t = threadIdx.x;
    int b = row / T_SEQ;
    for (int i = t; i < DDIM*HDIM; i += 256) w[i] = W[i];
    if (t < DDIM) drow[t] = dynv[(size_t)row*DDIM + t];
    __syncthreads();
    float acc = bias[t];
    #pragma unroll
    for (int j = 0; j < DDIM; ++j) acc = fmaf(drow[j], w[j*HDIM + t], acc);
    float mu  = block_sum256(acc, sred) * (1.f/256.f);
    float d   = acc - mu;
    float var = block_sum256(d*d, sred) * (1.f/256.f);
    float y = g[t] * d * rsqrtf(var + 1e-5f) + be[t];
    x[(size_t)row*HDIM + t] = gelu_f(y) + sfeat[(size_t)b*HDIM + t];
}

// -------- templated fp32 GEMM: C = A[M,K]@B[K,N] + bias (+relu) (+addsrc) ----
// BN=128, BK=16, 256 threads, BM in {128,64,32,16}; requires M%BM==0, N%128==0,
// K%16==0. If addsrc!=null: C = acc + bias + addsrc (residual add fused).
template<int BM, int TM>
__global__ __launch_bounds__(256) void gemm_t(
    const float* __restrict__ A, const float* __restrict__ B,
    const float* __restrict__ bias, const float* __restrict__ addsrc,
    float* __restrict__ C, int M, int N, int K, int relu)
{
    const int BN = 128, BK = 16;
    __shared__ float As[BK][BM+4];
    __shared__ float Bs[BK][BN+4];
    int t = threadIdx.x;
    int tx = t & 15, ty = t >> 4;
    const float* Ab = A + (size_t)blockIdx.y * BM * K;
    const float* Bb = B + (size_t)blockIdx.x * BN;
    float acc[TM][8];
    #pragma unroll
    for (int i = 0; i < TM; ++i)
        #pragma unroll
        for (int j = 0; j < 8; ++j) acc[i][j] = 0.f;
    const int EPT = BM / 16;        // A elements per thread per k-panel
    const int TPR = 16 / EPT;       // threads per A row
    int arow = t / TPR, koff = (t % TPR) * EPT;
    int brow = t >> 4, bcol = (t & 15) * 8;
    for (int k0 = 0; k0 < K; k0 += BK) {
        const float* ap = Ab + (size_t)arow*K + k0 + koff;
        #pragma unroll
        for (int e = 0; e < EPT; ++e) As[koff+e][arow] = ap[e];
        float4 b0 = *reinterpret_cast<const float4*>(Bb + (size_t)(k0+brow)*N + bcol);
        float4 b1 = *reinterpret_cast<const float4*>(Bb + (size_t)(k0+brow)*N + bcol + 4);
        *reinterpret_cast<float4*>(&Bs[brow][bcol])   = b0;
        *reinterpret_cast<float4*>(&Bs[brow][bcol+4]) = b1;
        __syncthreads();
        #pragma unroll
        for (int k = 0; k < BK; ++k) {
            float a[TM], bb[8];
            #pragma unroll
            for (int i = 0; i < TM; ++i) a[i] = As[k][ty*TM + i];
            #pragma unroll
            for (int j = 0; j < 8; ++j) bb[j] = Bs[k][tx*8 + j];
            #pragma unroll
            for (int i = 0; i < TM; ++i)
                #pragma unroll
                for (int j = 0; j < 8; ++j)
                    acc[i][j] = fmaf(a[i], bb[j], acc[i][j]);
        }
        __syncthreads();
    }
    #pragma unroll
    for (int i = 0; i < TM; ++i) {
        size_t row  = (size_t)blockIdx.y*BM + ty*TM + i;
        size_t col0 = (size_t)blockIdx.x*BN + tx*8;
        float* Cr = C + row*N + col0;
        const float* xr = addsrc ? (addsrc + row*N + col0) : nullptr;
        #pragma unroll
        for (int j = 0; j < 8; ++j) {
            float v = acc[i][j] + bias[col0 + j];
            if (relu) v = fmaxf(v, 0.f);
            if (xr) v += xr[j];
            Cr[j] = v;
        }
    }
}

// ---------------- attention (one block per (local b, h)) ----------------
__global__ __launch_bounds__(256) void attn_kernel(
    const float* __restrict__ qkv, float* __restrict__ aout)
{
    __shared__ float Ks[T_SEQ][HD+1];
    __shared__ float Vs[T_SEQ][HD+1];
    __shared__ float Ps[4][T_SEQ+3];
    int bh = blockIdx.x;
    int b = bh >> 3, h = bh & 7;
    int t = threadIdx.x, wave = t >> 6, lane = t & 63;
    for (int i = t; i < T_SEQ*HD; i += 256) {
        int r = i >> 5, d = i & 31;
        size_t base = ((size_t)(b*T_SEQ + r))*768 + h*HD + d;
        Ks[r][d] = qkv[base + 256];
        Vs[r][d] = qkv[base + 512];
    }
    __syncthreads();
    const float scale = 0.17677669529663687f; // 1/sqrt(32)
    for (int it = 0; it < 92; ++it) {
        int qrow = wave + it*4;
        bool active = qrow < T_SEQ;
        float sc[6];
        #pragma unroll
        for (int s = 0; s < 6; ++s) sc[s] = 0.f;
        if (active) {
            float qv = (lane < HD) ? qkv[((size_t)(b*T_SEQ + qrow))*768 + h*HD + lane] : 0.f;
            #pragma unroll
            for (int d = 0; d < HD; ++d) {
                float qd = __shfl(qv, d);
                #pragma unroll
                for (int s = 0; s < 6; ++s) {
                    int j = lane + (s << 6);
                    if (j < T_SEQ) sc[s] = fmaf(qd, Ks[j][d], sc[s]);
                }
            }
            float mx = -1e30f;
            #pragma unroll
            for (int s = 0; s < 6; ++s) {
                int j = lane + (s << 6);
                if (j < T_SEQ) { sc[s] *= scale; mx = fmaxf(mx, sc[s]); }
            }
            #pragma unroll
            for (int off = 32; off; off >>= 1) mx = fmaxf(mx, __shfl_xor(mx, off));
            float sum = 0.f;
            #pragma unroll
            for (int s = 0; s < 6; ++s) {
                int j = lane + (s << 6);
                if (j < T_SEQ) { sc[s] = expf(sc[s] - mx); sum += sc[s]; }
            }
            #pragma unroll
            for (int off = 32; off; off >>= 1) sum += __shfl_xor(sum, off);
            float inv = 1.f / sum;
            #pragma unroll
            for (int s = 0; s < 6; ++s) {
                int j = lane + (s << 6);
                if (j < T_SEQ) Ps[wave][j] = sc[s] * inv;
            }
        }
        __syncthreads();
        if (active) {
            int d = lane & 31, half = lane >> 5;
            int j0 = half ? 183 : 0, j1 = half ? T_SEQ : 183;
            float o = 0.f;
            for (int j = j0; j < j1; ++j) o = fmaf(Ps[wave][j], Vs[j][d], o);
            o += __shfl_xor(o, 32);
            if (half == 0)
                aout[((size_t)(b*T_SEQ + qrow))*HDIM + h*HD + d] = o;
        }
        __syncthreads();
    }
}

// ---------------- LN in place on x rows ----------------
__global__ __launch_bounds__(256) void ln_kernel(
    float* __restrict__ x, const float* __restrict__ g, const float* __restrict__ be)
{
    __shared__ float sred[4];
    size_t row = blockIdx.x;
    int t = threadIdx.x;
    float v = x[row*HDIM + t];
    float mu  = block_sum256(v, sred) * (1.f/256.f);
    float d   = v - mu;
    float var = block_sum256(d*d, sred) * (1.f/256.f);
    x[row*HDIM + t] = g[t] * d * rsqrtf(var + 1e-5f) + be[t];
}

// ---------------- mean-pool + output head ----------------
__global__ __launch_bounds__(256) void head_kernel(
    const float* __restrict__ x, const float* __restrict__ sfeat,
    const float* __restrict__ W1, const float* __restrict__ b1,
    const float* __restrict__ W2, const float* __restrict__ b2,
    const float* __restrict__ scale, const float* __restrict__ shift,
    float* __restrict__ out)
{
    __shared__ float p[HDIM];
    __shared__ float h1[HDIM/2];
    int b = blockIdx.x, t = threadIdx.x;
    float acc = 0.f;
    for (int tt = 0; tt < T_SEQ; ++tt)
        acc += x[((size_t)b*T_SEQ + tt)*HDIM + t];
    p[t] = acc * (1.f/365.f) + sfeat[(size_t)b*HDIM + t];
    __syncthreads();
    if (t < HDIM/2) {
        float a = b1[t];
        for (int c = 0; c < HDIM; ++c) a = fmaf(p[c], W1[c*(HDIM/2) + t], a);
        h1[t] = gelu_f(a);
    }
    __syncthreads();
    if (t < 30) {
        float a = b2[t];
        for (int j = 0; j < HDIM/2; ++j) a = fmaf(h1[j], W2[j*30 + t], a);
        out[b*30 + t] = tanhf(a) * scale[0] + shift[0];
    }
}

extern "C" void kernel_launch(void* const* d_in, const int* in_sizes, int n_in,
                              void* d_out, int out_size, void* d_ws, size_t ws_size,
                              hipStream_t stream) {
    const float* p_static = (const float*)d_in[0];
    const float* p_dyn    = (const float*)d_in[1];
    const float* p_lat    = (const float*)d_in[2];
    const float* p_lon    = (const float*)d_in[3];
    const float* p_all    = (const float*)d_in[4];
    const float* p_coords = (const float*)d_in[5];
    const float* p_Wst    = (const float*)d_in[6];
    const float* p_bst    = (const float*)d_in[7];
    const float* p_gst    = (const float*)d_in[8];
    const float* p_best   = (const float*)d_in[9];
    const float* p_Wdy    = (const float*)d_in[10];
    const float* p_bdy    = (const float*)d_in[11];
    const float* p_gdy    = (const float*)d_in[12];
    const float* p_bedy   = (const float*)d_in[13];
    const float* p_Wqkv   = (const float*)d_in[14];
    const float* p_bqkv   = (const float*)d_in[15];
    const float* p_Wo     = (const float*)d_in[16];
    const float* p_bo     = (const float*)d_in[17];
    const float* p_gln1   = (const float*)d_in[18];
    const float* p_beln1  = (const float*)d_in[19];
    const float* p_Wf1    = (const float*)d_in[20];
    const float* p_bf1    = (const float*)d_in[21];
    const float* p_Wf2    = (const float*)d_in[22];
    const float* p_bf2    = (const float*)d_in[23];
    const float* p_gln2   = (const float*)d_in[24];
    const float* p_beln2  = (const float*)d_in[25];
    const float* p_Wo1    = (const float*)d_in[26];
    const float* p_bo1    = (const float*)d_in[27];
    const float* p_Wo2    = (const float*)d_in[28];
    const float* p_bo2    = (const float*)d_in[29];
    const float* p_scale  = (const float*)d_in[30];
    const float* p_shift  = (const float*)d_in[31];
    float* out = (float*)d_out;
    (void)in_sizes; (void)n_in; (void)out_size;

    char* ws = (char*)d_ws;
    size_t off = 0;
    auto alloc = [&](size_t bytes) -> void* {
        void* p = ws + off;
        off += (bytes + 255) & ~(size_t)255;
        return p;
    };
    const int ROWS = BATCH * T_SEQ; // 93440
    int*   nbr   = (int*)  alloc((size_t)BATCH*KNB*sizeof(int));
    float* sfeat = (float*)alloc((size_t)BATCH*HDIM*sizeof(float));
    float* x     = (float*)alloc((size_t)ROWS*HDIM*sizeof(float));
    size_t fixed = off;

    // big buffer per chunk of CH batch elems: qkv (CH*365*768) then attn-out
    // (CH*365*256) = CH*365*1024 floats total; FF hidden (CH*365*1024) reuses
    // the same region (disjoint live ranges).
    const size_t PER_B = (size_t)T_SEQ * 1024 * sizeof(float); // 1,495,040 B
    int CH = 16;
    if      (fixed + 256*PER_B + 4096 <= ws_size) CH = 256;
    else if (fixed + 128*PER_B + 4096 <= ws_size) CH = 128;
    else if (fixed +  64*PER_B + 4096 <= ws_size) CH = 64;
    else if (fixed +  32*PER_B + 4096 <= ws_size) CH = 32;
    float* big = (float*)alloc((size_t)CH * PER_B);
    const int RW = CH * T_SEQ;
    const int BM = (CH >= 128) ? 128 : CH;  // RW % BM == 0 for all tiers
    float* qkv  = big;
    float* aatt = big + (size_t)RW * 768;
    float* hbuf = big;

    auto GEMM = [&](const float* A, const float* B, const float* bias,
                    const float* add, float* C, int M, int N, int K, int relu) {
        dim3 grid(N/128, M/BM);
        if (BM == 128)
            gemm_t<128,8><<<grid,256,0,stream>>>(A,B,bias,add,C,M,N,K,relu);
        else if (BM == 64)
            gemm_t<64,4><<<grid,256,0,stream>>>(A,B,bias,add,C,M,N,K,relu);
        else if (BM == 32)
            gemm_t<32,2><<<grid,256,0,stream>>>(A,B,bias,add,C,M,N,K,relu);
        else
            gemm_t<16,1><<<grid,256,0,stream>>>(A,B,bias,add,C,M,N,K,relu);
    };

    topk_kernel <<<BATCH, 256, 0, stream>>>(p_lat, p_lon, p_coords, nbr);
    sfeat_kernel<<<BATCH, 256, 0, stream>>>(p_static, p_all, nbr, p_Wst, p_bst, p_gst, p_best, sfeat);
    dyn_kernel  <<<ROWS, 256, 0, stream>>>(p_dyn, p_Wdy, p_bdy, p_gdy, p_bedy, sfeat, x);

    const int NCHUNK = BATCH / CH;
    for (int c = 0; c < NCHUNK; ++c) {
        float* xc = x + (size_t)c * CH * T_SEQ * HDIM;
        for (int l = 0; l < 4; ++l) {
            GEMM(xc, p_Wqkv + (size_t)l*HDIM*3*HDIM, p_bqkv + l*3*HDIM,
                 nullptr, qkv, RW, 3*HDIM, HDIM, 0);
            attn_kernel<<<CH*NHEADS, 256, 0, stream>>>(qkv, aatt);
            GEMM(aatt, p_Wo + (size_t)l*HDIM*HDIM, p_bo + l*HDIM,
                 xc, xc, RW, HDIM, HDIM, 0);
            ln_kernel<<<RW, 256, 0, stream>>>(xc, p_gln1 + l*HDIM, p_beln1 + l*HDIM);
            GEMM(xc, p_Wf1 + (size_t)l*HDIM*FFDIM, p_bf1 + l*FFDIM,
                 nullptr, hbuf, RW, FFDIM, HDIM, 1);
            GEMM(hbuf, p_Wf2 + (size_t)l*FFDIM*HDIM, p_bf2 + l*HDIM,
                 xc, xc, RW, HDIM, FFDIM, 0);
            ln_kernel<<<RW, 256, 0, stream>>>(xc, p_gln2 + l*HDIM, p_beln2 + l*HDIM);
        }
    }
    head_kernel<<<BATCH, 256, 0, stream>>>(x, sfeat, p_Wo1, p_bo1, p_Wo2, p_bo2, p_scale, p_shift, out);
}

// Round 3
// 14208.325 us; speedup vs baseline: 3.2958x; 3.2958x over previous
//
#include <hip/hip_runtime.h>
#include <math.h>

#define T_SEQ 365
#define HDIM 256
#define NHEADS 8
#define HD 32
#define BATCH 256
#define DDIM 16
#define FFDIM 1024
#define NST 10000
#define KNB 5
#define SDIM 64

__device__ __forceinline__ float gelu_f(float x) {
    return 0.5f * x * (1.f + erff(x * 0.70710678118654752f));
}

// block-wide (256 threads = 4 waves) sum; sred must be float[4] shared
__device__ __forceinline__ float block_sum256(float v, float* sred) {
    #pragma unroll
    for (int off = 32; off; off >>= 1) v += __shfl_xor(v, off);
    int wave = threadIdx.x >> 6;
    if ((threadIdx.x & 63) == 0) sred[wave] = v;
    __syncthreads();
    float s = sred[0] + sred[1] + sred[2] + sred[3];
    __syncthreads();
    return s;
}

// ---------------- top-K neighbor search ----------------
__global__ __launch_bounds__(256) void topk_kernel(
    const float* __restrict__ lat, const float* __restrict__ lon,
    const float* __restrict__ coords, int* __restrict__ nbr)
{
    __shared__ float hav[NST];
    __shared__ float rv[256];
    __shared__ int   ri[256];
    const float DEG = 0.017453292519943295f;
    int b = blockIdx.x, t = threadIdx.x;
    float lat_o = (lat[b] + 1.f) * 0.5f * 25.f + 24.f;
    float lon_o = (lon[b] + 1.f) * 0.5f * 58.5f - 125.f;
    float qlat = lat_o * DEG, qlon = lon_o * DEG;
    float cq = cosf(qlat);
    for (int i = t; i < NST; i += 256) {
        float slat = coords[2*i], slon = coords[2*i+1];
        float dlat = qlat - slat, dlon = qlon - slon;
        float s1 = sinf(dlat * 0.5f), s2 = sinf(dlon * 0.5f);
        hav[i] = s1*s1 + cq * cosf(slat) * s2*s2;
    }
    __syncthreads();
    for (int sel = 0; sel < KNB + 1; ++sel) {
        float bv = 1e30f; int bi = 0x7fffffff;
        for (int i = t; i < NST; i += 256) {
            float v = hav[i];
            if (v < bv || (v == bv && i < bi)) { bv = v; bi = i; }
        }
        rv[t] = bv; ri[t] = bi;
        __syncthreads();
        for (int s = 128; s > 0; s >>= 1) {
            if (t < s) {
                float ov = rv[t+s]; int oi = ri[t+s];
                if (ov < rv[t] || (ov == rv[t] && oi < ri[t])) { rv[t] = ov; ri[t] = oi; }
            }
            __syncthreads();
        }
        if (t == 0) {
            if (sel > 0) nbr[b*KNB + sel - 1] = ri[0];
            hav[ri[0]] = 1e30f;   // mask winner
        }
        __syncthreads();
    }
}

// ---------------- static-feature branch ----------------
__global__ __launch_bounds__(256) void sfeat_kernel(
    const float* __restrict__ stat, const float* __restrict__ all_st,
    const int* __restrict__ nbr, const float* __restrict__ W,
    const float* __restrict__ bias, const float* __restrict__ g,
    const float* __restrict__ be, float* __restrict__ sfeat)
{
    __shared__ float comb[(KNB+1)*SDIM]; // 384
    __shared__ float sred[4];
    int b = blockIdx.x, t = threadIdx.x;
    for (int i = t; i < (KNB+1)*SDIM; i += 256) {
        if (i < SDIM) comb[i] = stat[b*SDIM + i];
        else {
            int n = (i - SDIM) >> 6, d = (i - SDIM) & 63;
            comb[i] = all_st[(size_t)nbr[b*KNB + n] * SDIM + d];
        }
    }
    __syncthreads();
    float acc = bias[t];
    for (int j = 0; j < (KNB+1)*SDIM; ++j)
        acc = fmaf(comb[j], W[j*HDIM + t], acc);
    float mu  = block_sum256(acc, sred) * (1.f/256.f);
    float d   = acc - mu;
    float var = block_sum256(d*d, sred) * (1.f/256.f);
    float y = g[t] * d * rsqrtf(var + 1e-5f) + be[t];
    sfeat[(size_t)b*HDIM + t] = gelu_f(y);
}

// ---------------- dynamic embedding ----------------
__global__ __launch_bounds__(256) void dyn_kernel(
    const float* __restrict__ dynv, const float* __restrict__ W,
    const float* __restrict__ bias, const float* __restrict__ g,
    const float* __restrict__ be, const float* __restrict__ sfeat,
    float* __restrict__ x)
{
    __shared__ float w[DDIM*HDIM];
    __shared__ float drow[DDIM];
    __shared__ float sred[4];
    int row = blockIdx.x, t = threadIdx.x;
    int b = row / T_SEQ;
    for (int i = t; i < DDIM*HDIM; i += 256) w[i] = W[i];
    if (t < DDIM) drow[t] = dynv[(size_t)row*DDIM + t];
    __syncthreads();
    float acc = bias[t];
    #pragma unroll
    for (int j = 0; j < DDIM; ++j) acc = fmaf(drow[j], w[j*HDIM + t], acc);
    float mu  = block_sum256(acc, sred) * (1.f/256.f);
    float d   = acc - mu;
    float var = block_sum256(d*d, sred) * (1.f/256.f);
    float y = g[t] * d * rsqrtf(var + 1e-5f) + be[t];
    x[(size_t)row*HDIM + t] = gelu_f(y) + sfeat[(size_t)b*HDIM + t];
}

// -------- templated fp32 GEMM: C = A[M,K]@B[K,N] + bias (+relu) (+addsrc) ----
template<int BM, int TM>
__global__ __launch_bounds__(256) void gemm_t(
    const float* __restrict__ A, const float* __restrict__ B,
    const float* __restrict__ bias, const float* __restrict__ addsrc,
    float* __restrict__ C, int M, int N, int K, int relu)
{
    const int BN = 128, BK = 16;
    __shared__ float As[BK][BM+4];
    __shared__ float Bs[BK][BN+4];
    int t = threadIdx.x;
    int tx = t & 15, ty = t >> 4;
    const float* Ab = A + (size_t)blockIdx.y * BM * K;
    const float* Bb = B + (size_t)blockIdx.x * BN;
    float acc[TM][8];
    #pragma unroll
    for (int i = 0; i < TM; ++i)
        #pragma unroll
        for (int j = 0; j < 8; ++j) acc[i][j] = 0.f;
    const int EPT = BM / 16;        // A elements per thread per k-panel
    const int TPR = 16 / EPT;       // threads per A row
    int arow = t / TPR, koff = (t % TPR) * EPT;
    int brow = t >> 4, bcol = (t & 15) * 8;
    for (int k0 = 0; k0 < K; k0 += BK) {
        const float* ap = Ab + (size_t)arow*K + k0 + koff;
        #pragma unroll
        for (int e = 0; e < EPT; ++e) As[koff+e][arow] = ap[e];
        float4 b0 = *reinterpret_cast<const float4*>(Bb + (size_t)(k0+brow)*N + bcol);
        float4 b1 = *reinterpret_cast<const float4*>(Bb + (size_t)(k0+brow)*N + bcol + 4);
        *reinterpret_cast<float4*>(&Bs[brow][bcol])   = b0;
        *reinterpret_cast<float4*>(&Bs[brow][bcol+4]) = b1;
        __syncthreads();
        #pragma unroll
        for (int k = 0; k < BK; ++k) {
            float a[TM], bb[8];
            #pragma unroll
            for (int i = 0; i < TM; ++i) a[i] = As[k][ty*TM + i];
            #pragma unroll
            for (int j = 0; j < 8; ++j) bb[j] = Bs[k][tx*8 + j];
            #pragma unroll
            for (int i = 0; i < TM; ++i)
                #pragma unroll
                for (int j = 0; j < 8; ++j)
                    acc[i][j] = fmaf(a[i], bb[j], acc[i][j]);
        }
        __syncthreads();
    }
    #pragma unroll
    for (int i = 0; i < TM; ++i) {
        size_t row  = (size_t)blockIdx.y*BM + ty*TM + i;
        size_t col0 = (size_t)blockIdx.x*BN + tx*8;
        float* Cr = C + row*N + col0;
        const float* xr = addsrc ? (addsrc + row*N + col0) : nullptr;
        #pragma unroll
        for (int j = 0; j < 8; ++j) {
            float v = acc[i][j] + bias[col0 + j];
            if (relu) v = fmaxf(v, 0.f);
            if (xr) v += xr[j];
            Cr[j] = v;
        }
    }
}

// ---------------- attention (one block per (local b, h)) ----------------
// Register-blocked fp32: 4 independent waves, one barrier total.
// LDS: K[368][36] + V[368][36] + Q-stage[4][8][36] = 112.9 KB.
__global__ __launch_bounds__(256) void attn_kernel(
    const float* __restrict__ qkv, float* __restrict__ aout)
{
    __shared__ float Klds[368][36];
    __shared__ float Vlds[368][36];
    __shared__ float Qlds[4][8][36];
    int bh = blockIdx.x;
    int b = bh >> 3, h = bh & 7;
    int t = threadIdx.x;
    int wave = t >> 6, lane = t & 63;

    // stage K,V once (rows >=365 zeroed)
    for (int i = t; i < 368*8; i += 256) {
        int r = i >> 3, d0 = (i & 7) * 4;
        float4 kv, vv;
        if (r < T_SEQ) {
            size_t base = ((size_t)(b*T_SEQ + r))*768 + h*HD + d0;
            kv = *reinterpret_cast<const float4*>(&qkv[base + 256]);
            vv = *reinterpret_cast<const float4*>(&qkv[base + 512]);
        } else {
            kv = make_float4(0.f,0.f,0.f,0.f); vv = kv;
        }
        *reinterpret_cast<float4*>(&Klds[r][d0]) = kv;
        *reinterpret_cast<float4*>(&Vlds[r][d0]) = vv;
    }
    __syncthreads();   // only barrier; waves independent below

    const float scale = 0.17677669529663687f; // 1/sqrt(32)
    int rq = lane >> 3;         // 0..7: q-row in stage / j-phase in PV
    int a4 = (lane & 7) * 4;    // d-quad base
    int jj[6];
    #pragma unroll
    for (int c = 0; c < 6; ++c) jj[c] = min(c*64 + lane, 367);

    for (int st = wave; st < 46; st += 4) {
        int row0 = st * 8;
        // stage this wave's 8-row Q tile (clamped rows; stores guarded later)
        {
            int qr = min(row0 + rq, T_SEQ - 1);
            float4 qv = *reinterpret_cast<const float4*>(
                &qkv[((size_t)(b*T_SEQ + qr))*768 + h*HD + a4]);
            *reinterpret_cast<float4*>(&Qlds[wave][rq][a4]) = qv;
        }
        // ---- scores: s[r][c] = S[row0+r][c*64+lane] ----
        float s[8][6];
        #pragma unroll
        for (int r = 0; r < 8; ++r)
            #pragma unroll
            for (int c = 0; c < 6; ++c) s[r][c] = 0.f;
        #pragma unroll
        for (int dq = 0; dq < 8; ++dq) {
            float4 q[8];
            #pragma unroll
            for (int r = 0; r < 8; ++r)
                q[r] = *reinterpret_cast<const float4*>(&Qlds[wave][r][dq*4]);
            #pragma unroll
            for (int c = 0; c < 6; ++c) {
                float4 k = *reinterpret_cast<const float4*>(&Klds[jj[c]][dq*4]);
                #pragma unroll
                for (int r = 0; r < 8; ++r) {
                    s[r][c] = fmaf(q[r].x, k.x, s[r][c]);
                    s[r][c] = fmaf(q[r].y, k.y, s[r][c]);
                    s[r][c] = fmaf(q[r].z, k.z, s[r][c]);
                    s[r][c] = fmaf(q[r].w, k.w, s[r][c]);
                }
            }
        }
        // ---- softmax per row (in-register, shfl_xor reductions) ----
        #pragma unroll
        for (int r = 0; r < 8; ++r) {
            if (lane >= 45) s[r][5] = -3e38f;   // mask k-tail (j>=365)
            float mx = s[r][0];
            #pragma unroll
            for (int c = 1; c < 6; ++c) mx = fmaxf(mx, s[r][c]);
            #pragma unroll
            for (int off = 32; off; off >>= 1) mx = fmaxf(mx, __shfl_xor(mx, off));
            float sum = 0.f;
            #pragma unroll
            for (int c = 0; c < 6; ++c) {
                float e = __expf((s[r][c] - mx) * scale);
                s[r][c] = e; sum += e;
            }
            #pragma unroll
            for (int off = 32; off; off >>= 1) sum += __shfl_xor(sum, off);
            float inv = 1.f / sum;
            #pragma unroll
            for (int c = 0; c < 6; ++c) s[r][c] *= inv;
        }
        // ---- PV: lane (jp=rq, d-quad=a4); P via bpermute, V via b128 ----
        float acc[8][4];
        #pragma unroll
        for (int r = 0; r < 8; ++r)
            #pragma unroll
            for (int i = 0; i < 4; ++i) acc[r][i] = 0.f;
        #pragma unroll
        for (int k = 0; k < 46; ++k) {
            int j = rq + k*8;                 // <= 367
            float4 v = *reinterpret_cast<const float4*>(&Vlds[j][a4]);
            int srcl = j & 63;
            const int c = k >> 3;             // compile-time after unroll
            #pragma unroll
            for (int r = 0; r < 8; ++r) {
                float pv = __shfl(s[r][c], srcl);
                acc[r][0] = fmaf(pv, v.x, acc[r][0]);
                acc[r][1] = fmaf(pv, v.y, acc[r][1]);
                acc[r][2] = fmaf(pv, v.z, acc[r][2]);
                acc[r][3] = fmaf(pv, v.w, acc[r][3]);
            }
        }
        // reduce over j-phases (lanes sharing lane&7)
        #pragma unroll
        for (int r = 0; r < 8; ++r)
            #pragma unroll
            for (int i = 0; i < 4; ++i) {
                acc[r][i] += __shfl_xor(acc[r][i], 8);
                acc[r][i] += __shfl_xor(acc[r][i], 16);
                acc[r][i] += __shfl_xor(acc[r][i], 32);
            }
        if (rq == 0) {
            #pragma unroll
            for (int r = 0; r < 8; ++r) {
                int row = row0 + r;
                if (row < T_SEQ) {
                    float4 o = make_float4(acc[r][0], acc[r][1], acc[r][2], acc[r][3]);
                    *reinterpret_cast<float4*>(
                        &aout[((size_t)(b*T_SEQ + row))*HDIM + h*HD + a4]) = o;
                }
            }
        }
    }
}

// ---------------- LN in place on x rows ----------------
__global__ __launch_bounds__(256) void ln_kernel(
    float* __restrict__ x, const float* __restrict__ g, const float* __restrict__ be)
{
    __shared__ float sred[4];
    size_t row = blockIdx.x;
    int t = threadIdx.x;
    float v = x[row*HDIM + t];
    float mu  = block_sum256(v, sred) * (1.f/256.f);
    float d   = v - mu;
    float var = block_sum256(d*d, sred) * (1.f/256.f);
    x[row*HDIM + t] = g[t] * d * rsqrtf(var + 1e-5f) + be[t];
}

// ---------------- mean-pool + output head ----------------
__global__ __launch_bounds__(256) void head_kernel(
    const float* __restrict__ x, const float* __restrict__ sfeat,
    const float* __restrict__ W1, const float* __restrict__ b1,
    const float* __restrict__ W2, const float* __restrict__ b2,
    const float* __restrict__ scale, const float* __restrict__ shift,
    float* __restrict__ out)
{
    __shared__ float p[HDIM];
    __shared__ float h1[HDIM/2];
    int b = blockIdx.x, t = threadIdx.x;
    float acc = 0.f;
    for (int tt = 0; tt < T_SEQ; ++tt)
        acc += x[((size_t)b*T_SEQ + tt)*HDIM + t];
    p[t] = acc * (1.f/365.f) + sfeat[(size_t)b*HDIM + t];
    __syncthreads();
    if (t < HDIM/2) {
        float a = b1[t];
        for (int c = 0; c < HDIM; ++c) a = fmaf(p[c], W1[c*(HDIM/2) + t], a);
        h1[t] = gelu_f(a);
    }
    __syncthreads();
    if (t < 30) {
        float a = b2[t];
        for (int j = 0; j < HDIM/2; ++j) a = fmaf(h1[j], W2[j*30 + t], a);
        out[b*30 + t] = tanhf(a) * scale[0] + shift[0];
    }
}

extern "C" void kernel_launch(void* const* d_in, const int* in_sizes, int n_in,
                              void* d_out, int out_size, void* d_ws, size_t ws_size,
                              hipStream_t stream) {
    const float* p_static = (const float*)d_in[0];
    const float* p_dyn    = (const float*)d_in[1];
    const float* p_lat    = (const float*)d_in[2];
    const float* p_lon    = (const float*)d_in[3];
    const float* p_all    = (const float*)d_in[4];
    const float* p_coords = (const float*)d_in[5];
    const float* p_Wst    = (const float*)d_in[6];
    const float* p_bst    = (const float*)d_in[7];
    const float* p_gst    = (const float*)d_in[8];
    const float* p_best   = (const float*)d_in[9];
    const float* p_Wdy    = (const float*)d_in[10];
    const float* p_bdy    = (const float*)d_in[11];
    const float* p_gdy    = (const float*)d_in[12];
    const float* p_bedy   = (const float*)d_in[13];
    const float* p_Wqkv   = (const float*)d_in[14];
    const float* p_bqkv   = (const float*)d_in[15];
    const float* p_Wo     = (const float*)d_in[16];
    const float* p_bo     = (const float*)d_in[17];
    const float* p_gln1   = (const float*)d_in[18];
    const float* p_beln1  = (const float*)d_in[19];
    const float* p_Wf1    = (const float*)d_in[20];
    const float* p_bf1    = (const float*)d_in[21];
    const float* p_Wf2    = (const float*)d_in[22];
    const float* p_bf2    = (const float*)d_in[23];
    const float* p_gln2   = (const float*)d_in[24];
    const float* p_beln2  = (const float*)d_in[25];
    const float* p_Wo1    = (const float*)d_in[26];
    const float* p_bo1    = (const float*)d_in[27];
    const float* p_Wo2    = (const float*)d_in[28];
    const float* p_bo2    = (const float*)d_in[29];
    const float* p_scale  = (const float*)d_in[30];
    const float* p_shift  = (const float*)d_in[31];
    float* out = (float*)d_out;
    (void)in_sizes; (void)n_in; (void)out_size;

    char* ws = (char*)d_ws;
    size_t off = 0;
    auto alloc = [&](size_t bytes) -> void* {
        void* p = ws + off;
        off += (bytes + 255) & ~(size_t)255;
        return p;
    };
    const int ROWS = BATCH * T_SEQ; // 93440
    int*   nbr   = (int*)  alloc((size_t)BATCH*KNB*sizeof(int));
    float* sfeat = (float*)alloc((size_t)BATCH*HDIM*sizeof(float));
    float* x     = (float*)alloc((size_t)ROWS*HDIM*sizeof(float));
    size_t fixed = off;

    const size_t PER_B = (size_t)T_SEQ * 1024 * sizeof(float); // 1,495,040 B
    int CH = 16;
    if      (fixed + 256*PER_B + 4096 <= ws_size) CH = 256;
    else if (fixed + 128*PER_B + 4096 <= ws_size) CH = 128;
    else if (fixed +  64*PER_B + 4096 <= ws_size) CH = 64;
    else if (fixed +  32*PER_B + 4096 <= ws_size) CH = 32;
    float* big = (float*)alloc((size_t)CH * PER_B);
    const int RW = CH * T_SEQ;
    const int BM = (CH >= 128) ? 128 : CH;
    float* qkv  = big;
    float* aatt = big + (size_t)RW * 768;
    float* hbuf = big;

    auto GEMM = [&](const float* A, const float* B, const float* bias,
                    const float* add, float* C, int M, int N, int K, int relu) {
        dim3 grid(N/128, M/BM);
        if (BM == 128)
            gemm_t<128,8><<<grid,256,0,stream>>>(A,B,bias,add,C,M,N,K,relu);
        else if (BM == 64)
            gemm_t<64,4><<<grid,256,0,stream>>>(A,B,bias,add,C,M,N,K,relu);
        else if (BM == 32)
            gemm_t<32,2><<<grid,256,0,stream>>>(A,B,bias,add,C,M,N,K,relu);
        else
            gemm_t<16,1><<<grid,256,0,stream>>>(A,B,bias,add,C,M,N,K,relu);
    };

    topk_kernel <<<BATCH, 256, 0, stream>>>(p_lat, p_lon, p_coords, nbr);
    sfeat_kernel<<<BATCH, 256, 0, stream>>>(p_static, p_all, nbr, p_Wst, p_bst, p_gst, p_best, sfeat);
    dyn_kernel  <<<ROWS, 256, 0, stream>>>(p_dyn, p_Wdy, p_bdy, p_gdy, p_bedy, sfeat, x);

    const int NCHUNK = BATCH / CH;
    for (int c = 0; c < NCHUNK; ++c) {
        float* xc = x + (size_t)c * CH * T_SEQ * HDIM;
        for (int l = 0; l < 4; ++l) {
            GEMM(xc, p_Wqkv + (size_t)l*HDIM*3*HDIM, p_bqkv + l*3*HDIM,
                 nullptr, qkv, RW, 3*HDIM, HDIM, 0);
            attn_kernel<<<CH*NHEADS, 256, 0, stream>>>(qkv, aatt);
            GEMM(aatt, p_Wo + (size_t)l*HDIM*HDIM, p_bo + l*HDIM,
                 xc, xc, RW, HDIM, HDIM, 0);
            ln_kernel<<<RW, 256, 0, stream>>>(xc, p_gln1 + l*HDIM, p_beln1 + l*HDIM);
            GEMM(xc, p_Wf1 + (size_t)l*HDIM*FFDIM, p_bf1 + l*FFDIM,
                 nullptr, hbuf, RW, FFDIM, HDIM, 1);
            GEMM(hbuf, p_Wf2 + (size_t)l*FFDIM*HDIM, p_bf2 + l*HDIM,
                 xc, xc, RW, HDIM, FFDIM, 0);
            ln_kernel<<<RW, 256, 0, stream>>>(xc, p_gln2 + l*HDIM, p_beln2 + l*HDIM);
        }
    }
    head_kernel<<<BATCH, 256, 0, stream>>>(x, sfeat, p_Wo1, p_bo1, p_Wo2, p_bo2, p_scale, p_shift, out);
}

// Round 5
// 12320.853 us; speedup vs baseline: 3.8007x; 1.1532x over previous
//
#include <hip/hip_runtime.h>
#include <math.h>

#define T_SEQ 365
#define HDIM 256
#define NHEADS 8
#define HD 32
#define BATCH 256
#define DDIM 16
#define FFDIM 1024
#define NST 10000
#define KNB 5
#define SDIM 64

typedef __bf16 bf16x8 __attribute__((ext_vector_type(8)));
typedef float  f32x16 __attribute__((ext_vector_type(16)));

__device__ __forceinline__ ushort f2b_hi(float v) {
    unsigned u = __float_as_uint(v);
    unsigned r = u + 0x7fffu + ((u >> 16) & 1u);
    return (ushort)(r >> 16);
}
__device__ __forceinline__ float b2f(ushort h) {
    return __uint_as_float(((unsigned)h) << 16);
}
__device__ __forceinline__ ushort f2b_lo(float v, ushort hi) {
    return f2b_hi(v - b2f(hi));
}

__device__ __forceinline__ float gelu_f(float x) {
    return 0.5f * x * (1.f + erff(x * 0.70710678118654752f));
}

// block-wide (256 threads = 4 waves) sum; sred must be float[4] shared
__device__ __forceinline__ float block_sum256(float v, float* sred) {
    #pragma unroll
    for (int off = 32; off; off >>= 1) v += __shfl_xor(v, off);
    int wave = threadIdx.x >> 6;
    if ((threadIdx.x & 63) == 0) sred[wave] = v;
    __syncthreads();
    float s = sred[0] + sred[1] + sred[2] + sred[3];
    __syncthreads();
    return s;
}

// ---------------- top-K neighbor search ----------------
__global__ __launch_bounds__(256) void topk_kernel(
    const float* __restrict__ lat, const float* __restrict__ lon,
    const float* __restrict__ coords, int* __restrict__ nbr)
{
    __shared__ float hav[NST];
    __shared__ float rv[256];
    __shared__ int   ri[256];
    const float DEG = 0.017453292519943295f;
    int b = blockIdx.x, t = threadIdx.x;
    float lat_o = (lat[b] + 1.f) * 0.5f * 25.f + 24.f;
    float lon_o = (lon[b] + 1.f) * 0.5f * 58.5f - 125.f;
    float qlat = lat_o * DEG, qlon = lon_o * DEG;
    float cq = cosf(qlat);
    for (int i = t; i < NST; i += 256) {
        float slat = coords[2*i], slon = coords[2*i+1];
        float dlat = qlat - slat, dlon = qlon - slon;
        float s1 = sinf(dlat * 0.5f), s2 = sinf(dlon * 0.5f);
        hav[i] = s1*s1 + cq * cosf(slat) * s2*s2;
    }
    __syncthreads();
    for (int sel = 0; sel < KNB + 1; ++sel) {
        float bv = 1e30f; int bi = 0x7fffffff;
        for (int i = t; i < NST; i += 256) {
            float v = hav[i];
            if (v < bv || (v == bv && i < bi)) { bv = v; bi = i; }
        }
        rv[t] = bv; ri[t] = bi;
        __syncthreads();
        for (int s = 128; s > 0; s >>= 1) {
            if (t < s) {
                float ov = rv[t+s]; int oi = ri[t+s];
                if (ov < rv[t] || (ov == rv[t] && oi < ri[t])) { rv[t] = ov; ri[t] = oi; }
            }
            __syncthreads();
        }
        if (t == 0) {
            if (sel > 0) nbr[b*KNB + sel - 1] = ri[0];
            hav[ri[0]] = 1e30f;   // mask winner
        }
        __syncthreads();
    }
}

// ---------------- static-feature branch ----------------
__global__ __launch_bounds__(256) void sfeat_kernel(
    const float* __restrict__ stat, const float* __restrict__ all_st,
    const int* __restrict__ nbr, const float* __restrict__ W,
    const float* __restrict__ bias, const float* __restrict__ g,
    const float* __restrict__ be, float* __restrict__ sfeat)
{
    __shared__ float comb[(KNB+1)*SDIM]; // 384
    __shared__ float sred[4];
    int b = blockIdx.x, t = threadIdx.x;
    for (int i = t; i < (KNB+1)*SDIM; i += 256) {
        if (i < SDIM) comb[i] = stat[b*SDIM + i];
        else {
            int n = (i - SDIM) >> 6, d = (i - SDIM) & 63;
            comb[i] = all_st[(size_t)nbr[b*KNB + n] * SDIM + d];
        }
    }
    __syncthreads();
    float acc = bias[t];
    for (int j = 0; j < (KNB+1)*SDIM; ++j)
        acc = fmaf(comb[j], W[j*HDIM + t], acc);
    float mu  = block_sum256(acc, sred) * (1.f/256.f);
    float d   = acc - mu;
    float var = block_sum256(d*d, sred) * (1.f/256.f);
    float y = g[t] * d * rsqrtf(var + 1e-5f) + be[t];
    sfeat[(size_t)b*HDIM + t] = gelu_f(y);
}

// ------ dynamic embedding (writes residual stream as bf16 hi/lo pair) ------
__global__ __launch_bounds__(256) void dyn_kernel(
    const float* __restrict__ dynv, const float* __restrict__ W,
    const float* __restrict__ bias, const float* __restrict__ g,
    const float* __restrict__ be, const float* __restrict__ sfeat,
    ushort* __restrict__ xhi, ushort* __restrict__ xlo)
{
    __shared__ float w[DDIM*HDIM];
    __shared__ float drow[DDIM];
    __shared__ float sred[4];
    int row = blockIdx.x, t = threadIdx.x;
    int b = row / T_SEQ;
    for (int i = t; i < DDIM*HDIM; i += 256) w[i] = W[i];
    if (t < DDIM) drow[t] = dynv[(size_t)row*DDIM + t];
    __syncthreads();
    float acc = bias[t];
    #pragma unroll
    for (int j = 0; j < DDIM; ++j) acc = fmaf(drow[j], w[j*HDIM + t], acc);
    float mu  = block_sum256(acc, sred) * (1.f/256.f);
    float d   = acc - mu;
    float var = block_sum256(d*d, sred) * (1.f/256.f);
    float y = g[t] * d * rsqrtf(var + 1e-5f) + be[t];
    float val = gelu_f(y) + sfeat[(size_t)b*HDIM + t];
    size_t idx = (size_t)row*HDIM + t;
    ushort hh = f2b_hi(val);
    xhi[idx] = hh;
    xlo[idx] = f2b_lo(val, hh);
}

// ------- weight transpose + bf16 hi/lo split: W[L][K][N] -> Wt[L][N][K] -------
__global__ __launch_bounds__(256) void tsplit_kernel(
    const float* __restrict__ W, ushort* __restrict__ hi, ushort* __restrict__ lo,
    int K, int N)
{
    __shared__ float tile[32][33];
    size_t l = blockIdx.z;
    const float* Wl = W + l*(size_t)K*N;
    ushort* hil = hi + l*(size_t)K*N;
    ushort* lol = lo + l*(size_t)K*N;
    int n0 = blockIdx.x*32, k0 = blockIdx.y*32;
    int tx = threadIdx.x & 31, ty = threadIdx.x >> 5;
    for (int i = ty; i < 32; i += 8) tile[i][tx] = Wl[(size_t)(k0+i)*N + n0 + tx];
    __syncthreads();
    for (int i = ty; i < 32; i += 8) {
        float v = tile[tx][i];              // W[k0+tx][n0+i]
        ushort h = f2b_hi(v);
        size_t o = (size_t)(n0+i)*K + k0 + tx;
        hil[o] = h;
        lol[o] = f2b_lo(v, h);
    }
}

// ---------------- split-bf16 MFMA GEMM ----------------
// C[M][N] = A[M][K] @ B[K][N] + bias; A as hi/lo bf16 [M][K], B pre-transposed
// hi/lo bf16 [N][K]. 3-term split (ah*bh + ah*bl + al*bh), fp32 accumulate.
// Block 256 = 4 waves (2x2), wave tile 64x64, frags 2x2 of 32x32, K-step 16.
// Rows guarded (any M). DO_ADD: += (addhi+addlo) residual. OUT_HILO: write
// bf16 hi/lo, else fp32.
template<int DO_RELU, int DO_ADD, int OUT_HILO>
__global__ __launch_bounds__(256) void gemm_mfma(
    const ushort* __restrict__ Ahi, const ushort* __restrict__ Alo,
    const ushort* __restrict__ Bhi, const ushort* __restrict__ Blo,
    const float* __restrict__ bias,
    const ushort* __restrict__ Addhi, const ushort* __restrict__ Addlo,
    float* __restrict__ Cf, ushort* __restrict__ Chi, ushort* __restrict__ Clo,
    int M, int N, int K)
{
    int t = threadIdx.x;
    int lane = t & 63, wave = t >> 6;
    int wr = wave >> 1, wc = wave & 1;
    int lr = lane & 31;            // row (A) / col (B) within 32
    int kg = lane >> 5;            // k-half: lanes 0-31 -> k 0..7, 32-63 -> 8..15
    int row_b = blockIdx.y * 128 + wr * 64;
    int col_b = blockIdx.x * 128 + wc * 64;

    f32x16 acc[2][2];
    #pragma unroll
    for (int i = 0; i < 2; ++i)
        #pragma unroll
        for (int j = 0; j < 2; ++j)
            #pragma unroll
            for (int r = 0; r < 16; ++r) acc[i][j][r] = 0.f;

    for (int k0 = 0; k0 < K; k0 += 16) {
        int ka = k0 + kg * 8;
        bf16x8 ah[2], al[2], bh[2], bl[2];
        #pragma unroll
        for (int mi = 0; mi < 2; ++mi) {
            int ar = row_b + mi*32 + lr;
            if (ar >= M) ar = M - 1;           // clamp (stores guarded)
            size_t o = (size_t)ar * K + ka;
            ah[mi] = *reinterpret_cast<const bf16x8*>(Ahi + o);
            al[mi] = *reinterpret_cast<const bf16x8*>(Alo + o);
        }
        #pragma unroll
        for (int nj = 0; nj < 2; ++nj) {
            size_t o = (size_t)(col_b + nj*32 + lr) * K + ka;
            bh[nj] = *reinterpret_cast<const bf16x8*>(Bhi + o);
            bl[nj] = *reinterpret_cast<const bf16x8*>(Blo + o);
        }
        #pragma unroll
        for (int mi = 0; mi < 2; ++mi)
            #pragma unroll
            for (int nj = 0; nj < 2; ++nj) {
                acc[mi][nj] = __builtin_amdgcn_mfma_f32_32x32x16_bf16(
                    ah[mi], bh[nj], acc[mi][nj], 0, 0, 0);
                acc[mi][nj] = __builtin_amdgcn_mfma_f32_32x32x16_bf16(
                    ah[mi], bl[nj], acc[mi][nj], 0, 0, 0);
                acc[mi][nj] = __builtin_amdgcn_mfma_f32_32x32x16_bf16(
                    al[mi], bh[nj], acc[mi][nj], 0, 0, 0);
            }
    }

    // epilogue: C/D map: col = lane&31, row = (r&3)+8*(r>>2)+4*kg
    #pragma unroll
    for (int mi = 0; mi < 2; ++mi)
        #pragma unroll
        for (int nj = 0; nj < 2; ++nj) {
            int col = col_b + nj*32 + lr;
            float bv = bias[col];
            #pragma unroll
            for (int r = 0; r < 16; ++r) {
                int row = row_b + mi*32 + (r & 3) + 8*(r >> 2) + 4*kg;
                if (row >= M) continue;
                float v = acc[mi][nj][r] + bv;
                if (DO_RELU) v = fmaxf(v, 0.f);
                size_t o = (size_t)row * N + col;
                if (DO_ADD) v += b2f(Addhi[o]) + b2f(Addlo[o]);
                if (OUT_HILO) {
                    ushort hh = f2b_hi(v);
                    Chi[o] = hh;
                    Clo[o] = f2b_lo(v, hh);
                } else {
                    Cf[o] = v;
                }
            }
        }
}

// ---------------- attention (one block per (local b, h)) ----------------
// Register-blocked fp32; epilogue emits bf16 hi/lo for the O-proj GEMM.
__global__ __launch_bounds__(256) void attn_kernel(
    const float* __restrict__ qkv,
    ushort* __restrict__ ahi, ushort* __restrict__ alo)
{
    __shared__ float Klds[368][36];
    __shared__ float Vlds[368][36];
    __shared__ float Qlds[4][8][36];
    int bh = blockIdx.x;
    int b = bh >> 3, h = bh & 7;
    int t = threadIdx.x;
    int wave = t >> 6, lane = t & 63;

    for (int i = t; i < 368*8; i += 256) {
        int r = i >> 3, d0 = (i & 7) * 4;
        float4 kv, vv;
        if (r < T_SEQ) {
            size_t base = ((size_t)(b*T_SEQ + r))*768 + h*HD + d0;
            kv = *reinterpret_cast<const float4*>(&qkv[base + 256]);
            vv = *reinterpret_cast<const float4*>(&qkv[base + 512]);
        } else {
            kv = make_float4(0.f,0.f,0.f,0.f); vv = kv;
        }
        *reinterpret_cast<float4*>(&Klds[r][d0]) = kv;
        *reinterpret_cast<float4*>(&Vlds[r][d0]) = vv;
    }
    __syncthreads();   // only barrier; waves independent below

    const float scale = 0.17677669529663687f; // 1/sqrt(32)
    int rq = lane >> 3;
    int a4 = (lane & 7) * 4;
    int jj[6];
    #pragma unroll
    for (int c = 0; c < 6; ++c) jj[c] = min(c*64 + lane, 367);

    for (int st = wave; st < 46; st += 4) {
        int row0 = st * 8;
        {
            int qr = min(row0 + rq, T_SEQ - 1);
            float4 qv = *reinterpret_cast<const float4*>(
                &qkv[((size_t)(b*T_SEQ + qr))*768 + h*HD + a4]);
            *reinterpret_cast<float4*>(&Qlds[wave][rq][a4]) = qv;
        }
        float s[8][6];
        #pragma unroll
        for (int r = 0; r < 8; ++r)
            #pragma unroll
            for (int c = 0; c < 6; ++c) s[r][c] = 0.f;
        #pragma unroll
        for (int dq = 0; dq < 8; ++dq) {
            float4 q[8];
            #pragma unroll
            for (int r = 0; r < 8; ++r)
                q[r] = *reinterpret_cast<const float4*>(&Qlds[wave][r][dq*4]);
            #pragma unroll
            for (int c = 0; c < 6; ++c) {
                float4 k = *reinterpret_cast<const float4*>(&Klds[jj[c]][dq*4]);
                #pragma unroll
                for (int r = 0; r < 8; ++r) {
                    s[r][c] = fmaf(q[r].x, k.x, s[r][c]);
                    s[r][c] = fmaf(q[r].y, k.y, s[r][c]);
                    s[r][c] = fmaf(q[r].z, k.z, s[r][c]);
                    s[r][c] = fmaf(q[r].w, k.w, s[r][c]);
                }
            }
        }
        #pragma unroll
        for (int r = 0; r < 8; ++r) {
            if (lane >= 45) s[r][5] = -3e38f;
            float mx = s[r][0];
            #pragma unroll
            for (int c = 1; c < 6; ++c) mx = fmaxf(mx, s[r][c]);
            #pragma unroll
            for (int off = 32; off; off >>= 1) mx = fmaxf(mx, __shfl_xor(mx, off));
            float sum = 0.f;
            #pragma unroll
            for (int c = 0; c < 6; ++c) {
                float e = __expf((s[r][c] - mx) * scale);
                s[r][c] = e; sum += e;
            }
            #pragma unroll
            for (int off = 32; off; off >>= 1) sum += __shfl_xor(sum, off);
            float inv = 1.f / sum;
            #pragma unroll
            for (int c = 0; c < 6; ++c) s[r][c] *= inv;
        }
        float acc[8][4];
        #pragma unroll
        for (int r = 0; r < 8; ++r)
            #pragma unroll
            for (int i = 0; i < 4; ++i) acc[r][i] = 0.f;
        #pragma unroll
        for (int k = 0; k < 46; ++k) {
            int j = rq + k*8;
            float4 v = *reinterpret_cast<const float4*>(&Vlds[j][a4]);
            int srcl = j & 63;
            const int c = k >> 3;
            #pragma unroll
            for (int r = 0; r < 8; ++r) {
                float pv = __shfl(s[r][c], srcl);
                acc[r][0] = fmaf(pv, v.x, acc[r][0]);
                acc[r][1] = fmaf(pv, v.y, acc[r][1]);
                acc[r][2] = fmaf(pv, v.z, acc[r][2]);
                acc[r][3] = fmaf(pv, v.w, acc[r][3]);
            }
        }
        #pragma unroll
        for (int r = 0; r < 8; ++r)
            #pragma unroll
            for (int i = 0; i < 4; ++i) {
                acc[r][i] += __shfl_xor(acc[r][i], 8);
                acc[r][i] += __shfl_xor(acc[r][i], 16);
                acc[r][i] += __shfl_xor(acc[r][i], 32);
            }
        if (rq == 0) {
            #pragma unroll
            for (int r = 0; r < 8; ++r) {
                int row = row0 + r;
                if (row < T_SEQ) {
                    size_t idx = ((size_t)(b*T_SEQ + row))*HDIM + h*HD + a4;
                    ushort4 hv, lv;
                    hv.x = f2b_hi(acc[r][0]); lv.x = f2b_lo(acc[r][0], hv.x);
                    hv.y = f2b_hi(acc[r][1]); lv.y = f2b_lo(acc[r][1], hv.y);
                    hv.z = f2b_hi(acc[r][2]); lv.z = f2b_lo(acc[r][2], hv.z);
                    hv.w = f2b_hi(acc[r][3]); lv.w = f2b_lo(acc[r][3], hv.w);
                    *reinterpret_cast<ushort4*>(&ahi[idx]) = hv;
                    *reinterpret_cast<ushort4*>(&alo[idx]) = lv;
                }
            }
        }
    }
}

// ------- LN in place on hi/lo residual stream, wave-per-row (4 rows/blk) -------
__global__ __launch_bounds__(256) void ln2_kernel(
    ushort* __restrict__ xhi, ushort* __restrict__ xlo,
    const float* __restrict__ g, const float* __restrict__ be)
{
    int wave = threadIdx.x >> 6, lane = threadIdx.x & 63;
    size_t row = (size_t)blockIdx.x * 4 + wave;
    size_t base = row * HDIM + lane * 4;
    ushort4 h4 = *reinterpret_cast<const ushort4*>(&xhi[base]);
    ushort4 l4 = *reinterpret_cast<const ushort4*>(&xlo[base]);
    float4 v = make_float4(b2f(h4.x)+b2f(l4.x), b2f(h4.y)+b2f(l4.y),
                           b2f(h4.z)+b2f(l4.z), b2f(h4.w)+b2f(l4.w));
    float s = v.x + v.y + v.z + v.w;
    #pragma unroll
    for (int off = 32; off; off >>= 1) s += __shfl_xor(s, off);
    float mu = s * (1.f/256.f);
    float4 d = make_float4(v.x-mu, v.y-mu, v.z-mu, v.w-mu);
    float s2 = d.x*d.x + d.y*d.y + d.z*d.z + d.w*d.w;
    #pragma unroll
    for (int off = 32; off; off >>= 1) s2 += __shfl_xor(s2, off);
    float rs = rsqrtf(s2 * (1.f/256.f) + 1e-5f);
    float4 gg = *reinterpret_cast<const float4*>(&g[lane*4]);
    float4 bb = *reinterpret_cast<const float4*>(&be[lane*4]);
    float4 o;
    o.x = gg.x * d.x * rs + bb.x;
    o.y = gg.y * d.y * rs + bb.y;
    o.z = gg.z * d.z * rs + bb.z;
    o.w = gg.w * d.w * rs + bb.w;
    ushort4 hv, lv;
    hv.x = f2b_hi(o.x); lv.x = f2b_lo(o.x, hv.x);
    hv.y = f2b_hi(o.y); lv.y = f2b_lo(o.y, hv.y);
    hv.z = f2b_hi(o.z); lv.z = f2b_lo(o.z, hv.z);
    hv.w = f2b_hi(o.w); lv.w = f2b_lo(o.w, hv.w);
    *reinterpret_cast<ushort4*>(&xhi[base]) = hv;
    *reinterpret_cast<ushort4*>(&xlo[base]) = lv;
}

// ---------------- mean-pool + output head (reads hi/lo stream) ----------------
__global__ __launch_bounds__(256) void head_kernel(
    const ushort* __restrict__ xhi, const ushort* __restrict__ xlo,
    const float* __restrict__ sfeat,
    const float* __restrict__ W1, const float* __restrict__ b1,
    const float* __restrict__ W2, const float* __restrict__ b2,
    const float* __restrict__ scale, const float* __restrict__ shift,
    float* __restrict__ out)
{
    __shared__ float p[HDIM];
    __shared__ float h1[HDIM/2];
    int b = blockIdx.x, t = threadIdx.x;
    float acc = 0.f;
    for (int tt = 0; tt < T_SEQ; ++tt) {
        size_t idx = ((size_t)b*T_SEQ + tt)*HDIM + t;
        acc += b2f(xhi[idx]) + b2f(xlo[idx]);
    }
    p[t] = acc * (1.f/365.f) + sfeat[(size_t)b*HDIM + t];
    __syncthreads();
    if (t < HDIM/2) {
        float a = b1[t];
        for (int c = 0; c < HDIM; ++c) a = fmaf(p[c], W1[c*(HDIM/2) + t], a);
        h1[t] = gelu_f(a);
    }
    __syncthreads();
    if (t < 30) {
        float a = b2[t];
        for (int j = 0; j < HDIM/2; ++j) a = fmaf(h1[j], W2[j*30 + t], a);
        out[b*30 + t] = tanhf(a) * scale[0] + shift[0];
    }
}

extern "C" void kernel_launch(void* const* d_in, const int* in_sizes, int n_in,
                              void* d_out, int out_size, void* d_ws, size_t ws_size,
                              hipStream_t stream) {
    const float* p_static = (const float*)d_in[0];
    const float* p_dyn    = (const float*)d_in[1];
    const float* p_lat    = (const float*)d_in[2];
    const float* p_lon    = (const float*)d_in[3];
    const float* p_all    = (const float*)d_in[4];
    const float* p_coords = (const float*)d_in[5];
    const float* p_Wst    = (const float*)d_in[6];
    const float* p_bst    = (const float*)d_in[7];
    const float* p_gst    = (const float*)d_in[8];
    const float* p_best   = (const float*)d_in[9];
    const float* p_Wdy    = (const float*)d_in[10];
    const float* p_bdy    = (const float*)d_in[11];
    const float* p_gdy    = (const float*)d_in[12];
    const float* p_bedy   = (const float*)d_in[13];
    const float* p_Wqkv   = (const float*)d_in[14];
    const float* p_bqkv   = (const float*)d_in[15];
    const float* p_Wo     = (const float*)d_in[16];
    const float* p_bo     = (const float*)d_in[17];
    const float* p_gln1   = (const float*)d_in[18];
    const float* p_beln1  = (const float*)d_in[19];
    const float* p_Wf1    = (const float*)d_in[20];
    const float* p_bf1    = (const float*)d_in[21];
    const float* p_Wf2    = (const float*)d_in[22];
    const float* p_bf2    = (const float*)d_in[23];
    const float* p_gln2   = (const float*)d_in[24];
    const float* p_beln2  = (const float*)d_in[25];
    const float* p_Wo1    = (const float*)d_in[26];
    const float* p_bo1    = (const float*)d_in[27];
    const float* p_Wo2    = (const float*)d_in[28];
    const float* p_bo2    = (const float*)d_in[29];
    const float* p_scale  = (const float*)d_in[30];
    const float* p_shift  = (const float*)d_in[31];
    float* out = (float*)d_out;
    (void)in_sizes; (void)n_in; (void)out_size;

    char* ws = (char*)d_ws;
    size_t off = 0;
    auto alloc = [&](size_t bytes) -> void* {
        void* p = ws + off;
        off += (bytes + 255) & ~(size_t)255;
        return p;
    };
    const int ROWS = BATCH * T_SEQ; // 93440
    int*    nbr   = (int*)   alloc((size_t)BATCH*KNB*sizeof(int));
    float*  sfeat = (float*) alloc((size_t)BATCH*HDIM*sizeof(float));
    ushort* xhi   = (ushort*)alloc((size_t)ROWS*HDIM*sizeof(ushort));
    ushort* xlo   = (ushort*)alloc((size_t)ROWS*HDIM*sizeof(ushort));
    // transposed/split weights [L][N][K]: hi then lo, each SZ elements (2B)
    const size_t SZ_QKV = (size_t)4*768*256, SZ_O = (size_t)4*256*256;
    const size_t SZ_F1  = (size_t)4*1024*256, SZ_F2 = (size_t)4*256*1024;
    ushort* Wqkvt_h = (ushort*)alloc(SZ_QKV*2*sizeof(ushort)); ushort* Wqkvt_l = Wqkvt_h + SZ_QKV;
    ushort* Wot_h   = (ushort*)alloc(SZ_O  *2*sizeof(ushort)); ushort* Wot_l   = Wot_h   + SZ_O;
    ushort* Wf1t_h  = (ushort*)alloc(SZ_F1 *2*sizeof(ushort)); ushort* Wf1t_l  = Wf1t_h  + SZ_F1;
    ushort* Wf2t_h  = (ushort*)alloc(SZ_F2 *2*sizeof(ushort)); ushort* Wf2t_l  = Wf2t_h  + SZ_F2;
    size_t fixed = off;

    // per-chunk: union(qkv f32: RW*768*4B, hbuf hi/lo: RW*1024*4B) + aatt hi/lo
    // (RW*256*4B) => CH * 365 * 5120 B.
    const size_t PER_B = (size_t)T_SEQ * 1024 * 4;   // union(qkv, hbuf hilo)
    const size_t PER_A = (size_t)T_SEQ * 256 * 4;    // aatt hi+lo
    const size_t PER_CH = PER_B + PER_A;             // 1,868,800 B
    int CH = 4;
    {
        const int tiers[6] = {256, 128, 64, 32, 16, 8};
        for (int i = 0; i < 6; ++i) {
            if (fixed + (size_t)tiers[i]*PER_CH + 8192 <= ws_size) { CH = tiers[i]; break; }
        }
    }
    char*   big    = (char*)alloc((size_t)CH * PER_B);
    ushort* aatt_h = (ushort*)alloc((size_t)CH * PER_A);
    const int RW = CH * T_SEQ;
    ushort* aatt_l = aatt_h + (size_t)RW * HDIM;
    float*  qkv    = (float*)big;
    ushort* hbuf_h = (ushort*)big;
    ushort* hbuf_l = hbuf_h + (size_t)RW * FFDIM;
    const int GY = (RW + 127) / 128;   // guarded M-tiles

    topk_kernel <<<BATCH, 256, 0, stream>>>(p_lat, p_lon, p_coords, nbr);
    sfeat_kernel<<<BATCH, 256, 0, stream>>>(p_static, p_all, nbr, p_Wst, p_bst, p_gst, p_best, sfeat);
    dyn_kernel  <<<ROWS, 256, 0, stream>>>(p_dyn, p_Wdy, p_bdy, p_gdy, p_bedy, sfeat, xhi, xlo);
    tsplit_kernel<<<dim3(24, 8, 4), 256, 0, stream>>>(p_Wqkv, Wqkvt_h, Wqkvt_l, 256, 768);
    tsplit_kernel<<<dim3( 8, 8, 4), 256, 0, stream>>>(p_Wo,   Wot_h,   Wot_l,   256, 256);
    tsplit_kernel<<<dim3(32, 8, 4), 256, 0, stream>>>(p_Wf1,  Wf1t_h,  Wf1t_l,  256, 1024);
    tsplit_kernel<<<dim3( 8,32, 4), 256, 0, stream>>>(p_Wf2,  Wf2t_h,  Wf2t_l,  1024, 256);

    const int NCHUNK = BATCH / CH;
    for (int c = 0; c < NCHUNK; ++c) {
        size_t co = (size_t)c * CH * T_SEQ * HDIM;
        ushort* xhic = xhi + co;
        ushort* xloc = xlo + co;
        for (int l = 0; l < 4; ++l) {
            gemm_mfma<0,0,0><<<dim3(6, GY), 256, 0, stream>>>(
                xhic, xloc, Wqkvt_h + (size_t)l*768*256, Wqkvt_l + (size_t)l*768*256,
                p_bqkv + l*768, nullptr, nullptr, qkv, nullptr, nullptr, RW, 768, 256);
            attn_kernel<<<CH*NHEADS, 256, 0, stream>>>(qkv, aatt_h, aatt_l);
            gemm_mfma<0,1,1><<<dim3(2, GY), 256, 0, stream>>>(
                aatt_h, aatt_l, Wot_h + (size_t)l*256*256, Wot_l + (size_t)l*256*256,
                p_bo + l*256, xhic, xloc, nullptr, xhic, xloc, RW, 256, 256);
            ln2_kernel<<<RW/4, 256, 0, stream>>>(xhic, xloc, p_gln1 + l*256, p_beln1 + l*256);
            gemm_mfma<1,0,1><<<dim3(8, GY), 256, 0, stream>>>(
                xhic, xloc, Wf1t_h + (size_t)l*1024*256, Wf1t_l + (size_t)l*1024*256,
                p_bf1 + l*1024, nullptr, nullptr, nullptr, hbuf_h, hbuf_l, RW, 1024, 256);
            gemm_mfma<0,1,1><<<dim3(2, GY), 256, 0, stream>>>(
                hbuf_h, hbuf_l, Wf2t_h + (size_t)l*256*1024, Wf2t_l + (size_t)l*256*1024,
                p_bf2 + l*256, xhic, xloc, nullptr, xhic, xloc, RW, 256, 1024);
            ln2_kernel<<<RW/4, 256, 0, stream>>>(xhic, xloc, p_gln2 + l*256, p_beln2 + l*256);
        }
    }
    head_kernel<<<BATCH, 256, 0, stream>>>(xhi, xlo, sfeat, p_Wo1, p_bo1, p_Wo2, p_bo2, p_scale, p_shift, out);
}

// Round 6
// 8594.064 us; speedup vs baseline: 5.4489x; 1.4336x over previous
//
#include <hip/hip_runtime.h>
#include <math.h>

#define T_SEQ 365
#define HDIM 256
#define NHEADS 8
#define HD 32
#define BATCH 256
#define DDIM 16
#define FFDIM 1024
#define NST 10000
#define KNB 5
#define SDIM 64

typedef __bf16 bf16x8 __attribute__((ext_vector_type(8)));
typedef float  f32x16 __attribute__((ext_vector_type(16)));

__device__ __forceinline__ ushort f2b_hi(float v) {
    unsigned u = __float_as_uint(v);
    unsigned r = u + 0x7fffu + ((u >> 16) & 1u);
    return (ushort)(r >> 16);
}
__device__ __forceinline__ float b2f(ushort h) {
    return __uint_as_float(((unsigned)h) << 16);
}
__device__ __forceinline__ ushort f2b_lo(float v, ushort hi) {
    return f2b_hi(v - b2f(hi));
}

__device__ __forceinline__ float gelu_f(float x) {
    return 0.5f * x * (1.f + erff(x * 0.70710678118654752f));
}

// FT (fragment-tiled) layout for a [R][C] bf16 matrix, C%8==0, R%32==0:
// offset(r,c) = ((r>>5)*(C>>3) + (c>>3))*256 + (r&31)*8 + (c&7)
// A wave's MFMA fragment (32 rows x 8 k) is then one contiguous 512-ushort run.

// block-wide (256 threads = 4 waves) sum; sred must be float[4] shared
__device__ __forceinline__ float block_sum256(float v, float* sred) {
    #pragma unroll
    for (int off = 32; off; off >>= 1) v += __shfl_xor(v, off);
    int wave = threadIdx.x >> 6;
    if ((threadIdx.x & 63) == 0) sred[wave] = v;
    __syncthreads();
    float s = sred[0] + sred[1] + sred[2] + sred[3];
    __syncthreads();
    return s;
}

// ---------------- top-K neighbor search ----------------
__global__ __launch_bounds__(256) void topk_kernel(
    const float* __restrict__ lat, const float* __restrict__ lon,
    const float* __restrict__ coords, int* __restrict__ nbr)
{
    __shared__ float hav[NST];
    __shared__ float rv[256];
    __shared__ int   ri[256];
    const float DEG = 0.017453292519943295f;
    int b = blockIdx.x, t = threadIdx.x;
    float lat_o = (lat[b] + 1.f) * 0.5f * 25.f + 24.f;
    float lon_o = (lon[b] + 1.f) * 0.5f * 58.5f - 125.f;
    float qlat = lat_o * DEG, qlon = lon_o * DEG;
    float cq = cosf(qlat);
    for (int i = t; i < NST; i += 256) {
        float slat = coords[2*i], slon = coords[2*i+1];
        float dlat = qlat - slat, dlon = qlon - slon;
        float s1 = sinf(dlat * 0.5f), s2 = sinf(dlon * 0.5f);
        hav[i] = s1*s1 + cq * cosf(slat) * s2*s2;
    }
    __syncthreads();
    for (int sel = 0; sel < KNB + 1; ++sel) {
        float bv = 1e30f; int bi = 0x7fffffff;
        for (int i = t; i < NST; i += 256) {
            float v = hav[i];
            if (v < bv || (v == bv && i < bi)) { bv = v; bi = i; }
        }
        rv[t] = bv; ri[t] = bi;
        __syncthreads();
        for (int s = 128; s > 0; s >>= 1) {
            if (t < s) {
                float ov = rv[t+s]; int oi = ri[t+s];
                if (ov < rv[t] || (ov == rv[t] && oi < ri[t])) { rv[t] = ov; ri[t] = oi; }
            }
            __syncthreads();
        }
        if (t == 0) {
            if (sel > 0) nbr[b*KNB + sel - 1] = ri[0];
            hav[ri[0]] = 1e30f;   // mask winner
        }
        __syncthreads();
    }
}

// ---------------- static-feature branch ----------------
__global__ __launch_bounds__(256) void sfeat_kernel(
    const float* __restrict__ stat, const float* __restrict__ all_st,
    const int* __restrict__ nbr, const float* __restrict__ W,
    const float* __restrict__ bias, const float* __restrict__ g,
    const float* __restrict__ be, float* __restrict__ sfeat)
{
    __shared__ float comb[(KNB+1)*SDIM]; // 384
    __shared__ float sred[4];
    int b = blockIdx.x, t = threadIdx.x;
    for (int i = t; i < (KNB+1)*SDIM; i += 256) {
        if (i < SDIM) comb[i] = stat[b*SDIM + i];
        else {
            int n = (i - SDIM) >> 6, d = (i - SDIM) & 63;
            comb[i] = all_st[(size_t)nbr[b*KNB + n] * SDIM + d];
        }
    }
    __syncthreads();
    float acc = bias[t];
    for (int j = 0; j < (KNB+1)*SDIM; ++j)
        acc = fmaf(comb[j], W[j*HDIM + t], acc);
    float mu  = block_sum256(acc, sred) * (1.f/256.f);
    float d   = acc - mu;
    float var = block_sum256(d*d, sred) * (1.f/256.f);
    float y = g[t] * d * rsqrtf(var + 1e-5f) + be[t];
    sfeat[(size_t)b*HDIM + t] = gelu_f(y);
}

// ------ dynamic embedding (writes residual stream hi/lo in FT layout) ------
__global__ __launch_bounds__(256) void dyn_kernel(
    const float* __restrict__ dynv, const float* __restrict__ W,
    const float* __restrict__ bias, const float* __restrict__ g,
    const float* __restrict__ be, const float* __restrict__ sfeat,
    ushort* __restrict__ xhi, ushort* __restrict__ xlo)
{
    __shared__ float w[DDIM*HDIM];
    __shared__ float drow[DDIM];
    __shared__ float sred[4];
    int row = blockIdx.x, t = threadIdx.x;
    int b = row / T_SEQ;
    for (int i = t; i < DDIM*HDIM; i += 256) w[i] = W[i];
    if (t < DDIM) drow[t] = dynv[(size_t)row*DDIM + t];
    __syncthreads();
    float acc = bias[t];
    #pragma unroll
    for (int j = 0; j < DDIM; ++j) acc = fmaf(drow[j], w[j*HDIM + t], acc);
    float mu  = block_sum256(acc, sred) * (1.f/256.f);
    float d   = acc - mu;
    float var = block_sum256(d*d, sred) * (1.f/256.f);
    float y = g[t] * d * rsqrtf(var + 1e-5f) + be[t];
    float val = gelu_f(y) + sfeat[(size_t)b*HDIM + t];
    size_t o = ((size_t)(row >> 5) * 32 + (t >> 3)) * 256 + ((row & 31) << 3) + (t & 7);
    ushort hh = f2b_hi(val);
    xhi[o] = hh;
    xlo[o] = f2b_lo(val, hh);
}

// --- weight transpose + split: W[L][K][N] -> FT([N][K]) hi/lo per layer ---
__global__ __launch_bounds__(256) void tsplit_kernel(
    const float* __restrict__ W, ushort* __restrict__ hi, ushort* __restrict__ lo,
    int K, int N)
{
    __shared__ float tile[32][33];
    size_t l = blockIdx.z;
    const float* Wl = W + l*(size_t)K*N;
    ushort* hil = hi + l*(size_t)K*N;
    ushort* lol = lo + l*(size_t)K*N;
    int n0 = blockIdx.x*32, k0 = blockIdx.y*32;
    int tx = threadIdx.x & 31, ty = threadIdx.x >> 5;
    int KB = K >> 3;
    for (int i = ty; i < 32; i += 8) tile[i][tx] = Wl[(size_t)(k0+i)*N + n0 + tx];
    __syncthreads();
    for (int i = ty; i < 32; i += 8) {
        float v = tile[tx][i];              // (k=k0+tx, n=n0+i)
        ushort h = f2b_hi(v);
        size_t o = ((size_t)(n0 >> 5) * KB + (k0 >> 3) + (tx >> 3)) * 256
                 + ((size_t)i << 3) + (tx & 7);
        hil[o] = h;
        lol[o] = f2b_lo(v, h);
    }
}

// ---------------- split-bf16 MFMA GEMM, FT operands, no LDS ----------------
// C[M][N] = A@B + bias; A = FT hi/lo [M][K], B = FT hi/lo [N][K].
// 3-term split (ah*bh + ah*bl + al*bh), fp32 accumulate. Block 256 = 4 waves
// (2x2), wave tile 64x64, frags 2x2 of 32x32, K-step 16, 2-deep pipeline.
// Requires M%32==0, K%32==0. DO_ADD: += FT(addhi+addlo). OUT_HILO: FT hi/lo
// out, else f32 row-major.
template<int DO_RELU, int DO_ADD, int OUT_HILO>
__global__ __launch_bounds__(256) void gemm_mfma(
    const ushort* __restrict__ Ahi, const ushort* __restrict__ Alo,
    const ushort* __restrict__ Bhi, const ushort* __restrict__ Blo,
    const float* __restrict__ bias,
    const ushort* __restrict__ Addhi, const ushort* __restrict__ Addlo,
    float* __restrict__ Cf, ushort* __restrict__ Chi, ushort* __restrict__ Clo,
    int M, int N, int K)
{
    const int t = threadIdx.x;
    const int lane = t & 63, wave = t >> 6;
    const int wr = wave >> 1, wc = wave & 1;
    const int lr = lane & 31, kg = lane >> 5;
    const int row_b = blockIdx.y * 128 + wr * 64;
    const int col_b = blockIdx.x * 128 + wc * 64;
    const int KB = K >> 3;

    const ushort *pAh[2], *pAl[2], *pBh[2], *pBl[2];
    #pragma unroll
    for (int mi = 0; mi < 2; ++mi) {
        int rb = row_b + mi*32; if (rb > M - 32) rb = M - 32;   // loads clamped
        size_t base = ((size_t)(rb >> 5) * KB + kg) * 256 + lr * 8;
        pAh[mi] = Ahi + base; pAl[mi] = Alo + base;
    }
    #pragma unroll
    for (int nj = 0; nj < 2; ++nj) {
        size_t base = ((size_t)((col_b + nj*32) >> 5) * KB + kg) * 256 + lr * 8;
        pBh[nj] = Bhi + base; pBl[nj] = Blo + base;
    }

    f32x16 acc[2][2];
    #pragma unroll
    for (int i = 0; i < 2; ++i)
        #pragma unroll
        for (int j = 0; j < 2; ++j)
            #pragma unroll
            for (int r = 0; r < 16; ++r) acc[i][j][r] = 0.f;

    bf16x8 a0h[2], a0l[2], b0h[2], b0l[2];
    bf16x8 a1h[2], a1l[2], b1h[2], b1l[2];

#define LOADF(AH, AL, BH, BL, OFF) do {                                        \
    _Pragma("unroll") for (int mi = 0; mi < 2; ++mi) {                         \
        AH[mi] = *reinterpret_cast<const bf16x8*>(pAh[mi] + (OFF));            \
        AL[mi] = *reinterpret_cast<const bf16x8*>(pAl[mi] + (OFF)); }          \
    _Pragma("unroll") for (int nj = 0; nj < 2; ++nj) {                         \
        BH[nj] = *reinterpret_cast<const bf16x8*>(pBh[nj] + (OFF));            \
        BL[nj] = *reinterpret_cast<const bf16x8*>(pBl[nj] + (OFF)); } } while(0)

#define MFMAF(AH, AL, BH, BL) do {                                             \
    _Pragma("unroll") for (int mi = 0; mi < 2; ++mi)                           \
    _Pragma("unroll") for (int nj = 0; nj < 2; ++nj) {                         \
        acc[mi][nj] = __builtin_amdgcn_mfma_f32_32x32x16_bf16(                 \
            AH[mi], BH[nj], acc[mi][nj], 0, 0, 0);                             \
        acc[mi][nj] = __builtin_amdgcn_mfma_f32_32x32x16_bf16(                 \
            AH[mi], BL[nj], acc[mi][nj], 0, 0, 0);                             \
        acc[mi][nj] = __builtin_amdgcn_mfma_f32_32x32x16_bf16(                 \
            AL[mi], BH[nj], acc[mi][nj], 0, 0, 0); } } while(0)

    LOADF(a0h, a0l, b0h, b0l, 0);
    for (int k0 = 0; k0 < K; k0 += 32) {
        size_t o1 = (size_t)((k0 + 16) >> 3) * 256;
        LOADF(a1h, a1l, b1h, b1l, o1);
        MFMAF(a0h, a0l, b0h, b0l);
        size_t o2 = (k0 + 32 < K) ? (size_t)((k0 + 32) >> 3) * 256 : 0;
        LOADF(a0h, a0l, b0h, b0l, o2);       // last iteration: harmless reload
        MFMAF(a1h, a1l, b1h, b1l);
    }
#undef LOADF
#undef MFMAF

    // epilogue: C/D map: col = lane&31, row31 = (r&3)+8*(r>>2)+4*kg
    #pragma unroll
    for (int mi = 0; mi < 2; ++mi) {
        int rb = row_b + mi*32;   // true (unclamped) row base for stores
        #pragma unroll
        for (int nj = 0; nj < 2; ++nj) {
            int col = col_b + nj*32 + lr;
            float bv = bias[col];
            size_t ftb = ((size_t)(rb >> 5) * (N >> 3) + (col >> 3)) * 256 + (col & 7);
            #pragma unroll
            for (int r = 0; r < 16; ++r) {
                int r31 = (r & 3) + 8*(r >> 2) + 4*kg;
                int row = rb + r31;
                if (row >= M) continue;
                float v = acc[mi][nj][r] + bv;
                if (DO_RELU) v = fmaxf(v, 0.f);
                size_t oo = ftb + (size_t)r31 * 8;
                if (DO_ADD) v += b2f(Addhi[oo]) + b2f(Addlo[oo]);
                if (OUT_HILO) {
                    ushort hh = f2b_hi(v);
                    Chi[oo] = hh;
                    Clo[oo] = f2b_lo(v, hh);
                } else {
                    Cf[(size_t)row * N + col] = v;
                }
            }
        }
    }
}

// ---------------- attention (one block per (local b, h), 8 waves) ----------------
// Register-blocked fp32; epilogue emits bf16 hi/lo in FT layout.
__global__ __launch_bounds__(512) void attn_kernel(
    const float* __restrict__ qkv,
    ushort* __restrict__ ahi, ushort* __restrict__ alo)
{
    __shared__ float Klds[368][36];
    __shared__ float Vlds[368][36];
    __shared__ float Qlds[8][8][36];
    int bh = blockIdx.x;
    int b = bh >> 3, h = bh & 7;
    int t = threadIdx.x;
    int wave = t >> 6, lane = t & 63;

    for (int i = t; i < 368*8; i += 512) {
        int r = i >> 3, d0 = (i & 7) * 4;
        float4 kv, vv;
        if (r < T_SEQ) {
            size_t base = ((size_t)(b*T_SEQ + r))*768 + h*HD + d0;
            kv = *reinterpret_cast<const float4*>(&qkv[base + 256]);
            vv = *reinterpret_cast<const float4*>(&qkv[base + 512]);
        } else {
            kv = make_float4(0.f,0.f,0.f,0.f); vv = kv;
        }
        *reinterpret_cast<float4*>(&Klds[r][d0]) = kv;
        *reinterpret_cast<float4*>(&Vlds[r][d0]) = vv;
    }
    __syncthreads();   // only barrier; waves independent below

    const float scale = 0.17677669529663687f; // 1/sqrt(32)
    int rq = lane >> 3;
    int a4 = (lane & 7) * 4;
    int jj[6];
    #pragma unroll
    for (int c = 0; c < 6; ++c) jj[c] = min(c*64 + lane, 367);

    for (int st = wave; st < 46; st += 8) {
        int row0 = st * 8;
        {
            int qr = min(row0 + rq, T_SEQ - 1);
            float4 qv = *reinterpret_cast<const float4*>(
                &qkv[((size_t)(b*T_SEQ + qr))*768 + h*HD + a4]);
            *reinterpret_cast<float4*>(&Qlds[wave][rq][a4]) = qv;
        }
        float s[8][6];
        #pragma unroll
        for (int r = 0; r < 8; ++r)
            #pragma unroll
            for (int c = 0; c < 6; ++c) s[r][c] = 0.f;
        #pragma unroll
        for (int dq = 0; dq < 8; ++dq) {
            float4 q[8];
            #pragma unroll
            for (int r = 0; r < 8; ++r)
                q[r] = *reinterpret_cast<const float4*>(&Qlds[wave][r][dq*4]);
            #pragma unroll
            for (int c = 0; c < 6; ++c) {
                float4 k = *reinterpret_cast<const float4*>(&Klds[jj[c]][dq*4]);
                #pragma unroll
                for (int r = 0; r < 8; ++r) {
                    s[r][c] = fmaf(q[r].x, k.x, s[r][c]);
                    s[r][c] = fmaf(q[r].y, k.y, s[r][c]);
                    s[r][c] = fmaf(q[r].z, k.z, s[r][c]);
                    s[r][c] = fmaf(q[r].w, k.w, s[r][c]);
                }
            }
        }
        #pragma unroll
        for (int r = 0; r < 8; ++r) {
            if (lane >= 45) s[r][5] = -3e38f;
            float mx = s[r][0];
            #pragma unroll
            for (int c = 1; c < 6; ++c) mx = fmaxf(mx, s[r][c]);
            #pragma unroll
            for (int off = 32; off; off >>= 1) mx = fmaxf(mx, __shfl_xor(mx, off));
            float sum = 0.f;
            #pragma unroll
            for (int c = 0; c < 6; ++c) {
                float e = __expf((s[r][c] - mx) * scale);
                s[r][c] = e; sum += e;
            }
            #pragma unroll
            for (int off = 32; off; off >>= 1) sum += __shfl_xor(sum, off);
            float inv = 1.f / sum;
            #pragma unroll
            for (int c = 0; c < 6; ++c) s[r][c] *= inv;
        }
        float acc[8][4];
        #pragma unroll
        for (int r = 0; r < 8; ++r)
            #pragma unroll
            for (int i = 0; i < 4; ++i) acc[r][i] = 0.f;
        #pragma unroll
        for (int k = 0; k < 46; ++k) {
            int j = rq + k*8;
            float4 v = *reinterpret_cast<const float4*>(&Vlds[j][a4]);
            int srcl = j & 63;
            const int c = k >> 3;
            #pragma unroll
            for (int r = 0; r < 8; ++r) {
                float pv = __shfl(s[r][c], srcl);
                acc[r][0] = fmaf(pv, v.x, acc[r][0]);
                acc[r][1] = fmaf(pv, v.y, acc[r][1]);
                acc[r][2] = fmaf(pv, v.z, acc[r][2]);
                acc[r][3] = fmaf(pv, v.w, acc[r][3]);
            }
        }
        #pragma unroll
        for (int r = 0; r < 8; ++r)
            #pragma unroll
            for (int i = 0; i < 4; ++i) {
                acc[r][i] += __shfl_xor(acc[r][i], 8);
                acc[r][i] += __shfl_xor(acc[r][i], 16);
                acc[r][i] += __shfl_xor(acc[r][i], 32);
            }
        if (rq == 0) {
            #pragma unroll
            for (int r = 0; r < 8; ++r) {
                int row = row0 + r;
                if (row < T_SEQ) {
                    int grow = b*T_SEQ + row;
                    int col  = h*HD + a4;
                    size_t o = ((size_t)(grow >> 5) * 32 + (col >> 3)) * 256
                             + ((grow & 31) << 3) + (col & 7);
                    ushort4 hv, lv;
                    hv.x = f2b_hi(acc[r][0]); lv.x = f2b_lo(acc[r][0], hv.x);
                    hv.y = f2b_hi(acc[r][1]); lv.y = f2b_lo(acc[r][1], hv.y);
                    hv.z = f2b_hi(acc[r][2]); lv.z = f2b_lo(acc[r][2], hv.z);
                    hv.w = f2b_hi(acc[r][3]); lv.w = f2b_lo(acc[r][3], hv.w);
                    *reinterpret_cast<ushort4*>(&ahi[o]) = hv;
                    *reinterpret_cast<ushort4*>(&alo[o]) = lv;
                }
            }
        }
    }
}

// ---- LN in place on FT hi/lo residual stream, wave-per-row (4 rows/blk) ----
__global__ __launch_bounds__(256) void ln2_kernel(
    ushort* __restrict__ xhi, ushort* __restrict__ xlo,
    const float* __restrict__ g, const float* __restrict__ be)
{
    int wave = threadIdx.x >> 6, lane = threadIdx.x & 63;
    size_t row = (size_t)blockIdx.x * 4 + wave;
    size_t o = ((row >> 5) * 32 + (lane >> 1)) * 256 + ((row & 31) << 3) + ((lane & 1) << 2);
    ushort4 h4 = *reinterpret_cast<const ushort4*>(&xhi[o]);
    ushort4 l4 = *reinterpret_cast<const ushort4*>(&xlo[o]);
    float4 v = make_float4(b2f(h4.x)+b2f(l4.x), b2f(h4.y)+b2f(l4.y),
                           b2f(h4.z)+b2f(l4.z), b2f(h4.w)+b2f(l4.w));
    float s = v.x + v.y + v.z + v.w;
    #pragma unroll
    for (int off = 32; off; off >>= 1) s += __shfl_xor(s, off);
    float mu = s * (1.f/256.f);
    float4 d = make_float4(v.x-mu, v.y-mu, v.z-mu, v.w-mu);
    float s2 = d.x*d.x + d.y*d.y + d.z*d.z + d.w*d.w;
    #pragma unroll
    for (int off = 32; off; off >>= 1) s2 += __shfl_xor(s2, off);
    float rs = rsqrtf(s2 * (1.f/256.f) + 1e-5f);
    float4 gg = *reinterpret_cast<const float4*>(&g[lane*4]);
    float4 bb = *reinterpret_cast<const float4*>(&be[lane*4]);
    float4 ov;
    ov.x = gg.x * d.x * rs + bb.x;
    ov.y = gg.y * d.y * rs + bb.y;
    ov.z = gg.z * d.z * rs + bb.z;
    ov.w = gg.w * d.w * rs + bb.w;
    ushort4 hv, lv;
    hv.x = f2b_hi(ov.x); lv.x = f2b_lo(ov.x, hv.x);
    hv.y = f2b_hi(ov.y); lv.y = f2b_lo(ov.y, hv.y);
    hv.z = f2b_hi(ov.z); lv.z = f2b_lo(ov.z, hv.z);
    hv.w = f2b_hi(ov.w); lv.w = f2b_lo(ov.w, hv.w);
    *reinterpret_cast<ushort4*>(&xhi[o]) = hv;
    *reinterpret_cast<ushort4*>(&xlo[o]) = lv;
}

// -------- mean-pool + output head (reads FT hi/lo stream) --------
__global__ __launch_bounds__(256) void head_kernel(
    const ushort* __restrict__ xhi, const ushort* __restrict__ xlo,
    const float* __restrict__ sfeat,
    const float* __restrict__ W1, const float* __restrict__ b1,
    const float* __restrict__ W2, const float* __restrict__ b2,
    const float* __restrict__ scale, const float* __restrict__ shift,
    float* __restrict__ out)
{
    __shared__ float p[HDIM];
    __shared__ float h1[HDIM/2];
    int b = blockIdx.x, t = threadIdx.x;
    float acc = 0.f;
    for (int tt = 0; tt < T_SEQ; ++tt) {
        size_t row = (size_t)b*T_SEQ + tt;
        size_t o = ((row >> 5) * 32 + (t >> 3)) * 256 + ((row & 31) << 3) + (t & 7);
        acc += b2f(xhi[o]) + b2f(xlo[o]);
    }
    p[t] = acc * (1.f/365.f) + sfeat[(size_t)b*HDIM + t];
    __syncthreads();
    if (t < HDIM/2) {
        float a = b1[t];
        for (int c = 0; c < HDIM; ++c) a = fmaf(p[c], W1[c*(HDIM/2) + t], a);
        h1[t] = gelu_f(a);
    }
    __syncthreads();
    if (t < 30) {
        float a = b2[t];
        for (int j = 0; j < HDIM/2; ++j) a = fmaf(h1[j], W2[j*30 + t], a);
        out[b*30 + t] = tanhf(a) * scale[0] + shift[0];
    }
}

extern "C" void kernel_launch(void* const* d_in, const int* in_sizes, int n_in,
                              void* d_out, int out_size, void* d_ws, size_t ws_size,
                              hipStream_t stream) {
    const float* p_static = (const float*)d_in[0];
    const float* p_dyn    = (const float*)d_in[1];
    const float* p_lat    = (const float*)d_in[2];
    const float* p_lon    = (const float*)d_in[3];
    const float* p_all    = (const float*)d_in[4];
    const float* p_coords = (const float*)d_in[5];
    const float* p_Wst    = (const float*)d_in[6];
    const float* p_bst    = (const float*)d_in[7];
    const float* p_gst    = (const float*)d_in[8];
    const float* p_best   = (const float*)d_in[9];
    const float* p_Wdy    = (const float*)d_in[10];
    const float* p_bdy    = (const float*)d_in[11];
    const float* p_gdy    = (const float*)d_in[12];
    const float* p_bedy   = (const float*)d_in[13];
    const float* p_Wqkv   = (const float*)d_in[14];
    const float* p_bqkv   = (const float*)d_in[15];
    const float* p_Wo     = (const float*)d_in[16];
    const float* p_bo     = (const float*)d_in[17];
    const float* p_gln1   = (const float*)d_in[18];
    const float* p_beln1  = (const float*)d_in[19];
    const float* p_Wf1    = (const float*)d_in[20];
    const float* p_bf1    = (const float*)d_in[21];
    const float* p_Wf2    = (const float*)d_in[22];
    const float* p_bf2    = (const float*)d_in[23];
    const float* p_gln2   = (const float*)d_in[24];
    const float* p_beln2  = (const float*)d_in[25];
    const float* p_Wo1    = (const float*)d_in[26];
    const float* p_bo1    = (const float*)d_in[27];
    const float* p_Wo2    = (const float*)d_in[28];
    const float* p_bo2    = (const float*)d_in[29];
    const float* p_scale  = (const float*)d_in[30];
    const float* p_shift  = (const float*)d_in[31];
    float* out = (float*)d_out;
    (void)in_sizes; (void)n_in; (void)out_size;

    char* ws = (char*)d_ws;
    size_t off = 0;
    auto alloc = [&](size_t bytes) -> void* {
        void* p = ws + off;
        off += (bytes + 255) & ~(size_t)255;
        return p;
    };
    const int ROWS = BATCH * T_SEQ; // 93440 (%32 == 0)
    int*    nbr   = (int*)   alloc((size_t)BATCH*KNB*sizeof(int));
    float*  sfeat = (float*) alloc((size_t)BATCH*HDIM*sizeof(float));
    ushort* xhi   = (ushort*)alloc((size_t)ROWS*HDIM*sizeof(ushort));
    ushort* xlo   = (ushort*)alloc((size_t)ROWS*HDIM*sizeof(ushort));
    const size_t SZ_QKV = (size_t)4*768*256, SZ_O = (size_t)4*256*256;
    const size_t SZ_F1  = (size_t)4*1024*256, SZ_F2 = (size_t)4*256*1024;
    ushort* Wqkvt_h = (ushort*)alloc(SZ_QKV*2*sizeof(ushort)); ushort* Wqkvt_l = Wqkvt_h + SZ_QKV;
    ushort* Wot_h   = (ushort*)alloc(SZ_O  *2*sizeof(ushort)); ushort* Wot_l   = Wot_h   + SZ_O;
    ushort* Wf1t_h  = (ushort*)alloc(SZ_F1 *2*sizeof(ushort)); ushort* Wf1t_l  = Wf1t_h  + SZ_F1;
    ushort* Wf2t_h  = (ushort*)alloc(SZ_F2 *2*sizeof(ushort)); ushort* Wf2t_l  = Wf2t_h  + SZ_F2;
    size_t fixed = off;

    // per-chunk: union(qkv f32: RW*768*4B, hbuf hi/lo FT: RW*1024*4B) + aatt
    // hi/lo FT (RW*256*4B). CH must keep RW%32==0 -> CH in {256,128,64,32}.
    const size_t PER_B = (size_t)T_SEQ * 1024 * 4;
    const size_t PER_A = (size_t)T_SEQ * 256 * 4;
    const size_t PER_CH = PER_B + PER_A;
    int CH = 32;
    {
        const int tiers[3] = {256, 128, 64};
        for (int i = 0; i < 3; ++i) {
            if (fixed + (size_t)tiers[i]*PER_CH + 8192 <= ws_size) { CH = tiers[i]; break; }
        }
    }
    char*   big    = (char*)alloc((size_t)CH * PER_B);
    ushort* aatt_h = (ushort*)alloc((size_t)CH * PER_A);
    const int RW = CH * T_SEQ;
    ushort* aatt_l = aatt_h + (size_t)RW * HDIM;
    float*  qkv    = (float*)big;
    ushort* hbuf_h = (ushort*)big;
    ushort* hbuf_l = hbuf_h + (size_t)RW * FFDIM;
    const int GY = (RW + 127) / 128;   // guarded M-tiles

    topk_kernel <<<BATCH, 256, 0, stream>>>(p_lat, p_lon, p_coords, nbr);
    sfeat_kernel<<<BATCH, 256, 0, stream>>>(p_static, p_all, nbr, p_Wst, p_bst, p_gst, p_best, sfeat);
    dyn_kernel  <<<ROWS, 256, 0, stream>>>(p_dyn, p_Wdy, p_bdy, p_gdy, p_bedy, sfeat, xhi, xlo);
    tsplit_kernel<<<dim3(24, 8, 4), 256, 0, stream>>>(p_Wqkv, Wqkvt_h, Wqkvt_l, 256, 768);
    tsplit_kernel<<<dim3( 8, 8, 4), 256, 0, stream>>>(p_Wo,   Wot_h,   Wot_l,   256, 256);
    tsplit_kernel<<<dim3(32, 8, 4), 256, 0, stream>>>(p_Wf1,  Wf1t_h,  Wf1t_l,  256, 1024);
    tsplit_kernel<<<dim3( 8,32, 4), 256, 0, stream>>>(p_Wf2,  Wf2t_h,  Wf2t_l,  1024, 256);

    const int NCHUNK = BATCH / CH;
    for (int c = 0; c < NCHUNK; ++c) {
        size_t co = (size_t)c * CH * T_SEQ * HDIM;
        ushort* xhic = xhi + co;
        ushort* xloc = xlo + co;
        for (int l = 0; l < 4; ++l) {
            gemm_mfma<0,0,0><<<dim3(6, GY), 256, 0, stream>>>(
                xhic, xloc, Wqkvt_h + (size_t)l*768*256, Wqkvt_l + (size_t)l*768*256,
                p_bqkv + l*768, nullptr, nullptr, qkv, nullptr, nullptr, RW, 768, 256);
            attn_kernel<<<CH*NHEADS, 512, 0, stream>>>(qkv, aatt_h, aatt_l);
            gemm_mfma<0,1,1><<<dim3(2, GY), 256, 0, stream>>>(
                aatt_h, aatt_l, Wot_h + (size_t)l*256*256, Wot_l + (size_t)l*256*256,
                p_bo + l*256, xhic, xloc, nullptr, xhic, xloc, RW, 256, 256);
            ln2_kernel<<<RW/4, 256, 0, stream>>>(xhic, xloc, p_gln1 + l*256, p_beln1 + l*256);
            gemm_mfma<1,0,1><<<dim3(8, GY), 256, 0, stream>>>(
                xhic, xloc, Wf1t_h + (size_t)l*1024*256, Wf1t_l + (size_t)l*1024*256,
                p_bf1 + l*1024, nullptr, nullptr, nullptr, hbuf_h, hbuf_l, RW, 1024, 256);
            gemm_mfma<0,1,1><<<dim3(2, GY), 256, 0, stream>>>(
                hbuf_h, hbuf_l, Wf2t_h + (size_t)l*256*1024, Wf2t_l + (size_t)l*256*1024,
                p_bf2 + l*256, xhic, xloc, nullptr, xhic, xloc, RW, 256, 1024);
            ln2_kernel<<<RW/4, 256, 0, stream>>>(xhic, xloc, p_gln2 + l*256, p_beln2 + l*256);
        }
    }
    head_kernel<<<BATCH, 256, 0, stream>>>(xhi, xlo, sfeat, p_Wo1, p_bo1, p_Wo2, p_bo2, p_scale, p_shift, out);
}

// Round 7
// 6322.706 us; speedup vs baseline: 7.4063x; 1.3592x over previous
//
#include <hip/hip_runtime.h>
#include <math.h>

#define T_SEQ 365
#define HDIM 256
#define NHEADS 8
#define HD 32
#define BATCH 256
#define DDIM 16
#define FFDIM 1024
#define NST 10000
#define KNB 5
#define SDIM 64

typedef __bf16 bf16x8 __attribute__((ext_vector_type(8)));
typedef float  f32x16 __attribute__((ext_vector_type(16)));
typedef unsigned short u16x8 __attribute__((ext_vector_type(8)));

__device__ __forceinline__ ushort f2b_hi(float v) {
    unsigned u = __float_as_uint(v);
    unsigned r = u + 0x7fffu + ((u >> 16) & 1u);
    return (ushort)(r >> 16);
}
__device__ __forceinline__ float b2f(ushort h) {
    return __uint_as_float(((unsigned)h) << 16);
}
__device__ __forceinline__ ushort f2b_lo(float v, ushort hi) {
    return f2b_hi(v - b2f(hi));
}

__device__ __forceinline__ float gelu_f(float x) {
    return 0.5f * x * (1.f + erff(x * 0.70710678118654752f));
}

// FT (fragment-tiled) layout for a [R][C] bf16 matrix, C%8==0, R%32==0:
// offset(r,c) = ((r>>5)*(C>>3) + (c>>3))*256 + (r&31)*8 + (c&7)
// A wave's MFMA fragment (32 rows x 8 k) is one contiguous 512-ushort run.
// Per-(b,h) attention buffers: Q,K = FT over [384 tok][32 d] (12288 ushorts);
// V^T = FT over [32 d][384 tok]: offset(d,tok) = (tok>>3)*256 + d*8 + (tok&7).

// block-wide (256 threads = 4 waves) sum; sred must be float[4] shared
__device__ __forceinline__ float block_sum256(float v, float* sred) {
    #pragma unroll
    for (int off = 32; off; off >>= 1) v += __shfl_xor(v, off);
    int wave = threadIdx.x >> 6;
    if ((threadIdx.x & 63) == 0) sred[wave] = v;
    __syncthreads();
    float s = sred[0] + sred[1] + sred[2] + sred[3];
    __syncthreads();
    return s;
}

// ---------------- top-K neighbor search ----------------
__global__ __launch_bounds__(256) void topk_kernel(
    const float* __restrict__ lat, const float* __restrict__ lon,
    const float* __restrict__ coords, int* __restrict__ nbr)
{
    __shared__ float hav[NST];
    __shared__ float rv[256];
    __shared__ int   ri[256];
    const float DEG = 0.017453292519943295f;
    int b = blockIdx.x, t = threadIdx.x;
    float lat_o = (lat[b] + 1.f) * 0.5f * 25.f + 24.f;
    float lon_o = (lon[b] + 1.f) * 0.5f * 58.5f - 125.f;
    float qlat = lat_o * DEG, qlon = lon_o * DEG;
    float cq = cosf(qlat);
    for (int i = t; i < NST; i += 256) {
        float slat = coords[2*i], slon = coords[2*i+1];
        float dlat = qlat - slat, dlon = qlon - slon;
        float s1 = sinf(dlat * 0.5f), s2 = sinf(dlon * 0.5f);
        hav[i] = s1*s1 + cq * cosf(slat) * s2*s2;
    }
    __syncthreads();
    for (int sel = 0; sel < KNB + 1; ++sel) {
        float bv = 1e30f; int bi = 0x7fffffff;
        for (int i = t; i < NST; i += 256) {
            float v = hav[i];
            if (v < bv || (v == bv && i < bi)) { bv = v; bi = i; }
        }
        rv[t] = bv; ri[t] = bi;
        __syncthreads();
        for (int s = 128; s > 0; s >>= 1) {
            if (t < s) {
                float ov = rv[t+s]; int oi = ri[t+s];
                if (ov < rv[t] || (ov == rv[t] && oi < ri[t])) { rv[t] = ov; ri[t] = oi; }
            }
            __syncthreads();
        }
        if (t == 0) {
            if (sel > 0) nbr[b*KNB + sel - 1] = ri[0];
            hav[ri[0]] = 1e30f;   // mask winner
        }
        __syncthreads();
    }
}

// ---------------- static-feature branch ----------------
__global__ __launch_bounds__(256) void sfeat_kernel(
    const float* __restrict__ stat, const float* __restrict__ all_st,
    const int* __restrict__ nbr, const float* __restrict__ W,
    const float* __restrict__ bias, const float* __restrict__ g,
    const float* __restrict__ be, float* __restrict__ sfeat)
{
    __shared__ float comb[(KNB+1)*SDIM]; // 384
    __shared__ float sred[4];
    int b = blockIdx.x, t = threadIdx.x;
    for (int i = t; i < (KNB+1)*SDIM; i += 256) {
        if (i < SDIM) comb[i] = stat[b*SDIM + i];
        else {
            int n = (i - SDIM) >> 6, d = (i - SDIM) & 63;
            comb[i] = all_st[(size_t)nbr[b*KNB + n] * SDIM + d];
        }
    }
    __syncthreads();
    float acc = bias[t];
    for (int j = 0; j < (KNB+1)*SDIM; ++j)
        acc = fmaf(comb[j], W[j*HDIM + t], acc);
    float mu  = block_sum256(acc, sred) * (1.f/256.f);
    float d   = acc - mu;
    float var = block_sum256(d*d, sred) * (1.f/256.f);
    float y = g[t] * d * rsqrtf(var + 1e-5f) + be[t];
    sfeat[(size_t)b*HDIM + t] = gelu_f(y);
}

// ------ dynamic embedding (writes residual stream hi/lo in FT layout) ------
__global__ __launch_bounds__(256) void dyn_kernel(
    const float* __restrict__ dynv, const float* __restrict__ W,
    const float* __restrict__ bias, const float* __restrict__ g,
    const float* __restrict__ be, const float* __restrict__ sfeat,
    ushort* __restrict__ xhi, ushort* __restrict__ xlo)
{
    __shared__ float w[DDIM*HDIM];
    __shared__ float drow[DDIM];
    __shared__ float sred[4];
    int row = blockIdx.x, t = threadIdx.x;
    int b = row / T_SEQ;
    for (int i = t; i < DDIM*HDIM; i += 256) w[i] = W[i];
    if (t < DDIM) drow[t] = dynv[(size_t)row*DDIM + t];
    __syncthreads();
    float acc = bias[t];
    #pragma unroll
    for (int j = 0; j < DDIM; ++j) acc = fmaf(drow[j], w[j*HDIM + t], acc);
    float mu  = block_sum256(acc, sred) * (1.f/256.f);
    float d   = acc - mu;
    float var = block_sum256(d*d, sred) * (1.f/256.f);
    float y = g[t] * d * rsqrtf(var + 1e-5f) + be[t];
    float val = gelu_f(y) + sfeat[(size_t)b*HDIM + t];
    size_t o = ((size_t)(row >> 5) * 32 + (t >> 3)) * 256 + ((row & 31) << 3) + (t & 7);
    ushort hh = f2b_hi(val);
    xhi[o] = hh;
    xlo[o] = f2b_lo(val, hh);
}

// --- weight transpose + split: W[L][K][N] -> FT([N][K]) hi/lo per layer ---
__global__ __launch_bounds__(256) void tsplit_kernel(
    const float* __restrict__ W, ushort* __restrict__ hi, ushort* __restrict__ lo,
    int K, int N)
{
    __shared__ float tile[32][33];
    size_t l = blockIdx.z;
    const float* Wl = W + l*(size_t)K*N;
    ushort* hil = hi + l*(size_t)K*N;
    ushort* lol = lo + l*(size_t)K*N;
    int n0 = blockIdx.x*32, k0 = blockIdx.y*32;
    int tx = threadIdx.x & 31, ty = threadIdx.x >> 5;
    int KB = K >> 3;
    for (int i = ty; i < 32; i += 8) tile[i][tx] = Wl[(size_t)(k0+i)*N + n0 + tx];
    __syncthreads();
    for (int i = ty; i < 32; i += 8) {
        float v = tile[tx][i];              // (k=k0+tx, n=n0+i)
        ushort h = f2b_hi(v);
        size_t o = ((size_t)(n0 >> 5) * KB + (k0 >> 3) + (tx >> 3)) * 256
                 + ((size_t)i << 3) + (tx & 7);
        hil[o] = h;
        lol[o] = f2b_lo(v, h);
    }
}

// ---------------- split-bf16 MFMA GEMM, FT operands, no LDS ----------------
// OUT=1: write FT hi/lo (Chi/Clo). OUT=2: scatter Q/K/V into per-(b,h)
// attention layouts (Q,K: FT [384][32]; V: transposed FT [32][384]).
template<int DO_RELU, int DO_ADD, int OUT>
__global__ __launch_bounds__(256) void gemm_mfma(
    const ushort* __restrict__ Ahi, const ushort* __restrict__ Alo,
    const ushort* __restrict__ Bhi, const ushort* __restrict__ Blo,
    const float* __restrict__ bias,
    const ushort* __restrict__ Addhi, const ushort* __restrict__ Addlo,
    ushort* __restrict__ Chi, ushort* __restrict__ Clo,
    ushort* __restrict__ Wq_h, ushort* __restrict__ Wq_l,
    ushort* __restrict__ Wk_h, ushort* __restrict__ Wk_l,
    ushort* __restrict__ Wv_h, ushort* __restrict__ Wv_l,
    int M, int N, int K)
{
    const int t = threadIdx.x;
    const int lane = t & 63, wave = t >> 6;
    const int wr = wave >> 1, wc = wave & 1;
    const int lr = lane & 31, kg = lane >> 5;
    const int row_b = blockIdx.y * 128 + wr * 64;
    const int col_b = blockIdx.x * 128 + wc * 64;
    const int KB = K >> 3;

    const ushort *pAh[2], *pAl[2], *pBh[2], *pBl[2];
    #pragma unroll
    for (int mi = 0; mi < 2; ++mi) {
        int rb = row_b + mi*32; if (rb > M - 32) rb = M - 32;   // loads clamped
        size_t base = ((size_t)(rb >> 5) * KB + kg) * 256 + lr * 8;
        pAh[mi] = Ahi + base; pAl[mi] = Alo + base;
    }
    #pragma unroll
    for (int nj = 0; nj < 2; ++nj) {
        size_t base = ((size_t)((col_b + nj*32) >> 5) * KB + kg) * 256 + lr * 8;
        pBh[nj] = Bhi + base; pBl[nj] = Blo + base;
    }

    f32x16 acc[2][2];
    #pragma unroll
    for (int i = 0; i < 2; ++i)
        #pragma unroll
        for (int j = 0; j < 2; ++j)
            #pragma unroll
            for (int r = 0; r < 16; ++r) acc[i][j][r] = 0.f;

    bf16x8 a0h[2], a0l[2], b0h[2], b0l[2];
    bf16x8 a1h[2], a1l[2], b1h[2], b1l[2];

#define LOADF(AH, AL, BH, BL, OFF) do {                                        \
    _Pragma("unroll") for (int mi = 0; mi < 2; ++mi) {                         \
        AH[mi] = *reinterpret_cast<const bf16x8*>(pAh[mi] + (OFF));            \
        AL[mi] = *reinterpret_cast<const bf16x8*>(pAl[mi] + (OFF)); }          \
    _Pragma("unroll") for (int nj = 0; nj < 2; ++nj) {                         \
        BH[nj] = *reinterpret_cast<const bf16x8*>(pBh[nj] + (OFF));            \
        BL[nj] = *reinterpret_cast<const bf16x8*>(pBl[nj] + (OFF)); } } while(0)

#define MFMAF(AH, AL, BH, BL) do {                                             \
    _Pragma("unroll") for (int mi = 0; mi < 2; ++mi)                           \
    _Pragma("unroll") for (int nj = 0; nj < 2; ++nj) {                         \
        acc[mi][nj] = __builtin_amdgcn_mfma_f32_32x32x16_bf16(                 \
            AH[mi], BH[nj], acc[mi][nj], 0, 0, 0);                             \
        acc[mi][nj] = __builtin_amdgcn_mfma_f32_32x32x16_bf16(                 \
            AH[mi], BL[nj], acc[mi][nj], 0, 0, 0);                             \
        acc[mi][nj] = __builtin_amdgcn_mfma_f32_32x32x16_bf16(                 \
            AL[mi], BH[nj], acc[mi][nj], 0, 0, 0); } } while(0)

    LOADF(a0h, a0l, b0h, b0l, 0);
    for (int k0 = 0; k0 < K; k0 += 32) {
        size_t o1 = (size_t)((k0 + 16) >> 3) * 256;
        LOADF(a1h, a1l, b1h, b1l, o1);
        MFMAF(a0h, a0l, b0h, b0l);
        size_t o2 = (k0 + 32 < K) ? (size_t)((k0 + 32) >> 3) * 256 : 0;
        LOADF(a0h, a0l, b0h, b0l, o2);       // last iteration: harmless reload
        MFMAF(a1h, a1l, b1h, b1l);
    }
#undef LOADF
#undef MFMAF

    // epilogue: C/D map: col = lane&31, row31 = (r&3)+8*(r>>2)+4*kg
    #pragma unroll
    for (int mi = 0; mi < 2; ++mi) {
        int rb2 = row_b + mi*32;
        #pragma unroll
        for (int nj = 0; nj < 2; ++nj) {
            int colf = col_b + nj*32 + lr;
            float bv = bias[colf];
            if (OUT == 1) {
                size_t ftb = ((size_t)(rb2 >> 5) * (N >> 3) + (colf >> 3)) * 256 + (colf & 7);
                #pragma unroll
                for (int r = 0; r < 16; ++r) {
                    int r31 = (r & 3) + 8*(r >> 2) + 4*kg;
                    int row = rb2 + r31;
                    if (row >= M) continue;
                    float v = acc[mi][nj][r] + bv;
                    if (DO_RELU) v = fmaxf(v, 0.f);
                    size_t oo = ftb + (size_t)r31 * 8;
                    if (DO_ADD) v += b2f(Addhi[oo]) + b2f(Addlo[oo]);
                    ushort hh = f2b_hi(v);
                    Chi[oo] = hh;
                    Clo[oo] = f2b_lo(v, hh);
                }
            } else {
                int sel = (col_b + nj*32) >> 8;   // 0=Q,1=K,2=V (tile-uniform)
                int h = (colf >> 5) & 7;
                int d = colf & 31;
                #pragma unroll
                for (int r = 0; r < 16; ++r) {
                    int r31 = (r & 3) + 8*(r >> 2) + 4*kg;
                    int row = rb2 + r31;
                    if (row >= M) continue;
                    float v = acc[mi][nj][r] + bv;
                    int bl = row / T_SEQ;
                    int tok = row - bl * T_SEQ;
                    size_t bb = (size_t)(bl*8 + h) * 12288;
                    ushort hh = f2b_hi(v);
                    ushort ll = f2b_lo(v, hh);
                    if (sel == 0) {
                        size_t o = bb + (size_t)((tok >> 5)*4 + (d >> 3))*256
                                 + ((tok & 31) << 3) + (d & 7);
                        Wq_h[o] = hh; Wq_l[o] = ll;
                    } else if (sel == 1) {
                        size_t o = bb + (size_t)((tok >> 5)*4 + (d >> 3))*256
                                 + ((tok & 31) << 3) + (d & 7);
                        Wk_h[o] = hh; Wk_l[o] = ll;
                    } else {
                        size_t o = bb + (size_t)(tok >> 3)*256 + d*8 + (tok & 7);
                        Wv_h[o] = hh; Wv_l[o] = ll;
                    }
                }
            }
        }
    }
}

// ---------------- MFMA attention: 1 wave per (b,h,q-tile) ----------------
// Swapped QK^T (A=K, B=Q) => per-lane q-column stats; 2-pass softmax;
// split-bf16 P; PV with V^T B-operand. No LDS, no barriers.
__global__ __launch_bounds__(256) void attn_mfma(
    const ushort* __restrict__ Qh, const ushort* __restrict__ Ql,
    const ushort* __restrict__ Kh, const ushort* __restrict__ Kl,
    const ushort* __restrict__ Vh, const ushort* __restrict__ Vl,
    ushort* __restrict__ ahi, ushort* __restrict__ alo)
{
    const int bh = blockIdx.y;
    const int wave = threadIdx.x >> 6, lane = threadIdx.x & 63;
    const int qt = blockIdx.x * 4 + wave;   // 0..11
    const int lr = lane & 31, kg = lane >> 5;
    const size_t base = (size_t)bh * 12288;
    const float scale = 0.17677669529663687f; // 1/sqrt(32)

    // Q B-fragments for the two d-ksteps
    bf16x8 qfh[2], qfl[2];
    #pragma unroll
    for (int ks = 0; ks < 2; ++ks) {
        size_t o = base + (size_t)(qt*4 + ks*2 + kg)*256 + lr*8;
        qfh[ks] = *reinterpret_cast<const bf16x8*>(Qh + o);
        qfl[ks] = *reinterpret_cast<const bf16x8*>(Ql + o);
    }

    // ---- pass 1: per-q max (lane-local via swapped S^T) ----
    float m = -3e38f;
    for (int kt = 0; kt < 12; ++kt) {
        f32x16 st;
        #pragma unroll
        for (int r = 0; r < 16; ++r) st[r] = 0.f;
        #pragma unroll
        for (int ks = 0; ks < 2; ++ks) {
            size_t o = base + (size_t)(kt*4 + ks*2 + kg)*256 + lr*8;
            bf16x8 kfh = *reinterpret_cast<const bf16x8*>(Kh + o);
            bf16x8 kfl = *reinterpret_cast<const bf16x8*>(Kl + o);
            st = __builtin_amdgcn_mfma_f32_32x32x16_bf16(kfh, qfh[ks], st, 0,0,0);
            st = __builtin_amdgcn_mfma_f32_32x32x16_bf16(kfh, qfl[ks], st, 0,0,0);
            st = __builtin_amdgcn_mfma_f32_32x32x16_bf16(kfl, qfh[ks], st, 0,0,0);
        }
        #pragma unroll
        for (int r = 0; r < 16; ++r) {
            int krow = kt*32 + (r & 3) + 8*(r >> 2) + 4*kg;
            m = fmaxf(m, (krow < T_SEQ) ? st[r] : -3e38f);
        }
    }
    m = fmaxf(m, __shfl_xor(m, 32));

    // ---- pass 2: recompute S, exp, split-P, PV ----
    f32x16 oacc;
    #pragma unroll
    for (int r = 0; r < 16; ++r) oacc[r] = 0.f;
    float l = 0.f;

    for (int kt = 0; kt < 12; ++kt) {
        f32x16 st;
        #pragma unroll
        for (int r = 0; r < 16; ++r) st[r] = 0.f;
        #pragma unroll
        for (int ks = 0; ks < 2; ++ks) {
            size_t o = base + (size_t)(kt*4 + ks*2 + kg)*256 + lr*8;
            bf16x8 kfh = *reinterpret_cast<const bf16x8*>(Kh + o);
            bf16x8 kfl = *reinterpret_cast<const bf16x8*>(Kl + o);
            st = __builtin_amdgcn_mfma_f32_32x32x16_bf16(kfh, qfh[ks], st, 0,0,0);
            st = __builtin_amdgcn_mfma_f32_32x32x16_bf16(kfh, qfl[ks], st, 0,0,0);
            st = __builtin_amdgcn_mfma_f32_32x32x16_bf16(kfl, qfh[ks], st, 0,0,0);
        }
        float p[16];
        #pragma unroll
        for (int r = 0; r < 16; ++r) {
            int krow = kt*32 + (r & 3) + 8*(r >> 2) + 4*kg;
            float sv = (krow < T_SEQ) ? st[r] : -3e38f;
            float e = __expf((sv - m) * scale);
            p[r] = e; l += e;
        }
        float pp[16];
        #pragma unroll
        for (int r = 0; r < 16; ++r) pp[r] = __shfl_xor(p[r], 32);
        #pragma unroll
        for (int ks = 0; ks < 2; ++ks) {
            union { u16x8 u; bf16x8 b; } fh, fl;
            #pragma unroll
            for (int j = 0; j < 8; ++j) {
                float e;
                if (ks == 0)
                    e = kg ? ((j < 4) ? pp[4+j] : p[j])
                           : ((j < 4) ? p[j]    : pp[j-4]);
                else
                    e = kg ? ((j < 4) ? pp[12+j] : p[8+j])
                           : ((j < 4) ? p[8+j]   : pp[4+j]);
                ushort hh = f2b_hi(e);
                fh.u[j] = hh;
                fl.u[j] = f2b_lo(e, hh);
            }
            size_t vo = base + (size_t)(kt*4 + ks*2 + kg)*256 + lr*8;
            bf16x8 vfh = *reinterpret_cast<const bf16x8*>(Vh + vo);
            bf16x8 vfl = *reinterpret_cast<const bf16x8*>(Vl + vo);
            oacc = __builtin_amdgcn_mfma_f32_32x32x16_bf16(fh.b, vfh, oacc, 0,0,0);
            oacc = __builtin_amdgcn_mfma_f32_32x32x16_bf16(fh.b, vfl, oacc, 0,0,0);
            oacc = __builtin_amdgcn_mfma_f32_32x32x16_bf16(fl.b, vfh, oacc, 0,0,0);
        }
    }
    l += __shfl_xor(l, 32);
    float il = 1.f / l;

    const int bl = bh >> 3, h = bh & 7;
    #pragma unroll
    for (int r = 0; r < 16; ++r) {
        int q = (r & 3) + 8*(r >> 2) + 4*kg;
        float sc = __shfl(il, q);
        int row_local = qt*32 + q;
        if (row_local < T_SEQ) {
            float v = oacc[r] * sc;
            int grow = bl*T_SEQ + row_local;
            int col = h*32 + lr;
            size_t o = ((size_t)(grow >> 5)*32 + (col >> 3))*256
                     + ((grow & 31) << 3) + (col & 7);
            ushort hh = f2b_hi(v);
            ahi[o] = hh;
            alo[o] = f2b_lo(v, hh);
        }
    }
}

// ---- LN in place on FT hi/lo residual stream, wave-per-row (4 rows/blk) ----
__global__ __launch_bounds__(256) void ln2_kernel(
    ushort* __restrict__ xhi, ushort* __restrict__ xlo,
    const float* __restrict__ g, const float* __restrict__ be)
{
    int wave = threadIdx.x >> 6, lane = threadIdx.x & 63;
    size_t row = (size_t)blockIdx.x * 4 + wave;
    size_t o = ((row >> 5) * 32 + (lane >> 1)) * 256 + ((row & 31) << 3) + ((lane & 1) << 2);
    ushort4 h4 = *reinterpret_cast<const ushort4*>(&xhi[o]);
    ushort4 l4 = *reinterpret_cast<const ushort4*>(&xlo[o]);
    float4 v = make_float4(b2f(h4.x)+b2f(l4.x), b2f(h4.y)+b2f(l4.y),
                           b2f(h4.z)+b2f(l4.z), b2f(h4.w)+b2f(l4.w));
    float s = v.x + v.y + v.z + v.w;
    #pragma unroll
    for (int off = 32; off; off >>= 1) s += __shfl_xor(s, off);
    float mu = s * (1.f/256.f);
    float4 d = make_float4(v.x-mu, v.y-mu, v.z-mu, v.w-mu);
    float s2 = d.x*d.x + d.y*d.y + d.z*d.z + d.w*d.w;
    #pragma unroll
    for (int off = 32; off; off >>= 1) s2 += __shfl_xor(s2, off);
    float rs = rsqrtf(s2 * (1.f/256.f) + 1e-5f);
    float4 gg = *reinterpret_cast<const float4*>(&g[lane*4]);
    float4 bb = *reinterpret_cast<const float4*>(&be[lane*4]);
    float4 ov;
    ov.x = gg.x * d.x * rs + bb.x;
    ov.y = gg.y * d.y * rs + bb.y;
    ov.z = gg.z * d.z * rs + bb.z;
    ov.w = gg.w * d.w * rs + bb.w;
    ushort4 hv, lv;
    hv.x = f2b_hi(ov.x); lv.x = f2b_lo(ov.x, hv.x);
    hv.y = f2b_hi(ov.y); lv.y = f2b_lo(ov.y, hv.y);
    hv.z = f2b_hi(ov.z); lv.z = f2b_lo(ov.z, hv.z);
    hv.w = f2b_hi(ov.w); lv.w = f2b_lo(ov.w, hv.w);
    *reinterpret_cast<ushort4*>(&xhi[o]) = hv;
    *reinterpret_cast<ushort4*>(&xlo[o]) = lv;
}

// -------- mean-pool + output head (reads FT hi/lo stream) --------
__global__ __launch_bounds__(256) void head_kernel(
    const ushort* __restrict__ xhi, const ushort* __restrict__ xlo,
    const float* __restrict__ sfeat,
    const float* __restrict__ W1, const float* __restrict__ b1,
    const float* __restrict__ W2, const float* __restrict__ b2,
    const float* __restrict__ scale, const float* __restrict__ shift,
    float* __restrict__ out)
{
    __shared__ float p[HDIM];
    __shared__ float h1[HDIM/2];
    int b = blockIdx.x, t = threadIdx.x;
    float acc = 0.f;
    for (int tt = 0; tt < T_SEQ; ++tt) {
        size_t row = (size_t)b*T_SEQ + tt;
        size_t o = ((row >> 5) * 32 + (t >> 3)) * 256 + ((row & 31) << 3) + (t & 7);
        acc += b2f(xhi[o]) + b2f(xlo[o]);
    }
    p[t] = acc * (1.f/365.f) + sfeat[(size_t)b*HDIM + t];
    __syncthreads();
    if (t < HDIM/2) {
        float a = b1[t];
        for (int c = 0; c < HDIM; ++c) a = fmaf(p[c], W1[c*(HDIM/2) + t], a);
        h1[t] = gelu_f(a);
    }
    __syncthreads();
    if (t < 30) {
        float a = b2[t];
        for (int j = 0; j < HDIM/2; ++j) a = fmaf(h1[j], W2[j*30 + t], a);
        out[b*30 + t] = tanhf(a) * scale[0] + shift[0];
    }
}

extern "C" void kernel_launch(void* const* d_in, const int* in_sizes, int n_in,
                              void* d_out, int out_size, void* d_ws, size_t ws_size,
                              hipStream_t stream) {
    const float* p_static = (const float*)d_in[0];
    const float* p_dyn    = (const float*)d_in[1];
    const float* p_lat    = (const float*)d_in[2];
    const float* p_lon    = (const float*)d_in[3];
    const float* p_all    = (const float*)d_in[4];
    const float* p_coords = (const float*)d_in[5];
    const float* p_Wst    = (const float*)d_in[6];
    const float* p_bst    = (const float*)d_in[7];
    const float* p_gst    = (const float*)d_in[8];
    const float* p_best   = (const float*)d_in[9];
    const float* p_Wdy    = (const float*)d_in[10];
    const float* p_bdy    = (const float*)d_in[11];
    const float* p_gdy    = (const float*)d_in[12];
    const float* p_bedy   = (const float*)d_in[13];
    const float* p_Wqkv   = (const float*)d_in[14];
    const float* p_bqkv   = (const float*)d_in[15];
    const float* p_Wo     = (const float*)d_in[16];
    const float* p_bo     = (const float*)d_in[17];
    const float* p_gln1   = (const float*)d_in[18];
    const float* p_beln1  = (const float*)d_in[19];
    const float* p_Wf1    = (const float*)d_in[20];
    const float* p_bf1    = (const float*)d_in[21];
    const float* p_Wf2    = (const float*)d_in[22];
    const float* p_bf2    = (const float*)d_in[23];
    const float* p_gln2   = (const float*)d_in[24];
    const float* p_beln2  = (const float*)d_in[25];
    const float* p_Wo1    = (const float*)d_in[26];
    const float* p_bo1    = (const float*)d_in[27];
    const float* p_Wo2    = (const float*)d_in[28];
    const float* p_bo2    = (const float*)d_in[29];
    const float* p_scale  = (const float*)d_in[30];
    const float* p_shift  = (const float*)d_in[31];
    float* out = (float*)d_out;
    (void)in_sizes; (void)n_in; (void)out_size;

    char* ws = (char*)d_ws;
    size_t off = 0;
    auto alloc = [&](size_t bytes) -> void* {
        void* p = ws + off;
        off += (bytes + 255) & ~(size_t)255;
        return p;
    };
    const int ROWS = BATCH * T_SEQ; // 93440 (%32 == 0)
    int*    nbr   = (int*)   alloc((size_t)BATCH*KNB*sizeof(int));
    float*  sfeat = (float*) alloc((size_t)BATCH*HDIM*sizeof(float));
    ushort* xhi   = (ushort*)alloc((size_t)ROWS*HDIM*sizeof(ushort));
    ushort* xlo   = (ushort*)alloc((size_t)ROWS*HDIM*sizeof(ushort));
    const size_t SZ_QKV = (size_t)4*768*256, SZ_O = (size_t)4*256*256;
    const size_t SZ_F1  = (size_t)4*1024*256, SZ_F2 = (size_t)4*256*1024;
    ushort* Wqkvt_h = (ushort*)alloc(SZ_QKV*2*sizeof(ushort)); ushort* Wqkvt_l = Wqkvt_h + SZ_QKV;
    ushort* Wot_h   = (ushort*)alloc(SZ_O  *2*sizeof(ushort)); ushort* Wot_l   = Wot_h   + SZ_O;
    ushort* Wf1t_h  = (ushort*)alloc(SZ_F1 *2*sizeof(ushort)); ushort* Wf1t_l  = Wf1t_h  + SZ_F1;
    ushort* Wf2t_h  = (ushort*)alloc(SZ_F2 *2*sizeof(ushort)); ushort* Wf2t_l  = Wf2t_h  + SZ_F2;
    size_t fixed = off;

    // per-chunk union region: QKV-split (6 x CH*8*12288 ushorts = CH*1,179,648 B)
    // during attention, OR hbuf hi/lo (CH*1,495,040 B) during FF. aatt separate.
    const size_t PER_B = (size_t)T_SEQ * 1024 * 4;   // 1,495,040
    const size_t PER_A = (size_t)T_SEQ * 256 * 4;    // aatt hi+lo
    const size_t PER_CH = PER_B + PER_A;
    int CH = 32;
    {
        const int tiers[3] = {256, 128, 64};
        for (int i = 0; i < 3; ++i) {
            if (fixed + (size_t)tiers[i]*PER_CH + 8192 <= ws_size) { CH = tiers[i]; break; }
        }
    }
    char*   big    = (char*)alloc((size_t)CH * PER_B);
    ushort* aatt_h = (ushort*)alloc((size_t)CH * PER_A);
    const int RW = CH * T_SEQ;
    ushort* aatt_l = aatt_h + (size_t)RW * HDIM;
    const size_t seg = (size_t)CH * 8 * 12288;       // ushorts per QKV buffer
    ushort* Qh  = (ushort*)big;
    ushort* Ql  = Qh  + seg;
    ushort* Kh2 = Ql  + seg;
    ushort* Kl2 = Kh2 + seg;
    ushort* Vth = Kl2 + seg;
    ushort* Vtl = Vth + seg;
    ushort* hbuf_h = (ushort*)big;
    ushort* hbuf_l = hbuf_h + (size_t)RW * FFDIM;
    const int GY = (RW + 127) / 128;   // guarded M-tiles

    topk_kernel <<<BATCH, 256, 0, stream>>>(p_lat, p_lon, p_coords, nbr);
    sfeat_kernel<<<BATCH, 256, 0, stream>>>(p_static, p_all, nbr, p_Wst, p_bst, p_gst, p_best, sfeat);
    dyn_kernel  <<<ROWS, 256, 0, stream>>>(p_dyn, p_Wdy, p_bdy, p_gdy, p_bedy, sfeat, xhi, xlo);
    tsplit_kernel<<<dim3(24, 8, 4), 256, 0, stream>>>(p_Wqkv, Wqkvt_h, Wqkvt_l, 256, 768);
    tsplit_kernel<<<dim3( 8, 8, 4), 256, 0, stream>>>(p_Wo,   Wot_h,   Wot_l,   256, 256);
    tsplit_kernel<<<dim3(32, 8, 4), 256, 0, stream>>>(p_Wf1,  Wf1t_h,  Wf1t_l,  256, 1024);
    tsplit_kernel<<<dim3( 8,32, 4), 256, 0, stream>>>(p_Wf2,  Wf2t_h,  Wf2t_l,  1024, 256);

    const int NCHUNK = BATCH / CH;
    for (int c = 0; c < NCHUNK; ++c) {
        size_t co = (size_t)c * CH * T_SEQ * HDIM;
        ushort* xhic = xhi + co;
        ushort* xloc = xlo + co;
        for (int l = 0; l < 4; ++l) {
            gemm_mfma<0,0,2><<<dim3(6, GY), 256, 0, stream>>>(
                xhic, xloc, Wqkvt_h + (size_t)l*768*256, Wqkvt_l + (size_t)l*768*256,
                p_bqkv + l*768, nullptr, nullptr, nullptr, nullptr,
                Qh, Ql, Kh2, Kl2, Vth, Vtl, RW, 768, 256);
            attn_mfma<<<dim3(3, CH*8), 256, 0, stream>>>(
                Qh, Ql, Kh2, Kl2, Vth, Vtl, aatt_h, aatt_l);
            gemm_mfma<0,1,1><<<dim3(2, GY), 256, 0, stream>>>(
                aatt_h, aatt_l, Wot_h + (size_t)l*256*256, Wot_l + (size_t)l*256*256,
                p_bo + l*256, xhic, xloc, xhic, xloc,
                nullptr, nullptr, nullptr, nullptr, nullptr, nullptr, RW, 256, 256);
            ln2_kernel<<<RW/4, 256, 0, stream>>>(xhic, xloc, p_gln1 + l*256, p_beln1 + l*256);
            gemm_mfma<1,0,1><<<dim3(8, GY), 256, 0, stream>>>(
                xhic, xloc, Wf1t_h + (size_t)l*1024*256, Wf1t_l + (size_t)l*1024*256,
                p_bf1 + l*1024, nullptr, nullptr, hbuf_h, hbuf_l,
                nullptr, nullptr, nullptr, nullptr, nullptr, nullptr, RW, 1024, 256);
            gemm_mfma<0,1,1><<<dim3(2, GY), 256, 0, stream>>>(
                hbuf_h, hbuf_l, Wf2t_h + (size_t)l*256*1024, Wf2t_l + (size_t)l*256*1024,
                p_bf2 + l*256, xhic, xloc, xhic, xloc,
                nullptr, nullptr, nullptr, nullptr, nullptr, nullptr, RW, 256, 1024);
            ln2_kernel<<<RW/4, 256, 0, stream>>>(xhic, xloc, p_gln2 + l*256, p_beln2 + l*256);
        }
    }
    head_kernel<<<BATCH, 256, 0, stream>>>(xhi, xlo, sfeat, p_Wo1, p_bo1, p_Wo2, p_bo2, p_scale, p_shift, out);
}

// Round 8
// 6210.432 us; speedup vs baseline: 7.5402x; 1.0181x over previous
//
#include <hip/hip_runtime.h>
#include <math.h>

#define T_SEQ 365
#define HDIM 256
#define NHEADS 8
#define HD 32
#define BATCH 256
#define DDIM 16
#define FFDIM 1024
#define NST 10000
#define KNB 5
#define SDIM 64

typedef __bf16 bf16x8 __attribute__((ext_vector_type(8)));
typedef float  f32x16 __attribute__((ext_vector_type(16)));
typedef unsigned short u16x8 __attribute__((ext_vector_type(8)));

__device__ __forceinline__ ushort f2b_hi(float v) {
    unsigned u = __float_as_uint(v);
    unsigned r = u + 0x7fffu + ((u >> 16) & 1u);
    return (ushort)(r >> 16);
}
__device__ __forceinline__ float b2f(ushort h) {
    return __uint_as_float(((unsigned)h) << 16);
}
__device__ __forceinline__ ushort f2b_lo(float v, ushort hi) {
    return f2b_hi(v - b2f(hi));
}

__device__ __forceinline__ float gelu_f(float x) {
    return 0.5f * x * (1.f + erff(x * 0.70710678118654752f));
}

// FT (fragment-tiled) layout for a [R][C] bf16 matrix, C%8==0:
// offset(r,c) = ((r>>5)*(C>>3) + (c>>3))*256 + (r&31)*8 + (c&7)
// A wave's MFMA fragment (32 rows x 8 k) is one contiguous 512-ushort run.
// Per-(b,h) attention buffers: Q,K = FT over [384 tok][32 d] (12288 ushorts);
// V^T = FT over [32 d][384 tok]: offset(d,tok) = (tok>>3)*256 + d*8 + (tok&7).

// block-wide (256 threads = 4 waves) sum; sred must be float[4] shared
__device__ __forceinline__ float block_sum256(float v, float* sred) {
    #pragma unroll
    for (int off = 32; off; off >>= 1) v += __shfl_xor(v, off);
    int wave = threadIdx.x >> 6;
    if ((threadIdx.x & 63) == 0) sred[wave] = v;
    __syncthreads();
    float s = sred[0] + sred[1] + sred[2] + sred[3];
    __syncthreads();
    return s;
}

// ---------------- top-K neighbor search ----------------
__global__ __launch_bounds__(256) void topk_kernel(
    const float* __restrict__ lat, const float* __restrict__ lon,
    const float* __restrict__ coords, int* __restrict__ nbr)
{
    __shared__ float hav[NST];
    __shared__ float rv[256];
    __shared__ int   ri[256];
    const float DEG = 0.017453292519943295f;
    int b = blockIdx.x, t = threadIdx.x;
    float lat_o = (lat[b] + 1.f) * 0.5f * 25.f + 24.f;
    float lon_o = (lon[b] + 1.f) * 0.5f * 58.5f - 125.f;
    float qlat = lat_o * DEG, qlon = lon_o * DEG;
    float cq = cosf(qlat);
    for (int i = t; i < NST; i += 256) {
        float slat = coords[2*i], slon = coords[2*i+1];
        float dlat = qlat - slat, dlon = qlon - slon;
        float s1 = sinf(dlat * 0.5f), s2 = sinf(dlon * 0.5f);
        hav[i] = s1*s1 + cq * cosf(slat) * s2*s2;
    }
    __syncthreads();
    for (int sel = 0; sel < KNB + 1; ++sel) {
        float bv = 1e30f; int bi = 0x7fffffff;
        for (int i = t; i < NST; i += 256) {
            float v = hav[i];
            if (v < bv || (v == bv && i < bi)) { bv = v; bi = i; }
        }
        rv[t] = bv; ri[t] = bi;
        __syncthreads();
        for (int s = 128; s > 0; s >>= 1) {
            if (t < s) {
                float ov = rv[t+s]; int oi = ri[t+s];
                if (ov < rv[t] || (ov == rv[t] && oi < ri[t])) { rv[t] = ov; ri[t] = oi; }
            }
            __syncthreads();
        }
        if (t == 0) {
            if (sel > 0) nbr[b*KNB + sel - 1] = ri[0];
            hav[ri[0]] = 1e30f;   // mask winner
        }
        __syncthreads();
    }
}

// ---------------- static-feature branch ----------------
__global__ __launch_bounds__(256) void sfeat_kernel(
    const float* __restrict__ stat, const float* __restrict__ all_st,
    const int* __restrict__ nbr, const float* __restrict__ W,
    const float* __restrict__ bias, const float* __restrict__ g,
    const float* __restrict__ be, float* __restrict__ sfeat)
{
    __shared__ float comb[(KNB+1)*SDIM]; // 384
    __shared__ float sred[4];
    int b = blockIdx.x, t = threadIdx.x;
    for (int i = t; i < (KNB+1)*SDIM; i += 256) {
        if (i < SDIM) comb[i] = stat[b*SDIM + i];
        else {
            int n = (i - SDIM) >> 6, d = (i - SDIM) & 63;
            comb[i] = all_st[(size_t)nbr[b*KNB + n] * SDIM + d];
        }
    }
    __syncthreads();
    float acc = bias[t];
    for (int j = 0; j < (KNB+1)*SDIM; ++j)
        acc = fmaf(comb[j], W[j*HDIM + t], acc);
    float mu  = block_sum256(acc, sred) * (1.f/256.f);
    float d   = acc - mu;
    float var = block_sum256(d*d, sred) * (1.f/256.f);
    float y = g[t] * d * rsqrtf(var + 1e-5f) + be[t];
    sfeat[(size_t)b*HDIM + t] = gelu_f(y);
}

// ------ dynamic embedding: 4 rows/block, wave per row, full-line FT writes ------
__global__ __launch_bounds__(256) void dyn_kernel(
    const float* __restrict__ dynv, const float* __restrict__ W,
    const float* __restrict__ bias, const float* __restrict__ g,
    const float* __restrict__ be, const float* __restrict__ sfeat,
    ushort* __restrict__ xhi, ushort* __restrict__ xlo)
{
    __shared__ float w[DDIM*HDIM];   // 16 KB
    __shared__ float dr[4][DDIM];
    int wave = threadIdx.x >> 6, lane = threadIdx.x & 63;
    int row0 = blockIdx.x * 4;
    for (int i = threadIdx.x; i < DDIM*HDIM; i += 256) w[i] = W[i];
    if (lane < DDIM)
        dr[wave][lane] = dynv[(size_t)(row0 + wave)*DDIM + lane];
    __syncthreads();
    int row = row0 + wave;
    int b = row / T_SEQ;
    int c0 = lane * 4;
    float v0 = bias[c0], v1 = bias[c0+1], v2 = bias[c0+2], v3 = bias[c0+3];
    #pragma unroll
    for (int k = 0; k < DDIM; ++k) {
        float dk = dr[wave][k];
        float4 wv = *reinterpret_cast<const float4*>(&w[k*HDIM + c0]);
        v0 = fmaf(dk, wv.x, v0); v1 = fmaf(dk, wv.y, v1);
        v2 = fmaf(dk, wv.z, v2); v3 = fmaf(dk, wv.w, v3);
    }
    float s = v0 + v1 + v2 + v3;
    #pragma unroll
    for (int off = 32; off; off >>= 1) s += __shfl_xor(s, off);
    float mu = s * (1.f/256.f);
    float d0 = v0-mu, d1 = v1-mu, d2 = v2-mu, d3 = v3-mu;
    float s2 = d0*d0 + d1*d1 + d2*d2 + d3*d3;
    #pragma unroll
    for (int off = 32; off; off >>= 1) s2 += __shfl_xor(s2, off);
    float rs = rsqrtf(s2 * (1.f/256.f) + 1e-5f);
    float4 gg = *reinterpret_cast<const float4*>(&g[c0]);
    float4 bb = *reinterpret_cast<const float4*>(&be[c0]);
    float4 sf = *reinterpret_cast<const float4*>(&sfeat[(size_t)b*HDIM + c0]);
    float o0 = gelu_f(gg.x*d0*rs + bb.x) + sf.x;
    float o1 = gelu_f(gg.y*d1*rs + bb.y) + sf.y;
    float o2 = gelu_f(gg.z*d2*rs + bb.z) + sf.z;
    float o3 = gelu_f(gg.w*d3*rs + bb.w) + sf.w;
    size_t o = ((size_t)(row >> 5) * 32 + (c0 >> 3)) * 256 + ((row & 31) << 3) + (c0 & 7);
    ushort4 hv, lv;
    hv.x = f2b_hi(o0); lv.x = f2b_lo(o0, hv.x);
    hv.y = f2b_hi(o1); lv.y = f2b_lo(o1, hv.y);
    hv.z = f2b_hi(o2); lv.z = f2b_lo(o2, hv.z);
    hv.w = f2b_hi(o3); lv.w = f2b_lo(o3, hv.w);
    *reinterpret_cast<ushort4*>(&xhi[o]) = hv;
    *reinterpret_cast<ushort4*>(&xlo[o]) = lv;
}

// --- weight transpose + split: W[L][K][N] -> FT([N][K]) hi/lo per layer ---
__global__ __launch_bounds__(256) void tsplit_kernel(
    const float* __restrict__ W, ushort* __restrict__ hi, ushort* __restrict__ lo,
    int K, int N)
{
    __shared__ float tile[32][33];
    size_t l = blockIdx.z;
    const float* Wl = W + l*(size_t)K*N;
    ushort* hil = hi + l*(size_t)K*N;
    ushort* lol = lo + l*(size_t)K*N;
    int n0 = blockIdx.x*32, k0 = blockIdx.y*32;
    int tx = threadIdx.x & 31, ty = threadIdx.x >> 5;
    int KB = K >> 3;
    for (int i = ty; i < 32; i += 8) tile[i][tx] = Wl[(size_t)(k0+i)*N + n0 + tx];
    __syncthreads();
    for (int i = ty; i < 32; i += 8) {
        float v = tile[tx][i];              // (k=k0+tx, n=n0+i)
        ushort h = f2b_hi(v);
        size_t o = ((size_t)(n0 >> 5) * KB + (k0 >> 3) + (tx >> 3)) * 256
                 + ((size_t)i << 3) + (tx & 7);
        hil[o] = h;
        lol[o] = f2b_lo(v, h);
    }
}

// ---------------- split-bf16 MFMA GEMM, FT operands, no LDS ----------------
// OUT=1: write FT hi/lo (Chi/Clo). OUT=2: scatter Q/K/V into per-(b,h)
// attention layouts (Q,K: FT [384][32]; V: transposed FT [32][384]).
template<int DO_RELU, int OUT>
__global__ __launch_bounds__(256) void gemm_mfma(
    const ushort* __restrict__ Ahi, const ushort* __restrict__ Alo,
    const ushort* __restrict__ Bhi, const ushort* __restrict__ Blo,
    const float* __restrict__ bias,
    ushort* __restrict__ Chi, ushort* __restrict__ Clo,
    ushort* __restrict__ Wq_h, ushort* __restrict__ Wq_l,
    ushort* __restrict__ Wk_h, ushort* __restrict__ Wk_l,
    ushort* __restrict__ Wv_h, ushort* __restrict__ Wv_l,
    int M, int N, int K)
{
    const int t = threadIdx.x;
    const int lane = t & 63, wave = t >> 6;
    const int wr = wave >> 1, wc = wave & 1;
    const int lr = lane & 31, kg = lane >> 5;
    const int row_b = blockIdx.y * 128 + wr * 64;
    const int col_b = blockIdx.x * 128 + wc * 64;
    const int KB = K >> 3;

    const ushort *pAh[2], *pAl[2], *pBh[2], *pBl[2];
    #pragma unroll
    for (int mi = 0; mi < 2; ++mi) {
        int rb = row_b + mi*32; if (rb > M - 32) rb = M - 32;   // loads clamped
        size_t base = ((size_t)(rb >> 5) * KB + kg) * 256 + lr * 8;
        pAh[mi] = Ahi + base; pAl[mi] = Alo + base;
    }
    #pragma unroll
    for (int nj = 0; nj < 2; ++nj) {
        size_t base = ((size_t)((col_b + nj*32) >> 5) * KB + kg) * 256 + lr * 8;
        pBh[nj] = Bhi + base; pBl[nj] = Blo + base;
    }

    f32x16 acc[2][2];
    #pragma unroll
    for (int i = 0; i < 2; ++i)
        #pragma unroll
        for (int j = 0; j < 2; ++j)
            #pragma unroll
            for (int r = 0; r < 16; ++r) acc[i][j][r] = 0.f;

    bf16x8 a0h[2], a0l[2], b0h[2], b0l[2];
    bf16x8 a1h[2], a1l[2], b1h[2], b1l[2];

#define LOADF(AH, AL, BH, BL, OFF) do {                                        \
    _Pragma("unroll") for (int mi = 0; mi < 2; ++mi) {                         \
        AH[mi] = *reinterpret_cast<const bf16x8*>(pAh[mi] + (OFF));            \
        AL[mi] = *reinterpret_cast<const bf16x8*>(pAl[mi] + (OFF)); }          \
    _Pragma("unroll") for (int nj = 0; nj < 2; ++nj) {                         \
        BH[nj] = *reinterpret_cast<const bf16x8*>(pBh[nj] + (OFF));            \
        BL[nj] = *reinterpret_cast<const bf16x8*>(pBl[nj] + (OFF)); } } while(0)

#define MFMAF(AH, AL, BH, BL) do {                                             \
    _Pragma("unroll") for (int mi = 0; mi < 2; ++mi)                           \
    _Pragma("unroll") for (int nj = 0; nj < 2; ++nj) {                         \
        acc[mi][nj] = __builtin_amdgcn_mfma_f32_32x32x16_bf16(                 \
            AH[mi], BH[nj], acc[mi][nj], 0, 0, 0);                             \
        acc[mi][nj] = __builtin_amdgcn_mfma_f32_32x32x16_bf16(                 \
            AH[mi], BL[nj], acc[mi][nj], 0, 0, 0);                             \
        acc[mi][nj] = __builtin_amdgcn_mfma_f32_32x32x16_bf16(                 \
            AL[mi], BH[nj], acc[mi][nj], 0, 0, 0); } } while(0)

    LOADF(a0h, a0l, b0h, b0l, 0);
    for (int k0 = 0; k0 < K; k0 += 32) {
        size_t o1 = (size_t)((k0 + 16) >> 3) * 256;
        LOADF(a1h, a1l, b1h, b1l, o1);
        MFMAF(a0h, a0l, b0h, b0l);
        size_t o2 = (k0 + 32 < K) ? (size_t)((k0 + 32) >> 3) * 256 : 0;
        LOADF(a0h, a0l, b0h, b0l, o2);       // last iteration: harmless reload
        MFMAF(a1h, a1l, b1h, b1l);
    }
#undef LOADF
#undef MFMAF

    // epilogue: C/D map: col = lane&31, row31 = (r&3)+8*(r>>2)+4*kg
    #pragma unroll
    for (int mi = 0; mi < 2; ++mi) {
        int rb2 = row_b + mi*32;
        #pragma unroll
        for (int nj = 0; nj < 2; ++nj) {
            int colf = col_b + nj*32 + lr;
            float bv = bias[colf];
            if (OUT == 1) {
                size_t ftb = ((size_t)(rb2 >> 5) * (N >> 3) + (colf >> 3)) * 256 + (colf & 7);
                #pragma unroll
                for (int r = 0; r < 16; ++r) {
                    int r31 = (r & 3) + 8*(r >> 2) + 4*kg;
                    int row = rb2 + r31;
                    if (row >= M) continue;
                    float v = acc[mi][nj][r] + bv;
                    if (DO_RELU) v = fmaxf(v, 0.f);
                    size_t oo = ftb + (size_t)r31 * 8;
                    ushort hh = f2b_hi(v);
                    Chi[oo] = hh;
                    Clo[oo] = f2b_lo(v, hh);
                }
            } else {
                int sel = (col_b + nj*32) >> 8;   // 0=Q,1=K,2=V (tile-uniform)
                int h = (colf >> 5) & 7;
                int d = colf & 31;
                #pragma unroll
                for (int r = 0; r < 16; ++r) {
                    int r31 = (r & 3) + 8*(r >> 2) + 4*kg;
                    int row = rb2 + r31;
                    if (row >= M) continue;
                    float v = acc[mi][nj][r] + bv;
                    int bl = row / T_SEQ;
                    int tok = row - bl * T_SEQ;
                    size_t bb = (size_t)(bl*8 + h) * 12288;
                    ushort hh = f2b_hi(v);
                    ushort ll = f2b_lo(v, hh);
                    if (sel == 0) {
                        size_t o = bb + (size_t)((tok >> 5)*4 + (d >> 3))*256
                                 + ((tok & 31) << 3) + (d & 7);
                        Wq_h[o] = hh; Wq_l[o] = ll;
                    } else if (sel == 1) {
                        size_t o = bb + (size_t)((tok >> 5)*4 + (d >> 3))*256
                                 + ((tok & 31) << 3) + (d & 7);
                        Wk_h[o] = hh; Wk_l[o] = ll;
                    } else {
                        size_t o = bb + (size_t)(tok >> 3)*256 + d*8 + (tok & 7);
                        Wv_h[o] = hh; Wv_l[o] = ll;
                    }
                }
            }
        }
    }
}

// ------- split-bf16 MFMA GEMM fused with residual add + LayerNorm -------
// Block = 64 rows x 256 cols (wave w owns cols w*64..w*64+63, 2x2 frags of
// 32x32 over rows x its col strip). x (FT hi/lo) is residual input AND LN
// output (in-place). v = A@B + bias + x; x = g*(v-mu)/sqrt(var+eps) + be.
__global__ __launch_bounds__(256) void gemm_ln(
    const ushort* __restrict__ Ahi, const ushort* __restrict__ Alo,
    const ushort* __restrict__ Bhi, const ushort* __restrict__ Blo,
    const float* __restrict__ bias,
    ushort* __restrict__ xhi, ushort* __restrict__ xlo,
    const float* __restrict__ g, const float* __restrict__ be,
    int M, int K)
{
    const int N = HDIM;
    const int t = threadIdx.x;
    const int lane = t & 63, wave = t >> 6;
    const int lr = lane & 31, kg = lane >> 5;
    const int row_b = blockIdx.y * 64;
    const int col_w = wave * 64;
    const int KB = K >> 3;

    const ushort *pAh[2], *pAl[2], *pBh[2], *pBl[2];
    #pragma unroll
    for (int mi = 0; mi < 2; ++mi) {
        int rb = row_b + mi*32; if (rb > M - 32) rb = M - 32;
        size_t base = ((size_t)(rb >> 5) * KB + kg) * 256 + lr * 8;
        pAh[mi] = Ahi + base; pAl[mi] = Alo + base;
    }
    #pragma unroll
    for (int nj = 0; nj < 2; ++nj) {
        size_t base = ((size_t)((col_w + nj*32) >> 5) * KB + kg) * 256 + lr * 8;
        pBh[nj] = Bhi + base; pBl[nj] = Blo + base;
    }

    f32x16 acc[2][2];
    #pragma unroll
    for (int i = 0; i < 2; ++i)
        #pragma unroll
        for (int j = 0; j < 2; ++j)
            #pragma unroll
            for (int r = 0; r < 16; ++r) acc[i][j][r] = 0.f;

    bf16x8 a0h[2], a0l[2], b0h[2], b0l[2];
    bf16x8 a1h[2], a1l[2], b1h[2], b1l[2];

#define LOADF(AH, AL, BH, BL, OFF) do {                                        \
    _Pragma("unroll") for (int mi = 0; mi < 2; ++mi) {                         \
        AH[mi] = *reinterpret_cast<const bf16x8*>(pAh[mi] + (OFF));            \
        AL[mi] = *reinterpret_cast<const bf16x8*>(pAl[mi] + (OFF)); }          \
    _Pragma("unroll") for (int nj = 0; nj < 2; ++nj) {                         \
        BH[nj] = *reinterpret_cast<const bf16x8*>(pBh[nj] + (OFF));            \
        BL[nj] = *reinterpret_cast<const bf16x8*>(pBl[nj] + (OFF)); } } while(0)

#define MFMAF(AH, AL, BH, BL) do {                                             \
    _Pragma("unroll") for (int mi = 0; mi < 2; ++mi)                           \
    _Pragma("unroll") for (int nj = 0; nj < 2; ++nj) {                         \
        acc[mi][nj] = __builtin_amdgcn_mfma_f32_32x32x16_bf16(                 \
            AH[mi], BH[nj], acc[mi][nj], 0, 0, 0);                             \
        acc[mi][nj] = __builtin_amdgcn_mfma_f32_32x32x16_bf16(                 \
            AH[mi], BL[nj], acc[mi][nj], 0, 0, 0);                             \
        acc[mi][nj] = __builtin_amdgcn_mfma_f32_32x32x16_bf16(                 \
            AL[mi], BH[nj], acc[mi][nj], 0, 0, 0); } } while(0)

    LOADF(a0h, a0l, b0h, b0l, 0);
    for (int k0 = 0; k0 < K; k0 += 32) {
        size_t o1 = (size_t)((k0 + 16) >> 3) * 256;
        LOADF(a1h, a1l, b1h, b1l, o1);
        MFMAF(a0h, a0l, b0h, b0l);
        size_t o2 = (k0 + 32 < K) ? (size_t)((k0 + 32) >> 3) * 256 : 0;
        LOADF(a0h, a0l, b0h, b0l, o2);
        MFMAF(a1h, a1l, b1h, b1l);
    }
#undef LOADF
#undef MFMAF

    // v = acc + bias + residual; accumulate per-row sum/sumsq (this lane: 2 cols/row)
    float s1[2][16], s2[2][16];
    #pragma unroll
    for (int mi = 0; mi < 2; ++mi)
        #pragma unroll
        for (int nj = 0; nj < 2; ++nj) {
            int col = col_w + nj*32 + lr;
            float bv = bias[col];
            #pragma unroll
            for (int r = 0; r < 16; ++r) {
                int r31 = (r & 3) + 8*(r >> 2) + 4*kg;
                int row = row_b + mi*32 + r31;
                int rowc = (row < M) ? row : (M - 1);
                size_t oo = ((size_t)(rowc >> 5) * (N >> 3) + (col >> 3)) * 256
                          + ((rowc & 31) << 3) + (col & 7);
                float v = acc[mi][nj][r] + bv + b2f(xhi[oo]) + b2f(xlo[oo]);
                acc[mi][nj][r] = v;
                if (nj == 0) { s1[mi][r] = v;  s2[mi][r] = v*v; }
                else         { s1[mi][r] += v; s2[mi][r] += v*v; }
            }
        }
    // butterfly over the 32-lane (same kg) group
    #pragma unroll
    for (int mi = 0; mi < 2; ++mi)
        #pragma unroll
        for (int r = 0; r < 16; ++r) {
            #pragma unroll
            for (int off = 1; off <= 16; off <<= 1) {
                s1[mi][r] += __shfl_xor(s1[mi][r], off);
                s2[mi][r] += __shfl_xor(s2[mi][r], off);
            }
        }
    __shared__ float red1[4][64];
    __shared__ float red2[4][64];
    __shared__ float tot1[64];
    __shared__ float tot2[64];
    if (lr == 0) {
        #pragma unroll
        for (int mi = 0; mi < 2; ++mi)
            #pragma unroll
            for (int r = 0; r < 16; ++r) {
                int rr = mi*32 + (r & 3) + 8*(r >> 2) + 4*kg;
                red1[wave][rr] = s1[mi][r];
                red2[wave][rr] = s2[mi][r];
            }
    }
    __syncthreads();
    if (t < 64) {
        tot1[t] = red1[0][t] + red1[1][t] + red1[2][t] + red1[3][t];
        tot2[t] = red2[0][t] + red2[1][t] + red2[2][t] + red2[3][t];
    }
    __syncthreads();
    // normalize + write
    #pragma unroll
    for (int mi = 0; mi < 2; ++mi) {
        #pragma unroll
        for (int r = 0; r < 16; ++r) {
            int r31 = (r & 3) + 8*(r >> 2) + 4*kg;
            int rr = mi*32 + r31;
            int row = row_b + rr;
            if (row >= M) continue;
            float mu = tot1[rr] * (1.f/256.f);
            float var = fmaf(-mu, mu, tot2[rr] * (1.f/256.f));
            float rs = rsqrtf(var + 1e-5f);
            #pragma unroll
            for (int nj = 0; nj < 2; ++nj) {
                int col = col_w + nj*32 + lr;
                float o = g[col] * (acc[mi][nj][r] - mu) * rs + be[col];
                size_t oo = ((size_t)(row >> 5) * (N >> 3) + (col >> 3)) * 256
                          + ((row & 31) << 3) + (col & 7);
                ushort hh = f2b_hi(o);
                xhi[oo] = hh;
                xlo[oo] = f2b_lo(o, hh);
            }
        }
    }
}

// ---------------- MFMA attention: 1 wave per (b,h,q-tile) ----------------
__global__ __launch_bounds__(256) void attn_mfma(
    const ushort* __restrict__ Qh, const ushort* __restrict__ Ql,
    const ushort* __restrict__ Kh, const ushort* __restrict__ Kl,
    const ushort* __restrict__ Vh, const ushort* __restrict__ Vl,
    ushort* __restrict__ ahi, ushort* __restrict__ alo)
{
    const int bh = blockIdx.y;
    const int wave = threadIdx.x >> 6, lane = threadIdx.x & 63;
    const int qt = blockIdx.x * 4 + wave;   // 0..11
    const int lr = lane & 31, kg = lane >> 5;
    const size_t base = (size_t)bh * 12288;
    const float scale = 0.17677669529663687f; // 1/sqrt(32)

    bf16x8 qfh[2], qfl[2];
    #pragma unroll
    for (int ks = 0; ks < 2; ++ks) {
        size_t o = base + (size_t)(qt*4 + ks*2 + kg)*256 + lr*8;
        qfh[ks] = *reinterpret_cast<const bf16x8*>(Qh + o);
        qfl[ks] = *reinterpret_cast<const bf16x8*>(Ql + o);
    }

    float m = -3e38f;
    for (int kt = 0; kt < 12; ++kt) {
        f32x16 st;
        #pragma unroll
        for (int r = 0; r < 16; ++r) st[r] = 0.f;
        #pragma unroll
        for (int ks = 0; ks < 2; ++ks) {
            size_t o = base + (size_t)(kt*4 + ks*2 + kg)*256 + lr*8;
            bf16x8 kfh = *reinterpret_cast<const bf16x8*>(Kh + o);
            bf16x8 kfl = *reinterpret_cast<const bf16x8*>(Kl + o);
            st = __builtin_amdgcn_mfma_f32_32x32x16_bf16(kfh, qfh[ks], st, 0,0,0);
            st = __builtin_amdgcn_mfma_f32_32x32x16_bf16(kfh, qfl[ks], st, 0,0,0);
            st = __builtin_amdgcn_mfma_f32_32x32x16_bf16(kfl, qfh[ks], st, 0,0,0);
        }
        #pragma unroll
        for (int r = 0; r < 16; ++r) {
            int krow = kt*32 + (r & 3) + 8*(r >> 2) + 4*kg;
            m = fmaxf(m, (krow < T_SEQ) ? st[r] : -3e38f);
        }
    }
    m = fmaxf(m, __shfl_xor(m, 32));

    f32x16 oacc;
    #pragma unroll
    for (int r = 0; r < 16; ++r) oacc[r] = 0.f;
    float l = 0.f;

    for (int kt = 0; kt < 12; ++kt) {
        f32x16 st;
        #pragma unroll
        for (int r = 0; r < 16; ++r) st[r] = 0.f;
        #pragma unroll
        for (int ks = 0; ks < 2; ++ks) {
            size_t o = base + (size_t)(kt*4 + ks*2 + kg)*256 + lr*8;
            bf16x8 kfh = *reinterpret_cast<const bf16x8*>(Kh + o);
            bf16x8 kfl = *reinterpret_cast<const bf16x8*>(Kl + o);
            st = __builtin_amdgcn_mfma_f32_32x32x16_bf16(kfh, qfh[ks], st, 0,0,0);
            st = __builtin_amdgcn_mfma_f32_32x32x16_bf16(kfh, qfl[ks], st, 0,0,0);
            st = __builtin_amdgcn_mfma_f32_32x32x16_bf16(kfl, qfh[ks], st, 0,0,0);
        }
        float p[16];
        #pragma unroll
        for (int r = 0; r < 16; ++r) {
            int krow = kt*32 + (r & 3) + 8*(r >> 2) + 4*kg;
            float sv = (krow < T_SEQ) ? st[r] : -3e38f;
            float e = __expf((sv - m) * scale);
            p[r] = e; l += e;
        }
        float pp[16];
        #pragma unroll
        for (int r = 0; r < 16; ++r) pp[r] = __shfl_xor(p[r], 32);
        #pragma unroll
        for (int ks = 0; ks < 2; ++ks) {
            union { u16x8 u; bf16x8 b; } fh, fl;
            #pragma unroll
            for (int j = 0; j < 8; ++j) {
                float e;
                if (ks == 0)
                    e = kg ? ((j < 4) ? pp[4+j] : p[j])
                           : ((j < 4) ? p[j]    : pp[j-4]);
                else
                    e = kg ? ((j < 4) ? pp[12+j] : p[8+j])
                           : ((j < 4) ? p[8+j]   : pp[4+j]);
                ushort hh = f2b_hi(e);
                fh.u[j] = hh;
                fl.u[j] = f2b_lo(e, hh);
            }
            size_t vo = base + (size_t)(kt*4 + ks*2 + kg)*256 + lr*8;
            bf16x8 vfh = *reinterpret_cast<const bf16x8*>(Vh + vo);
            bf16x8 vfl = *reinterpret_cast<const bf16x8*>(Vl + vo);
            oacc = __builtin_amdgcn_mfma_f32_32x32x16_bf16(fh.b, vfh, oacc, 0,0,0);
            oacc = __builtin_amdgcn_mfma_f32_32x32x16_bf16(fh.b, vfl, oacc, 0,0,0);
            oacc = __builtin_amdgcn_mfma_f32_32x32x16_bf16(fl.b, vfh, oacc, 0,0,0);
        }
    }
    l += __shfl_xor(l, 32);
    float il = 1.f / l;

    const int bl = bh >> 3, h = bh & 7;
    #pragma unroll
    for (int r = 0; r < 16; ++r) {
        int q = (r & 3) + 8*(r >> 2) + 4*kg;
        float sc = __shfl(il, q);
        int row_local = qt*32 + q;
        if (row_local < T_SEQ) {
            float v = oacc[r] * sc;
            int grow = bl*T_SEQ + row_local;
            int col = h*32 + lr;
            size_t o = ((size_t)(grow >> 5)*32 + (col >> 3))*256
                     + ((grow & 31) << 3) + (col & 7);
            ushort hh = f2b_hi(v);
            ahi[o] = hh;
            alo[o] = f2b_lo(v, hh);
        }
    }
}

// -------- mean-pool + output head (reads FT hi/lo stream) --------
__global__ __launch_bounds__(256) void head_kernel(
    const ushort* __restrict__ xhi, const ushort* __restrict__ xlo,
    const float* __restrict__ sfeat,
    const float* __restrict__ W1, const float* __restrict__ b1,
    const float* __restrict__ W2, const float* __restrict__ b2,
    const float* __restrict__ scale, const float* __restrict__ shift,
    float* __restrict__ out)
{
    __shared__ float p[HDIM];
    __shared__ float h1[HDIM/2];
    int b = blockIdx.x, t = threadIdx.x;
    float acc = 0.f;
    for (int tt = 0; tt < T_SEQ; ++tt) {
        size_t row = (size_t)b*T_SEQ + tt;
        size_t o = ((row >> 5) * 32 + (t >> 3)) * 256 + ((row & 31) << 3) + (t & 7);
        acc += b2f(xhi[o]) + b2f(xlo[o]);
    }
    p[t] = acc * (1.f/365.f) + sfeat[(size_t)b*HDIM + t];
    __syncthreads();
    if (t < HDIM/2) {
        float a = b1[t];
        for (int c = 0; c < HDIM; ++c) a = fmaf(p[c], W1[c*(HDIM/2) + t], a);
        h1[t] = gelu_f(a);
    }
    __syncthreads();
    if (t < 30) {
        float a = b2[t];
        for (int j = 0; j < HDIM/2; ++j) a = fmaf(h1[j], W2[j*30 + t], a);
        out[b*30 + t] = tanhf(a) * scale[0] + shift[0];
    }
}

extern "C" void kernel_launch(void* const* d_in, const int* in_sizes, int n_in,
                              void* d_out, int out_size, void* d_ws, size_t ws_size,
                              hipStream_t stream) {
    const float* p_static = (const float*)d_in[0];
    const float* p_dyn    = (const float*)d_in[1];
    const float* p_lat    = (const float*)d_in[2];
    const float* p_lon    = (const float*)d_in[3];
    const float* p_all    = (const float*)d_in[4];
    const float* p_coords = (const float*)d_in[5];
    const float* p_Wst    = (const float*)d_in[6];
    const float* p_bst    = (const float*)d_in[7];
    const float* p_gst    = (const float*)d_in[8];
    const float* p_best   = (const float*)d_in[9];
    const float* p_Wdy    = (const float*)d_in[10];
    const float* p_bdy    = (const float*)d_in[11];
    const float* p_gdy    = (const float*)d_in[12];
    const float* p_bedy   = (const float*)d_in[13];
    const float* p_Wqkv   = (const float*)d_in[14];
    const float* p_bqkv   = (const float*)d_in[15];
    const float* p_Wo     = (const float*)d_in[16];
    const float* p_bo     = (const float*)d_in[17];
    const float* p_gln1   = (const float*)d_in[18];
    const float* p_beln1  = (const float*)d_in[19];
    const float* p_Wf1    = (const float*)d_in[20];
    const float* p_bf1    = (const float*)d_in[21];
    const float* p_Wf2    = (const float*)d_in[22];
    const float* p_bf2    = (const float*)d_in[23];
    const float* p_gln2   = (const float*)d_in[24];
    const float* p_beln2  = (const float*)d_in[25];
    const float* p_Wo1    = (const float*)d_in[26];
    const float* p_bo1    = (const float*)d_in[27];
    const float* p_Wo2    = (const float*)d_in[28];
    const float* p_bo2    = (const float*)d_in[29];
    const float* p_scale  = (const float*)d_in[30];
    const float* p_shift  = (const float*)d_in[31];
    float* out = (float*)d_out;
    (void)in_sizes; (void)n_in; (void)out_size;

    char* ws = (char*)d_ws;
    size_t off = 0;
    auto alloc = [&](size_t bytes) -> void* {
        void* p = ws + off;
        off += (bytes + 255) & ~(size_t)255;
        return p;
    };
    const int ROWS = BATCH * T_SEQ; // 93440 (%32 == 0)
    int*    nbr   = (int*)   alloc((size_t)BATCH*KNB*sizeof(int));
    float*  sfeat = (float*) alloc((size_t)BATCH*HDIM*sizeof(float));
    ushort* xhi   = (ushort*)alloc((size_t)ROWS*HDIM*sizeof(ushort));
    ushort* xlo   = (ushort*)alloc((size_t)ROWS*HDIM*sizeof(ushort));
    const size_t SZ_QKV = (size_t)4*768*256, SZ_O = (size_t)4*256*256;
    const size_t SZ_F1  = (size_t)4*1024*256, SZ_F2 = (size_t)4*256*1024;
    ushort* Wqkvt_h = (ushort*)alloc(SZ_QKV*2*sizeof(ushort)); ushort* Wqkvt_l = Wqkvt_h + SZ_QKV;
    ushort* Wot_h   = (ushort*)alloc(SZ_O  *2*sizeof(ushort)); ushort* Wot_l   = Wot_h   + SZ_O;
    ushort* Wf1t_h  = (ushort*)alloc(SZ_F1 *2*sizeof(ushort)); ushort* Wf1t_l  = Wf1t_h  + SZ_F1;
    ushort* Wf2t_h  = (ushort*)alloc(SZ_F2 *2*sizeof(ushort)); ushort* Wf2t_l  = Wf2t_h  + SZ_F2;
    size_t fixed = off;

    // per-chunk union region: QKV-split (6 x CH*8*12288 ushorts) during attn,
    // OR hbuf hi/lo (CH*1,495,040 B) during FF. aatt separate.
    const size_t PER_B = (size_t)T_SEQ * 1024 * 4;   // 1,495,040
    const size_t PER_A = (size_t)T_SEQ * 256 * 4;    // aatt hi+lo
    const size_t PER_CH = PER_B + PER_A;
    int CH = 32;
    {
        const int tiers[3] = {256, 128, 64};
        for (int i = 0; i < 3; ++i) {
            if (fixed + (size_t)tiers[i]*PER_CH + 8192 <= ws_size) { CH = tiers[i]; break; }
        }
    }
    char*   big    = (char*)alloc((size_t)CH * PER_B);
    ushort* aatt_h = (ushort*)alloc((size_t)CH * PER_A);
    const int RW = CH * T_SEQ;
    ushort* aatt_l = aatt_h + (size_t)RW * HDIM;
    const size_t seg = (size_t)CH * 8 * 12288;       // ushorts per QKV buffer
    ushort* Qh  = (ushort*)big;
    ushort* Ql  = Qh  + seg;
    ushort* Kh2 = Ql  + seg;
    ushort* Kl2 = Kh2 + seg;
    ushort* Vth = Kl2 + seg;
    ushort* Vtl = Vth + seg;
    ushort* hbuf_h = (ushort*)big;
    ushort* hbuf_l = hbuf_h + (size_t)RW * FFDIM;
    const int GY  = (RW + 127) / 128;   // 128-row tiles (guarded)
    const int GY2 = (RW + 63) / 64;     // 64-row tiles (guarded)

    topk_kernel <<<BATCH, 256, 0, stream>>>(p_lat, p_lon, p_coords, nbr);
    sfeat_kernel<<<BATCH, 256, 0, stream>>>(p_static, p_all, nbr, p_Wst, p_bst, p_gst, p_best, sfeat);
    dyn_kernel  <<<ROWS/4, 256, 0, stream>>>(p_dyn, p_Wdy, p_bdy, p_gdy, p_bedy, sfeat, xhi, xlo);
    tsplit_kernel<<<dim3(24, 8, 4), 256, 0, stream>>>(p_Wqkv, Wqkvt_h, Wqkvt_l, 256, 768);
    tsplit_kernel<<<dim3( 8, 8, 4), 256, 0, stream>>>(p_Wo,   Wot_h,   Wot_l,   256, 256);
    tsplit_kernel<<<dim3(32, 8, 4), 256, 0, stream>>>(p_Wf1,  Wf1t_h,  Wf1t_l,  256, 1024);
    tsplit_kernel<<<dim3( 8,32, 4), 256, 0, stream>>>(p_Wf2,  Wf2t_h,  Wf2t_l,  1024, 256);

    const int NCHUNK = BATCH / CH;
    for (int c = 0; c < NCHUNK; ++c) {
        size_t co = (size_t)c * CH * T_SEQ * HDIM;
        ushort* xhic = xhi + co;
        ushort* xloc = xlo + co;
        for (int l = 0; l < 4; ++l) {
            gemm_mfma<0,2><<<dim3(6, GY), 256, 0, stream>>>(
                xhic, xloc, Wqkvt_h + (size_t)l*768*256, Wqkvt_l + (size_t)l*768*256,
                p_bqkv + l*768, nullptr, nullptr,
                Qh, Ql, Kh2, Kl2, Vth, Vtl, RW, 768, 256);
            attn_mfma<<<dim3(3, CH*8), 256, 0, stream>>>(
                Qh, Ql, Kh2, Kl2, Vth, Vtl, aatt_h, aatt_l);
            gemm_ln<<<dim3(1, GY2), 256, 0, stream>>>(
                aatt_h, aatt_l, Wot_h + (size_t)l*256*256, Wot_l + (size_t)l*256*256,
                p_bo + l*256, xhic, xloc, p_gln1 + l*256, p_beln1 + l*256, RW, 256);
            gemm_mfma<1,1><<<dim3(8, GY), 256, 0, stream>>>(
                xhic, xloc, Wf1t_h + (size_t)l*1024*256, Wf1t_l + (size_t)l*1024*256,
                p_bf1 + l*1024, hbuf_h, hbuf_l,
                nullptr, nullptr, nullptr, nullptr, nullptr, nullptr, RW, 1024, 256);
            gemm_ln<<<dim3(1, GY2), 256, 0, stream>>>(
                hbuf_h, hbuf_l, Wf2t_h + (size_t)l*256*1024, Wf2t_l + (size_t)l*256*1024,
                p_bf2 + l*256, xhic, xloc, p_gln2 + l*256, p_beln2 + l*256, RW, 1024);
        }
    }
    head_kernel<<<BATCH, 256, 0, stream>>>(xhi, xlo, sfeat, p_Wo1, p_bo1, p_Wo2, p_bo2, p_scale, p_shift, out);
}

// Round 9
// 4988.115 us; speedup vs baseline: 9.3879x; 1.2450x over previous
//
#include <hip/hip_runtime.h>
#include <math.h>

#define T_SEQ 365
#define HDIM 256
#define NHEADS 8
#define HD 32
#define BATCH 256
#define DDIM 16
#define FFDIM 1024
#define NST 10000
#define KNB 5
#define SDIM 64

typedef __bf16 bf16x8 __attribute__((ext_vector_type(8)));
typedef float  f32x16 __attribute__((ext_vector_type(16)));
typedef unsigned short u16x8 __attribute__((ext_vector_type(8)));

__device__ __forceinline__ ushort f2b_hi(float v) {
    unsigned u = __float_as_uint(v);
    unsigned r = u + 0x7fffu + ((u >> 16) & 1u);
    return (ushort)(r >> 16);
}
__device__ __forceinline__ float b2f(ushort h) {
    return __uint_as_float(((unsigned)h) << 16);
}
__device__ __forceinline__ ushort f2b_lo(float v, ushort hi) {
    return f2b_hi(v - b2f(hi));
}

__device__ __forceinline__ float gelu_f(float x) {
    return 0.5f * x * (1.f + erff(x * 0.70710678118654752f));
}

// FT (fragment-tiled) layout for a [R][C] bf16 matrix, C%8==0:
// offset(r,c) = ((r>>5)*(C>>3) + (c>>3))*256 + (r&31)*8 + (c&7)
// A wave's MFMA fragment (32 rows x 8 k) is one contiguous 512-ushort run.
// Per-(b,h) attention buffers: Q,K = FT over [384 tok][32 d] (12288 ushorts);
// V^T = FT over [32 d][384 tok]: offset(d,tok) = (tok>>3)*256 + d*8 + (tok&7).

// block-wide (256 threads = 4 waves) sum; sred must be float[4] shared
__device__ __forceinline__ float block_sum256(float v, float* sred) {
    #pragma unroll
    for (int off = 32; off; off >>= 1) v += __shfl_xor(v, off);
    int wave = threadIdx.x >> 6;
    if ((threadIdx.x & 63) == 0) sred[wave] = v;
    __syncthreads();
    float s = sred[0] + sred[1] + sred[2] + sred[3];
    __syncthreads();
    return s;
}

// ---------------- top-K neighbor search ----------------
__global__ __launch_bounds__(256) void topk_kernel(
    const float* __restrict__ lat, const float* __restrict__ lon,
    const float* __restrict__ coords, int* __restrict__ nbr)
{
    __shared__ float hav[NST];
    __shared__ float rv[256];
    __shared__ int   ri[256];
    const float DEG = 0.017453292519943295f;
    int b = blockIdx.x, t = threadIdx.x;
    float lat_o = (lat[b] + 1.f) * 0.5f * 25.f + 24.f;
    float lon_o = (lon[b] + 1.f) * 0.5f * 58.5f - 125.f;
    float qlat = lat_o * DEG, qlon = lon_o * DEG;
    float cq = cosf(qlat);
    for (int i = t; i < NST; i += 256) {
        float slat = coords[2*i], slon = coords[2*i+1];
        float dlat = qlat - slat, dlon = qlon - slon;
        float s1 = sinf(dlat * 0.5f), s2 = sinf(dlon * 0.5f);
        hav[i] = s1*s1 + cq * cosf(slat) * s2*s2;
    }
    __syncthreads();
    for (int sel = 0; sel < KNB + 1; ++sel) {
        float bv = 1e30f; int bi = 0x7fffffff;
        for (int i = t; i < NST; i += 256) {
            float v = hav[i];
            if (v < bv || (v == bv && i < bi)) { bv = v; bi = i; }
        }
        rv[t] = bv; ri[t] = bi;
        __syncthreads();
        for (int s = 128; s > 0; s >>= 1) {
            if (t < s) {
                float ov = rv[t+s]; int oi = ri[t+s];
                if (ov < rv[t] || (ov == rv[t] && oi < ri[t])) { rv[t] = ov; ri[t] = oi; }
            }
            __syncthreads();
        }
        if (t == 0) {
            if (sel > 0) nbr[b*KNB + sel - 1] = ri[0];
            hav[ri[0]] = 1e30f;   // mask winner
        }
        __syncthreads();
    }
}

// ---------------- static-feature branch ----------------
__global__ __launch_bounds__(256) void sfeat_kernel(
    const float* __restrict__ stat, const float* __restrict__ all_st,
    const int* __restrict__ nbr, const float* __restrict__ W,
    const float* __restrict__ bias, const float* __restrict__ g,
    const float* __restrict__ be, float* __restrict__ sfeat)
{
    __shared__ float comb[(KNB+1)*SDIM]; // 384
    __shared__ float sred[4];
    int b = blockIdx.x, t = threadIdx.x;
    for (int i = t; i < (KNB+1)*SDIM; i += 256) {
        if (i < SDIM) comb[i] = stat[b*SDIM + i];
        else {
            int n = (i - SDIM) >> 6, d = (i - SDIM) & 63;
            comb[i] = all_st[(size_t)nbr[b*KNB + n] * SDIM + d];
        }
    }
    __syncthreads();
    float acc = bias[t];
    for (int j = 0; j < (KNB+1)*SDIM; ++j)
        acc = fmaf(comb[j], W[j*HDIM + t], acc);
    float mu  = block_sum256(acc, sred) * (1.f/256.f);
    float d   = acc - mu;
    float var = block_sum256(d*d, sred) * (1.f/256.f);
    float y = g[t] * d * rsqrtf(var + 1e-5f) + be[t];
    sfeat[(size_t)b*HDIM + t] = gelu_f(y);
}

// ------ dynamic embedding: 4 rows/block, wave per row, full-line FT writes ------
__global__ __launch_bounds__(256) void dyn_kernel(
    const float* __restrict__ dynv, const float* __restrict__ W,
    const float* __restrict__ bias, const float* __restrict__ g,
    const float* __restrict__ be, const float* __restrict__ sfeat,
    ushort* __restrict__ xhi, ushort* __restrict__ xlo)
{
    __shared__ float w[DDIM*HDIM];   // 16 KB
    __shared__ float dr[4][DDIM];
    int wave = threadIdx.x >> 6, lane = threadIdx.x & 63;
    int row0 = blockIdx.x * 4;
    for (int i = threadIdx.x; i < DDIM*HDIM; i += 256) w[i] = W[i];
    if (lane < DDIM)
        dr[wave][lane] = dynv[(size_t)(row0 + wave)*DDIM + lane];
    __syncthreads();
    int row = row0 + wave;
    int b = row / T_SEQ;
    int c0 = lane * 4;
    float v0 = bias[c0], v1 = bias[c0+1], v2 = bias[c0+2], v3 = bias[c0+3];
    #pragma unroll
    for (int k = 0; k < DDIM; ++k) {
        float dk = dr[wave][k];
        float4 wv = *reinterpret_cast<const float4*>(&w[k*HDIM + c0]);
        v0 = fmaf(dk, wv.x, v0); v1 = fmaf(dk, wv.y, v1);
        v2 = fmaf(dk, wv.z, v2); v3 = fmaf(dk, wv.w, v3);
    }
    float s = v0 + v1 + v2 + v3;
    #pragma unroll
    for (int off = 32; off; off >>= 1) s += __shfl_xor(s, off);
    float mu = s * (1.f/256.f);
    float d0 = v0-mu, d1 = v1-mu, d2 = v2-mu, d3 = v3-mu;
    float s2 = d0*d0 + d1*d1 + d2*d2 + d3*d3;
    #pragma unroll
    for (int off = 32; off; off >>= 1) s2 += __shfl_xor(s2, off);
    float rs = rsqrtf(s2 * (1.f/256.f) + 1e-5f);
    float4 gg = *reinterpret_cast<const float4*>(&g[c0]);
    float4 bb = *reinterpret_cast<const float4*>(&be[c0]);
    float4 sf = *reinterpret_cast<const float4*>(&sfeat[(size_t)b*HDIM + c0]);
    float o0 = gelu_f(gg.x*d0*rs + bb.x) + sf.x;
    float o1 = gelu_f(gg.y*d1*rs + bb.y) + sf.y;
    float o2 = gelu_f(gg.z*d2*rs + bb.z) + sf.z;
    float o3 = gelu_f(gg.w*d3*rs + bb.w) + sf.w;
    size_t o = ((size_t)(row >> 5) * 32 + (c0 >> 3)) * 256 + ((row & 31) << 3) + (c0 & 7);
    ushort4 hv, lv;
    hv.x = f2b_hi(o0); lv.x = f2b_lo(o0, hv.x);
    hv.y = f2b_hi(o1); lv.y = f2b_lo(o1, hv.y);
    hv.z = f2b_hi(o2); lv.z = f2b_lo(o2, hv.z);
    hv.w = f2b_hi(o3); lv.w = f2b_lo(o3, hv.w);
    *reinterpret_cast<ushort4*>(&xhi[o]) = hv;
    *reinterpret_cast<ushort4*>(&xlo[o]) = lv;
}

// --- weight transpose + split: W[L][K][N] -> FT([N][K]) hi/lo per layer ---
__global__ __launch_bounds__(256) void tsplit_kernel(
    const float* __restrict__ W, ushort* __restrict__ hi, ushort* __restrict__ lo,
    int K, int N)
{
    __shared__ float tile[32][33];
    size_t l = blockIdx.z;
    const float* Wl = W + l*(size_t)K*N;
    ushort* hil = hi + l*(size_t)K*N;
    ushort* lol = lo + l*(size_t)K*N;
    int n0 = blockIdx.x*32, k0 = blockIdx.y*32;
    int tx = threadIdx.x & 31, ty = threadIdx.x >> 5;
    int KB = K >> 3;
    for (int i = ty; i < 32; i += 8) tile[i][tx] = Wl[(size_t)(k0+i)*N + n0 + tx];
    __syncthreads();
    for (int i = ty; i < 32; i += 8) {
        float v = tile[tx][i];              // (k=k0+tx, n=n0+i)
        ushort h = f2b_hi(v);
        size_t o = ((size_t)(n0 >> 5) * KB + (k0 >> 3) + (tx >> 3)) * 256
                 + ((size_t)i << 3) + (tx & 7);
        hil[o] = h;
        lol[o] = f2b_lo(v, h);
    }
}

// ---------------- split-bf16 MFMA GEMM, FT operands, no LDS ----------------
// OUT=1: write FT hi/lo (Chi/Clo). OUT=2: scatter Q/K/V into per-(b,h)
// attention layouts (Q,K: FT [384][32]; V: transposed FT [32][384]).
template<int DO_RELU, int OUT>
__global__ __launch_bounds__(256) void gemm_mfma(
    const ushort* __restrict__ Ahi, const ushort* __restrict__ Alo,
    const ushort* __restrict__ Bhi, const ushort* __restrict__ Blo,
    const float* __restrict__ bias,
    ushort* __restrict__ Chi, ushort* __restrict__ Clo,
    ushort* __restrict__ Wq_h, ushort* __restrict__ Wq_l,
    ushort* __restrict__ Wk_h, ushort* __restrict__ Wk_l,
    ushort* __restrict__ Wv_h, ushort* __restrict__ Wv_l,
    int M, int N, int K)
{
    const int t = threadIdx.x;
    const int lane = t & 63, wave = t >> 6;
    const int wr = wave >> 1, wc = wave & 1;
    const int lr = lane & 31, kg = lane >> 5;
    const int row_b = blockIdx.y * 128 + wr * 64;
    const int col_b = blockIdx.x * 128 + wc * 64;
    const int KB = K >> 3;

    const ushort *pAh[2], *pAl[2], *pBh[2], *pBl[2];
    #pragma unroll
    for (int mi = 0; mi < 2; ++mi) {
        int rb = row_b + mi*32; if (rb > M - 32) rb = M - 32;   // loads clamped
        size_t base = ((size_t)(rb >> 5) * KB + kg) * 256 + lr * 8;
        pAh[mi] = Ahi + base; pAl[mi] = Alo + base;
    }
    #pragma unroll
    for (int nj = 0; nj < 2; ++nj) {
        size_t base = ((size_t)((col_b + nj*32) >> 5) * KB + kg) * 256 + lr * 8;
        pBh[nj] = Bhi + base; pBl[nj] = Blo + base;
    }

    f32x16 acc[2][2];
    #pragma unroll
    for (int i = 0; i < 2; ++i)
        #pragma unroll
        for (int j = 0; j < 2; ++j)
            #pragma unroll
            for (int r = 0; r < 16; ++r) acc[i][j][r] = 0.f;

    bf16x8 a0h[2], a0l[2], b0h[2], b0l[2];
    bf16x8 a1h[2], a1l[2], b1h[2], b1l[2];

#define LOADF(AH, AL, BH, BL, OFF) do {                                        \
    _Pragma("unroll") for (int mi = 0; mi < 2; ++mi) {                         \
        AH[mi] = *reinterpret_cast<const bf16x8*>(pAh[mi] + (OFF));            \
        AL[mi] = *reinterpret_cast<const bf16x8*>(pAl[mi] + (OFF)); }          \
    _Pragma("unroll") for (int nj = 0; nj < 2; ++nj) {                         \
        BH[nj] = *reinterpret_cast<const bf16x8*>(pBh[nj] + (OFF));            \
        BL[nj] = *reinterpret_cast<const bf16x8*>(pBl[nj] + (OFF)); } } while(0)

#define MFMAF(AH, AL, BH, BL) do {                                             \
    _Pragma("unroll") for (int mi = 0; mi < 2; ++mi)                           \
    _Pragma("unroll") for (int nj = 0; nj < 2; ++nj) {                         \
        acc[mi][nj] = __builtin_amdgcn_mfma_f32_32x32x16_bf16(                 \
            AH[mi], BH[nj], acc[mi][nj], 0, 0, 0);                             \
        acc[mi][nj] = __builtin_amdgcn_mfma_f32_32x32x16_bf16(                 \
            AH[mi], BL[nj], acc[mi][nj], 0, 0, 0);                             \
        acc[mi][nj] = __builtin_amdgcn_mfma_f32_32x32x16_bf16(                 \
            AL[mi], BH[nj], acc[mi][nj], 0, 0, 0); } } while(0)

    LOADF(a0h, a0l, b0h, b0l, 0);
    for (int k0 = 0; k0 < K; k0 += 32) {
        size_t o1 = (size_t)((k0 + 16) >> 3) * 256;
        LOADF(a1h, a1l, b1h, b1l, o1);
        MFMAF(a0h, a0l, b0h, b0l);
        size_t o2 = (k0 + 32 < K) ? (size_t)((k0 + 32) >> 3) * 256 : 0;
        LOADF(a0h, a0l, b0h, b0l, o2);       // last iteration: harmless reload
        MFMAF(a1h, a1l, b1h, b1l);
    }
#undef LOADF
#undef MFMAF

    // epilogue: C/D map: col = lane&31, row31 = (r&3)+8*(r>>2)+4*kg
    #pragma unroll
    for (int mi = 0; mi < 2; ++mi) {
        int rb2 = row_b + mi*32;
        #pragma unroll
        for (int nj = 0; nj < 2; ++nj) {
            int colf = col_b + nj*32 + lr;
            float bv = bias[colf];
            if (OUT == 1) {
                size_t ftb = ((size_t)(rb2 >> 5) * (N >> 3) + (colf >> 3)) * 256 + (colf & 7);
                #pragma unroll
                for (int r = 0; r < 16; ++r) {
                    int r31 = (r & 3) + 8*(r >> 2) + 4*kg;
                    int row = rb2 + r31;
                    if (row >= M) continue;
                    float v = acc[mi][nj][r] + bv;
                    if (DO_RELU) v = fmaxf(v, 0.f);
                    size_t oo = ftb + (size_t)r31 * 8;
                    ushort hh = f2b_hi(v);
                    Chi[oo] = hh;
                    Clo[oo] = f2b_lo(v, hh);
                }
            } else {
                int sel = (col_b + nj*32) >> 8;   // 0=Q,1=K,2=V (tile-uniform)
                int h = (colf >> 5) & 7;
                int d = colf & 31;
                #pragma unroll
                for (int r = 0; r < 16; ++r) {
                    int r31 = (r & 3) + 8*(r >> 2) + 4*kg;
                    int row = rb2 + r31;
                    if (row >= M) continue;
                    float v = acc[mi][nj][r] + bv;
                    int bl = row / T_SEQ;
                    int tok = row - bl * T_SEQ;
                    size_t bb = (size_t)(bl*8 + h) * 12288;
                    ushort hh = f2b_hi(v);
                    ushort ll = f2b_lo(v, hh);
                    if (sel == 0) {
                        size_t o = bb + (size_t)((tok >> 5)*4 + (d >> 3))*256
                                 + ((tok & 31) << 3) + (d & 7);
                        Wq_h[o] = hh; Wq_l[o] = ll;
                    } else if (sel == 1) {
                        size_t o = bb + (size_t)((tok >> 5)*4 + (d >> 3))*256
                                 + ((tok & 31) << 3) + (d & 7);
                        Wk_h[o] = hh; Wk_l[o] = ll;
                    } else {
                        size_t o = bb + (size_t)(tok >> 3)*256 + d*8 + (tok & 7);
                        Wv_h[o] = hh; Wv_l[o] = ll;
                    }
                }
            }
        }
    }
}

// ------- split-bf16 MFMA GEMM fused with residual add + LayerNorm -------
// Block = 32 rows x 256 cols: wave w owns cols w*64..w*64+63 (1x2 frags of
// 32x32). x (FT hi/lo) is residual input AND LN output (in-place).
// v = A@B + bias + x; x = g*(v-mu)/sqrt(var+eps) + be. Requires M%32==0.
__global__ __launch_bounds__(256) void gemm_ln(
    const ushort* __restrict__ Ahi, const ushort* __restrict__ Alo,
    const ushort* __restrict__ Bhi, const ushort* __restrict__ Blo,
    const float* __restrict__ bias,
    ushort* __restrict__ xhi, ushort* __restrict__ xlo,
    const float* __restrict__ g, const float* __restrict__ be,
    int M, int K)
{
    const int N = HDIM;
    const int t = threadIdx.x;
    const int lane = t & 63, wave = t >> 6;
    const int lr = lane & 31, kg = lane >> 5;
    const int row_b = blockIdx.y * 32;
    const int col_w = wave * 64;
    const int KB = K >> 3;

    const ushort *pAh, *pAl, *pBh[2], *pBl[2];
    {
        size_t base = ((size_t)(row_b >> 5) * KB + kg) * 256 + lr * 8;
        pAh = Ahi + base; pAl = Alo + base;
    }
    #pragma unroll
    for (int nj = 0; nj < 2; ++nj) {
        size_t base = ((size_t)((col_w + nj*32) >> 5) * KB + kg) * 256 + lr * 8;
        pBh[nj] = Bhi + base; pBl[nj] = Blo + base;
    }

    f32x16 acc[2];
    #pragma unroll
    for (int j = 0; j < 2; ++j)
        #pragma unroll
        for (int r = 0; r < 16; ++r) acc[j][r] = 0.f;

    bf16x8 a0h, a0l, b0h[2], b0l[2];
    bf16x8 a1h, a1l, b1h[2], b1l[2];

#define LOADF(AH, AL, BH, BL, OFF) do {                                        \
    AH = *reinterpret_cast<const bf16x8*>(pAh + (OFF));                        \
    AL = *reinterpret_cast<const bf16x8*>(pAl + (OFF));                        \
    _Pragma("unroll") for (int nj = 0; nj < 2; ++nj) {                         \
        BH[nj] = *reinterpret_cast<const bf16x8*>(pBh[nj] + (OFF));            \
        BL[nj] = *reinterpret_cast<const bf16x8*>(pBl[nj] + (OFF)); } } while(0)

#define MFMAF(AH, AL, BH, BL) do {                                             \
    _Pragma("unroll") for (int nj = 0; nj < 2; ++nj) {                         \
        acc[nj] = __builtin_amdgcn_mfma_f32_32x32x16_bf16(                     \
            AH, BH[nj], acc[nj], 0, 0, 0);                                     \
        acc[nj] = __builtin_amdgcn_mfma_f32_32x32x16_bf16(                     \
            AH, BL[nj], acc[nj], 0, 0, 0);                                     \
        acc[nj] = __builtin_amdgcn_mfma_f32_32x32x16_bf16(                     \
            AL, BH[nj], acc[nj], 0, 0, 0); } } while(0)

    LOADF(a0h, a0l, b0h, b0l, 0);
    for (int k0 = 0; k0 < K; k0 += 32) {
        size_t o1 = (size_t)((k0 + 16) >> 3) * 256;
        LOADF(a1h, a1l, b1h, b1l, o1);
        MFMAF(a0h, a0l, b0h, b0l);
        size_t o2 = (k0 + 32 < K) ? (size_t)((k0 + 32) >> 3) * 256 : 0;
        LOADF(a0h, a0l, b0h, b0l, o2);
        MFMAF(a1h, a1l, b1h, b1l);
    }
#undef LOADF
#undef MFMAF

    // v = acc + bias + residual; per-row sum/sumsq (this lane: 2 cols/row)
    float s1[16], s2[16];
    #pragma unroll
    for (int nj = 0; nj < 2; ++nj) {
        int col = col_w + nj*32 + lr;
        float bv = bias[col];
        #pragma unroll
        for (int r = 0; r < 16; ++r) {
            int r31 = (r & 3) + 8*(r >> 2) + 4*kg;
            int row = row_b + r31;          // M%32==0 -> always < M
            size_t oo = ((size_t)(row >> 5) * (N >> 3) + (col >> 3)) * 256
                      + ((row & 31) << 3) + (col & 7);
            float v = acc[nj][r] + bv + b2f(xhi[oo]) + b2f(xlo[oo]);
            acc[nj][r] = v;
            if (nj == 0) { s1[r] = v;  s2[r] = v*v; }
            else         { s1[r] += v; s2[r] += v*v; }
        }
    }
    // butterfly over the 32-lane (same kg) group
    #pragma unroll
    for (int r = 0; r < 16; ++r) {
        #pragma unroll
        for (int off = 1; off <= 16; off <<= 1) {
            s1[r] += __shfl_xor(s1[r], off);
            s2[r] += __shfl_xor(s2[r], off);
        }
    }
    __shared__ float red1[4][32];
    __shared__ float red2[4][32];
    __shared__ float tot1[32];
    __shared__ float tot2[32];
    if (lr == 0) {
        #pragma unroll
        for (int r = 0; r < 16; ++r) {
            int rr = (r & 3) + 8*(r >> 2) + 4*kg;
            red1[wave][rr] = s1[r];
            red2[wave][rr] = s2[r];
        }
    }
    __syncthreads();
    if (t < 32) {
        tot1[t] = red1[0][t] + red1[1][t] + red1[2][t] + red1[3][t];
        tot2[t] = red2[0][t] + red2[1][t] + red2[2][t] + red2[3][t];
    }
    __syncthreads();
    // normalize + write
    #pragma unroll
    for (int r = 0; r < 16; ++r) {
        int r31 = (r & 3) + 8*(r >> 2) + 4*kg;
        int row = row_b + r31;
        float mu = tot1[r31] * (1.f/256.f);
        float var = fmaf(-mu, mu, tot2[r31] * (1.f/256.f));
        float rs = rsqrtf(var + 1e-5f);
        #pragma unroll
        for (int nj = 0; nj < 2; ++nj) {
            int col = col_w + nj*32 + lr;
            float o = g[col] * (acc[nj][r] - mu) * rs + be[col];
            size_t oo = ((size_t)(row >> 5) * (N >> 3) + (col >> 3)) * 256
                      + ((row & 31) << 3) + (col & 7);
            ushort hh = f2b_hi(o);
            xhi[oo] = hh;
            xlo[oo] = f2b_lo(o, hh);
        }
    }
}

// ---------------- MFMA attention: 1 wave per (b,h,q-tile) ----------------
__global__ __launch_bounds__(256) void attn_mfma(
    const ushort* __restrict__ Qh, const ushort* __restrict__ Ql,
    const ushort* __restrict__ Kh, const ushort* __restrict__ Kl,
    const ushort* __restrict__ Vh, const ushort* __restrict__ Vl,
    ushort* __restrict__ ahi, ushort* __restrict__ alo)
{
    const int bh = blockIdx.y;
    const int wave = threadIdx.x >> 6, lane = threadIdx.x & 63;
    const int qt = blockIdx.x * 4 + wave;   // 0..11
    const int lr = lane & 31, kg = lane >> 5;
    const size_t base = (size_t)bh * 12288;
    const float scale = 0.17677669529663687f; // 1/sqrt(32)

    bf16x8 qfh[2], qfl[2];
    #pragma unroll
    for (int ks = 0; ks < 2; ++ks) {
        size_t o = base + (size_t)(qt*4 + ks*2 + kg)*256 + lr*8;
        qfh[ks] = *reinterpret_cast<const bf16x8*>(Qh + o);
        qfl[ks] = *reinterpret_cast<const bf16x8*>(Ql + o);
    }

    float m = -3e38f;
    for (int kt = 0; kt < 12; ++kt) {
        f32x16 st;
        #pragma unroll
        for (int r = 0; r < 16; ++r) st[r] = 0.f;
        #pragma unroll
        for (int ks = 0; ks < 2; ++ks) {
            size_t o = base + (size_t)(kt*4 + ks*2 + kg)*256 + lr*8;
            bf16x8 kfh = *reinterpret_cast<const bf16x8*>(Kh + o);
            bf16x8 kfl = *reinterpret_cast<const bf16x8*>(Kl + o);
            st = __builtin_amdgcn_mfma_f32_32x32x16_bf16(kfh, qfh[ks], st, 0,0,0);
            st = __builtin_amdgcn_mfma_f32_32x32x16_bf16(kfh, qfl[ks], st, 0,0,0);
            st = __builtin_amdgcn_mfma_f32_32x32x16_bf16(kfl, qfh[ks], st, 0,0,0);
        }
        #pragma unroll
        for (int r = 0; r < 16; ++r) {
            int krow = kt*32 + (r & 3) + 8*(r >> 2) + 4*kg;
            m = fmaxf(m, (krow < T_SEQ) ? st[r] : -3e38f);
        }
    }
    m = fmaxf(m, __shfl_xor(m, 32));

    f32x16 oacc;
    #pragma unroll
    for (int r = 0; r < 16; ++r) oacc[r] = 0.f;
    float l = 0.f;

    for (int kt = 0; kt < 12; ++kt) {
        f32x16 st;
        #pragma unroll
        for (int r = 0; r < 16; ++r) st[r] = 0.f;
        #pragma unroll
        for (int ks = 0; ks < 2; ++ks) {
            size_t o = base + (size_t)(kt*4 + ks*2 + kg)*256 + lr*8;
            bf16x8 kfh = *reinterpret_cast<const bf16x8*>(Kh + o);
            bf16x8 kfl = *reinterpret_cast<const bf16x8*>(Kl + o);
            st = __builtin_amdgcn_mfma_f32_32x32x16_bf16(kfh, qfh[ks], st, 0,0,0);
            st = __builtin_amdgcn_mfma_f32_32x32x16_bf16(kfh, qfl[ks], st, 0,0,0);
            st = __builtin_amdgcn_mfma_f32_32x32x16_bf16(kfl, qfh[ks], st, 0,0,0);
        }
        float p[16];
        #pragma unroll
        for (int r = 0; r < 16; ++r) {
            int krow = kt*32 + (r & 3) + 8*(r >> 2) + 4*kg;
            float sv = (krow < T_SEQ) ? st[r] : -3e38f;
            float e = __expf((sv - m) * scale);
            p[r] = e; l += e;
        }
        float pp[16];
        #pragma unroll
        for (int r = 0; r < 16; ++r) pp[r] = __shfl_xor(p[r], 32);
        #pragma unroll
        for (int ks = 0; ks < 2; ++ks) {
            union { u16x8 u; bf16x8 b; } fh, fl;
            #pragma unroll
            for (int j = 0; j < 8; ++j) {
                float e;
                if (ks == 0)
                    e = kg ? ((j < 4) ? pp[4+j] : p[j])
                           : ((j < 4) ? p[j]    : pp[j-4]);
                else
                    e = kg ? ((j < 4) ? pp[12+j] : p[8+j])
                           : ((j < 4) ? p[8+j]   : pp[4+j]);
                ushort hh = f2b_hi(e);
                fh.u[j] = hh;
                fl.u[j] = f2b_lo(e, hh);
            }
            size_t vo = base + (size_t)(kt*4 + ks*2 + kg)*256 + lr*8;
            bf16x8 vfh = *reinterpret_cast<const bf16x8*>(Vh + vo);
            bf16x8 vfl = *reinterpret_cast<const bf16x8*>(Vl + vo);
            oacc = __builtin_amdgcn_mfma_f32_32x32x16_bf16(fh.b, vfh, oacc, 0,0,0);
            oacc = __builtin_amdgcn_mfma_f32_32x32x16_bf16(fh.b, vfl, oacc, 0,0,0);
            oacc = __builtin_amdgcn_mfma_f32_32x32x16_bf16(fl.b, vfh, oacc, 0,0,0);
        }
    }
    l += __shfl_xor(l, 32);
    float il = 1.f / l;

    const int bl = bh >> 3, h = bh & 7;
    #pragma unroll
    for (int r = 0; r < 16; ++r) {
        int q = (r & 3) + 8*(r >> 2) + 4*kg;
        float sc = __shfl(il, q);
        int row_local = qt*32 + q;
        if (row_local < T_SEQ) {
            float v = oacc[r] * sc;
            int grow = bl*T_SEQ + row_local;
            int col = h*32 + lr;
            size_t o = ((size_t)(grow >> 5)*32 + (col >> 3))*256
                     + ((grow & 31) << 3) + (col & 7);
            ushort hh = f2b_hi(v);
            ahi[o] = hh;
            alo[o] = f2b_lo(v, hh);
        }
    }
}

// -------- mean-pool + output head (reads FT hi/lo stream) --------
__global__ __launch_bounds__(256) void head_kernel(
    const ushort* __restrict__ xhi, const ushort* __restrict__ xlo,
    const float* __restrict__ sfeat,
    const float* __restrict__ W1, const float* __restrict__ b1,
    const float* __restrict__ W2, const float* __restrict__ b2,
    const float* __restrict__ scale, const float* __restrict__ shift,
    float* __restrict__ out)
{
    __shared__ float p[HDIM];
    __shared__ float h1[HDIM/2];
    int b = blockIdx.x, t = threadIdx.x;
    float acc = 0.f;
    for (int tt = 0; tt < T_SEQ; ++tt) {
        size_t row = (size_t)b*T_SEQ + tt;
        size_t o = ((row >> 5) * 32 + (t >> 3)) * 256 + ((row & 31) << 3) + (t & 7);
        acc += b2f(xhi[o]) + b2f(xlo[o]);
    }
    p[t] = acc * (1.f/365.f) + sfeat[(size_t)b*HDIM + t];
    __syncthreads();
    if (t < HDIM/2) {
        float a = b1[t];
        for (int c = 0; c < HDIM; ++c) a = fmaf(p[c], W1[c*(HDIM/2) + t], a);
        h1[t] = gelu_f(a);
    }
    __syncthreads();
    if (t < 30) {
        float a = b2[t];
        for (int j = 0; j < HDIM/2; ++j) a = fmaf(h1[j], W2[j*30 + t], a);
        out[b*30 + t] = tanhf(a) * scale[0] + shift[0];
    }
}

extern "C" void kernel_launch(void* const* d_in, const int* in_sizes, int n_in,
                              void* d_out, int out_size, void* d_ws, size_t ws_size,
                              hipStream_t stream) {
    const float* p_static = (const float*)d_in[0];
    const float* p_dyn    = (const float*)d_in[1];
    const float* p_lat    = (const float*)d_in[2];
    const float* p_lon    = (const float*)d_in[3];
    const float* p_all    = (const float*)d_in[4];
    const float* p_coords = (const float*)d_in[5];
    const float* p_Wst    = (const float*)d_in[6];
    const float* p_bst    = (const float*)d_in[7];
    const float* p_gst    = (const float*)d_in[8];
    const float* p_best   = (const float*)d_in[9];
    const float* p_Wdy    = (const float*)d_in[10];
    const float* p_bdy    = (const float*)d_in[11];
    const float* p_gdy    = (const float*)d_in[12];
    const float* p_bedy   = (const float*)d_in[13];
    const float* p_Wqkv   = (const float*)d_in[14];
    const float* p_bqkv   = (const float*)d_in[15];
    const float* p_Wo     = (const float*)d_in[16];
    const float* p_bo     = (const float*)d_in[17];
    const float* p_gln1   = (const float*)d_in[18];
    const float* p_beln1  = (const float*)d_in[19];
    const float* p_Wf1    = (const float*)d_in[20];
    const float* p_bf1    = (const float*)d_in[21];
    const float* p_Wf2    = (const float*)d_in[22];
    const float* p_bf2    = (const float*)d_in[23];
    const float* p_gln2   = (const float*)d_in[24];
    const float* p_beln2  = (const float*)d_in[25];
    const float* p_Wo1    = (const float*)d_in[26];
    const float* p_bo1    = (const float*)d_in[27];
    const float* p_Wo2    = (const float*)d_in[28];
    const float* p_bo2    = (const float*)d_in[29];
    const float* p_scale  = (const float*)d_in[30];
    const float* p_shift  = (const float*)d_in[31];
    float* out = (float*)d_out;
    (void)in_sizes; (void)n_in; (void)out_size;

    char* ws = (char*)d_ws;
    size_t off = 0;
    auto alloc = [&](size_t bytes) -> void* {
        void* p = ws + off;
        off += (bytes + 255) & ~(size_t)255;
        return p;
    };
    const int ROWS = BATCH * T_SEQ; // 93440 (%32 == 0)
    int*    nbr   = (int*)   alloc((size_t)BATCH*KNB*sizeof(int));
    float*  sfeat = (float*) alloc((size_t)BATCH*HDIM*sizeof(float));
    ushort* xhi   = (ushort*)alloc((size_t)ROWS*HDIM*sizeof(ushort));
    ushort* xlo   = (ushort*)alloc((size_t)ROWS*HDIM*sizeof(ushort));
    const size_t SZ_QKV = (size_t)4*768*256, SZ_O = (size_t)4*256*256;
    const size_t SZ_F1  = (size_t)4*1024*256, SZ_F2 = (size_t)4*256*1024;
    ushort* Wqkvt_h = (ushort*)alloc(SZ_QKV*2*sizeof(ushort)); ushort* Wqkvt_l = Wqkvt_h + SZ_QKV;
    ushort* Wot_h   = (ushort*)alloc(SZ_O  *2*sizeof(ushort)); ushort* Wot_l   = Wot_h   + SZ_O;
    ushort* Wf1t_h  = (ushort*)alloc(SZ_F1 *2*sizeof(ushort)); ushort* Wf1t_l  = Wf1t_h  + SZ_F1;
    ushort* Wf2t_h  = (ushort*)alloc(SZ_F2 *2*sizeof(ushort)); ushort* Wf2t_l  = Wf2t_h  + SZ_F2;
    size_t fixed = off;

    // per-chunk union region: QKV-split (6 x CH*8*12288 ushorts) during attn,
    // OR hbuf hi/lo (CH*1,495,040 B) during FF. aatt separate.
    const size_t PER_B = (size_t)T_SEQ * 1024 * 4;   // 1,495,040
    const size_t PER_A = (size_t)T_SEQ * 256 * 4;    // aatt hi+lo
    const size_t PER_CH = PER_B + PER_A;
    int CH = 32;
    {
        const int tiers[5] = {256, 192, 128, 96, 64};
        for (int i = 0; i < 5; ++i) {
            if (fixed + (size_t)tiers[i]*PER_CH + 8192 <= ws_size) { CH = tiers[i]; break; }
        }
    }
    char*   big    = (char*)alloc((size_t)CH * PER_B);
    ushort* aatt_h = (ushort*)alloc((size_t)CH * PER_A);
    const int RW = CH * T_SEQ;
    ushort* aatt_l = aatt_h + (size_t)RW * HDIM;
    const size_t seg = (size_t)CH * 8 * 12288;       // ushorts per QKV buffer
    ushort* Qh  = (ushort*)big;
    ushort* Ql  = Qh  + seg;
    ushort* Kh2 = Ql  + seg;
    ushort* Kl2 = Kh2 + seg;
    ushort* Vth = Kl2 + seg;
    ushort* Vtl = Vth + seg;
    ushort* hbuf_h = (ushort*)big;
    ushort* hbuf_l = hbuf_h + (size_t)RW * FFDIM;
    const int GY  = (RW + 127) / 128;   // 128-row tiles (guarded)
    const int GY3 = RW / 32;            // 32-row tiles (exact: RW%32==0)

    topk_kernel <<<BATCH, 256, 0, stream>>>(p_lat, p_lon, p_coords, nbr);
    sfeat_kernel<<<BATCH, 256, 0, stream>>>(p_static, p_all, nbr, p_Wst, p_bst, p_gst, p_best, sfeat);
    dyn_kernel  <<<ROWS/4, 256, 0, stream>>>(p_dyn, p_Wdy, p_bdy, p_gdy, p_bedy, sfeat, xhi, xlo);
    tsplit_kernel<<<dim3(24, 8, 4), 256, 0, stream>>>(p_Wqkv, Wqkvt_h, Wqkvt_l, 256, 768);
    tsplit_kernel<<<dim3( 8, 8, 4), 256, 0, stream>>>(p_Wo,   Wot_h,   Wot_l,   256, 256);
    tsplit_kernel<<<dim3(32, 8, 4), 256, 0, stream>>>(p_Wf1,  Wf1t_h,  Wf1t_l,  256, 1024);
    tsplit_kernel<<<dim3( 8,32, 4), 256, 0, stream>>>(p_Wf2,  Wf2t_h,  Wf2t_l,  1024, 256);

    const int NCHUNK = BATCH / CH;
    for (int c = 0; c < NCHUNK; ++c) {
        size_t co = (size_t)c * CH * T_SEQ * HDIM;
        ushort* xhic = xhi + co;
        ushort* xloc = xlo + co;
        for (int l = 0; l < 4; ++l) {
            gemm_mfma<0,2><<<dim3(6, GY), 256, 0, stream>>>(
                xhic, xloc, Wqkvt_h + (size_t)l*768*256, Wqkvt_l + (size_t)l*768*256,
                p_bqkv + l*768, nullptr, nullptr,
                Qh, Ql, Kh2, Kl2, Vth, Vtl, RW, 768, 256);
            attn_mfma<<<dim3(3, CH*8), 256, 0, stream>>>(
                Qh, Ql, Kh2, Kl2, Vth, Vtl, aatt_h, aatt_l);
            gemm_ln<<<dim3(1, GY3), 256, 0, stream>>>(
                aatt_h, aatt_l, Wot_h + (size_t)l*256*256, Wot_l + (size_t)l*256*256,
                p_bo + l*256, xhic, xloc, p_gln1 + l*256, p_beln1 + l*256, RW, 256);
            gemm_mfma<1,1><<<dim3(8, GY), 256, 0, stream>>>(
                xhic, xloc, Wf1t_h + (size_t)l*1024*256, Wf1t_l + (size_t)l*1024*256,
                p_bf1 + l*1024, hbuf_h, hbuf_l,
                nullptr, nullptr, nullptr, nullptr, nullptr, nullptr, RW, 1024, 256);
            gemm_ln<<<dim3(1, GY3), 256, 0, stream>>>(
                hbuf_h, hbuf_l, Wf2t_h + (size_t)l*256*1024, Wf2t_l + (size_t)l*256*1024,
                p_bf2 + l*256, xhic, xloc, p_gln2 + l*256, p_beln2 + l*256, RW, 1024);
        }
    }
    head_kernel<<<BATCH, 256, 0, stream>>>(xhi, xlo, sfeat, p_Wo1, p_bo1, p_Wo2, p_bo2, p_scale, p_shift, out);
}

// Round 10
// 4584.050 us; speedup vs baseline: 10.2154x; 1.0881x over previous
//
#include <hip/hip_runtime.h>
#include <math.h>

#define T_SEQ 365
#define HDIM 256
#define NHEADS 8
#define HD 32
#define BATCH 256
#define DDIM 16
#define FFDIM 1024
#define NST 10000
#define KNB 5
#define SDIM 64

typedef __bf16 bf16x8 __attribute__((ext_vector_type(8)));
typedef float  f32x16 __attribute__((ext_vector_type(16)));
typedef unsigned short u16x8 __attribute__((ext_vector_type(8)));

__device__ __forceinline__ ushort f2b_hi(float v) {
    unsigned u = __float_as_uint(v);
    unsigned r = u + 0x7fffu + ((u >> 16) & 1u);
    return (ushort)(r >> 16);
}
__device__ __forceinline__ float b2f(ushort h) {
    return __uint_as_float(((unsigned)h) << 16);
}
__device__ __forceinline__ ushort f2b_lo(float v, ushort hi) {
    return f2b_hi(v - b2f(hi));
}

__device__ __forceinline__ float gelu_f(float x) {
    return 0.5f * x * (1.f + erff(x * 0.70710678118654752f));
}

// FT (fragment-tiled) layout for a [R][C] bf16 matrix, C%8==0:
// offset(r,c) = ((r>>5)*(C>>3) + (c>>3))*256 + (r&31)*8 + (c&7)
// Per-(b,h) attention buffers: Q,K = FT over [384 tok][32 d] (12288 ushorts);
// V^T = FT over [32 d][384 tok]: offset(d,tok) = (tok>>3)*256 + d*8 + (tok&7).

// block-wide (256 threads = 4 waves) sum; sred must be float[4] shared
__device__ __forceinline__ float block_sum256(float v, float* sred) {
    #pragma unroll
    for (int off = 32; off; off >>= 1) v += __shfl_xor(v, off);
    int wave = threadIdx.x >> 6;
    if ((threadIdx.x & 63) == 0) sred[wave] = v;
    __syncthreads();
    float s = sred[0] + sred[1] + sred[2] + sred[3];
    __syncthreads();
    return s;
}

// ---------------- top-K neighbor search ----------------
__global__ __launch_bounds__(256) void topk_kernel(
    const float* __restrict__ lat, const float* __restrict__ lon,
    const float* __restrict__ coords, int* __restrict__ nbr)
{
    __shared__ float hav[NST];
    __shared__ float rv[256];
    __shared__ int   ri[256];
    const float DEG = 0.017453292519943295f;
    int b = blockIdx.x, t = threadIdx.x;
    float lat_o = (lat[b] + 1.f) * 0.5f * 25.f + 24.f;
    float lon_o = (lon[b] + 1.f) * 0.5f * 58.5f - 125.f;
    float qlat = lat_o * DEG, qlon = lon_o * DEG;
    float cq = cosf(qlat);
    for (int i = t; i < NST; i += 256) {
        float slat = coords[2*i], slon = coords[2*i+1];
        float dlat = qlat - slat, dlon = qlon - slon;
        float s1 = sinf(dlat * 0.5f), s2 = sinf(dlon * 0.5f);
        hav[i] = s1*s1 + cq * cosf(slat) * s2*s2;
    }
    __syncthreads();
    for (int sel = 0; sel < KNB + 1; ++sel) {
        float bv = 1e30f; int bi = 0x7fffffff;
        for (int i = t; i < NST; i += 256) {
            float v = hav[i];
            if (v < bv || (v == bv && i < bi)) { bv = v; bi = i; }
        }
        rv[t] = bv; ri[t] = bi;
        __syncthreads();
        for (int s = 128; s > 0; s >>= 1) {
            if (t < s) {
                float ov = rv[t+s]; int oi = ri[t+s];
                if (ov < rv[t] || (ov == rv[t] && oi < ri[t])) { rv[t] = ov; ri[t] = oi; }
            }
            __syncthreads();
        }
        if (t == 0) {
            if (sel > 0) nbr[b*KNB + sel - 1] = ri[0];
            hav[ri[0]] = 1e30f;   // mask winner
        }
        __syncthreads();
    }
}

// ---------------- static-feature branch ----------------
__global__ __launch_bounds__(256) void sfeat_kernel(
    const float* __restrict__ stat, const float* __restrict__ all_st,
    const int* __restrict__ nbr, const float* __restrict__ W,
    const float* __restrict__ bias, const float* __restrict__ g,
    const float* __restrict__ be, float* __restrict__ sfeat)
{
    __shared__ float comb[(KNB+1)*SDIM]; // 384
    __shared__ float sred[4];
    int b = blockIdx.x, t = threadIdx.x;
    for (int i = t; i < (KNB+1)*SDIM; i += 256) {
        if (i < SDIM) comb[i] = stat[b*SDIM + i];
        else {
            int n = (i - SDIM) >> 6, d = (i - SDIM) & 63;
            comb[i] = all_st[(size_t)nbr[b*KNB + n] * SDIM + d];
        }
    }
    __syncthreads();
    float acc = bias[t];
    for (int j = 0; j < (KNB+1)*SDIM; ++j)
        acc = fmaf(comb[j], W[j*HDIM + t], acc);
    float mu  = block_sum256(acc, sred) * (1.f/256.f);
    float d   = acc - mu;
    float var = block_sum256(d*d, sred) * (1.f/256.f);
    float y = g[t] * d * rsqrtf(var + 1e-5f) + be[t];
    sfeat[(size_t)b*HDIM + t] = gelu_f(y);
}

// ------ dynamic embedding (per-chunk): 4 rows/block, wave per row ------
// dynv/sfeatc pre-offset to the chunk; writes chunk-local FT x hi/lo.
__global__ __launch_bounds__(256) void dyn_kernel(
    const float* __restrict__ dynv, const float* __restrict__ W,
    const float* __restrict__ bias, const float* __restrict__ g,
    const float* __restrict__ be, const float* __restrict__ sfeatc,
    ushort* __restrict__ xhi, ushort* __restrict__ xlo)
{
    __shared__ float w[DDIM*HDIM];   // 16 KB
    __shared__ float dr[4][DDIM];
    int wave = threadIdx.x >> 6, lane = threadIdx.x & 63;
    int row0 = blockIdx.x * 4;
    for (int i = threadIdx.x; i < DDIM*HDIM; i += 256) w[i] = W[i];
    if (lane < DDIM)
        dr[wave][lane] = dynv[(size_t)(row0 + wave)*DDIM + lane];
    __syncthreads();
    int row = row0 + wave;
    int b = row / T_SEQ;     // chunk-local batch index
    int c0 = lane * 4;
    float v0 = bias[c0], v1 = bias[c0+1], v2 = bias[c0+2], v3 = bias[c0+3];
    #pragma unroll
    for (int k = 0; k < DDIM; ++k) {
        float dk = dr[wave][k];
        float4 wv = *reinterpret_cast<const float4*>(&w[k*HDIM + c0]);
        v0 = fmaf(dk, wv.x, v0); v1 = fmaf(dk, wv.y, v1);
        v2 = fmaf(dk, wv.z, v2); v3 = fmaf(dk, wv.w, v3);
    }
    float s = v0 + v1 + v2 + v3;
    #pragma unroll
    for (int off = 32; off; off >>= 1) s += __shfl_xor(s, off);
    float mu = s * (1.f/256.f);
    float d0 = v0-mu, d1 = v1-mu, d2 = v2-mu, d3 = v3-mu;
    float s2 = d0*d0 + d1*d1 + d2*d2 + d3*d3;
    #pragma unroll
    for (int off = 32; off; off >>= 1) s2 += __shfl_xor(s2, off);
    float rs = rsqrtf(s2 * (1.f/256.f) + 1e-5f);
    float4 gg = *reinterpret_cast<const float4*>(&g[c0]);
    float4 bb = *reinterpret_cast<const float4*>(&be[c0]);
    float4 sf = *reinterpret_cast<const float4*>(&sfeatc[(size_t)b*HDIM + c0]);
    float o0 = gelu_f(gg.x*d0*rs + bb.x) + sf.x;
    float o1 = gelu_f(gg.y*d1*rs + bb.y) + sf.y;
    float o2 = gelu_f(gg.z*d2*rs + bb.z) + sf.z;
    float o3 = gelu_f(gg.w*d3*rs + bb.w) + sf.w;
    size_t o = ((size_t)(row >> 5) * 32 + (c0 >> 3)) * 256 + ((row & 31) << 3) + (c0 & 7);
    ushort4 hv, lv;
    hv.x = f2b_hi(o0); lv.x = f2b_lo(o0, hv.x);
    hv.y = f2b_hi(o1); lv.y = f2b_lo(o1, hv.y);
    hv.z = f2b_hi(o2); lv.z = f2b_lo(o2, hv.z);
    hv.w = f2b_hi(o3); lv.w = f2b_lo(o3, hv.w);
    *reinterpret_cast<ushort4*>(&xhi[o]) = hv;
    *reinterpret_cast<ushort4*>(&xlo[o]) = lv;
}

// --- weight transpose + split: W[L][K][N] -> FT([N][K]) hi/lo per layer ---
__global__ __launch_bounds__(256) void tsplit_kernel(
    const float* __restrict__ W, ushort* __restrict__ hi, ushort* __restrict__ lo,
    int K, int N)
{
    __shared__ float tile[32][33];
    size_t l = blockIdx.z;
    const float* Wl = W + l*(size_t)K*N;
    ushort* hil = hi + l*(size_t)K*N;
    ushort* lol = lo + l*(size_t)K*N;
    int n0 = blockIdx.x*32, k0 = blockIdx.y*32;
    int tx = threadIdx.x & 31, ty = threadIdx.x >> 5;
    int KB = K >> 3;
    for (int i = ty; i < 32; i += 8) tile[i][tx] = Wl[(size_t)(k0+i)*N + n0 + tx];
    __syncthreads();
    for (int i = ty; i < 32; i += 8) {
        float v = tile[tx][i];              // (k=k0+tx, n=n0+i)
        ushort h = f2b_hi(v);
        size_t o = ((size_t)(n0 >> 5) * KB + (k0 >> 3) + (tx >> 3)) * 256
                 + ((size_t)i << 3) + (tx & 7);
        hil[o] = h;
        lol[o] = f2b_lo(v, h);
    }
}

// ---------------- split-bf16 MFMA GEMM, FT operands, no LDS ----------------
// OUT=1: write FT hi/lo (Chi/Clo). OUT=2: scatter Q/K/V into per-(b,h)
// attention layouts (Q,K: FT [384][32]; V: transposed FT [32][384]).
template<int DO_RELU, int OUT>
__global__ __launch_bounds__(256) void gemm_mfma(
    const ushort* __restrict__ Ahi, const ushort* __restrict__ Alo,
    const ushort* __restrict__ Bhi, const ushort* __restrict__ Blo,
    const float* __restrict__ bias,
    ushort* __restrict__ Chi, ushort* __restrict__ Clo,
    ushort* __restrict__ Wq_h, ushort* __restrict__ Wq_l,
    ushort* __restrict__ Wk_h, ushort* __restrict__ Wk_l,
    ushort* __restrict__ Wv_h, ushort* __restrict__ Wv_l,
    int M, int N, int K)
{
    const int t = threadIdx.x;
    const int lane = t & 63, wave = t >> 6;
    const int wr = wave >> 1, wc = wave & 1;
    const int lr = lane & 31, kg = lane >> 5;
    const int row_b = blockIdx.y * 128 + wr * 64;
    const int col_b = blockIdx.x * 128 + wc * 64;
    const int KB = K >> 3;

    const ushort *pAh[2], *pAl[2], *pBh[2], *pBl[2];
    #pragma unroll
    for (int mi = 0; mi < 2; ++mi) {
        int rb = row_b + mi*32; if (rb > M - 32) rb = M - 32;   // loads clamped
        size_t base = ((size_t)(rb >> 5) * KB + kg) * 256 + lr * 8;
        pAh[mi] = Ahi + base; pAl[mi] = Alo + base;
    }
    #pragma unroll
    for (int nj = 0; nj < 2; ++nj) {
        size_t base = ((size_t)((col_b + nj*32) >> 5) * KB + kg) * 256 + lr * 8;
        pBh[nj] = Bhi + base; pBl[nj] = Blo + base;
    }

    f32x16 acc[2][2];
    #pragma unroll
    for (int i = 0; i < 2; ++i)
        #pragma unroll
        for (int j = 0; j < 2; ++j)
            #pragma unroll
            for (int r = 0; r < 16; ++r) acc[i][j][r] = 0.f;

    bf16x8 a0h[2], a0l[2], b0h[2], b0l[2];
    bf16x8 a1h[2], a1l[2], b1h[2], b1l[2];

#define LOADF(AH, AL, BH, BL, OFF) do {                                        \
    _Pragma("unroll") for (int mi = 0; mi < 2; ++mi) {                         \
        AH[mi] = *reinterpret_cast<const bf16x8*>(pAh[mi] + (OFF));            \
        AL[mi] = *reinterpret_cast<const bf16x8*>(pAl[mi] + (OFF)); }          \
    _Pragma("unroll") for (int nj = 0; nj < 2; ++nj) {                         \
        BH[nj] = *reinterpret_cast<const bf16x8*>(pBh[nj] + (OFF));            \
        BL[nj] = *reinterpret_cast<const bf16x8*>(pBl[nj] + (OFF)); } } while(0)

#define MFMAF(AH, AL, BH, BL) do {                                             \
    _Pragma("unroll") for (int mi = 0; mi < 2; ++mi)                           \
    _Pragma("unroll") for (int nj = 0; nj < 2; ++nj) {                         \
        acc[mi][nj] = __builtin_amdgcn_mfma_f32_32x32x16_bf16(                 \
            AH[mi], BH[nj], acc[mi][nj], 0, 0, 0);                             \
        acc[mi][nj] = __builtin_amdgcn_mfma_f32_32x32x16_bf16(                 \
            AH[mi], BL[nj], acc[mi][nj], 0, 0, 0);                             \
        acc[mi][nj] = __builtin_amdgcn_mfma_f32_32x32x16_bf16(                 \
            AL[mi], BH[nj], acc[mi][nj], 0, 0, 0); } } while(0)

    LOADF(a0h, a0l, b0h, b0l, 0);
    for (int k0 = 0; k0 < K; k0 += 32) {
        size_t o1 = (size_t)((k0 + 16) >> 3) * 256;
        LOADF(a1h, a1l, b1h, b1l, o1);
        MFMAF(a0h, a0l, b0h, b0l);
        size_t o2 = (k0 + 32 < K) ? (size_t)((k0 + 32) >> 3) * 256 : 0;
        LOADF(a0h, a0l, b0h, b0l, o2);       // last iteration: harmless reload
        MFMAF(a1h, a1l, b1h, b1l);
    }
#undef LOADF
#undef MFMAF

    // epilogue: C/D map: col = lane&31, row31 = (r&3)+8*(r>>2)+4*kg
    #pragma unroll
    for (int mi = 0; mi < 2; ++mi) {
        int rb2 = row_b + mi*32;
        #pragma unroll
        for (int nj = 0; nj < 2; ++nj) {
            int colf = col_b + nj*32 + lr;
            float bv = bias[colf];
            if (OUT == 1) {
                size_t ftb = ((size_t)(rb2 >> 5) * (N >> 3) + (colf >> 3)) * 256 + (colf & 7);
                #pragma unroll
                for (int r = 0; r < 16; ++r) {
                    int r31 = (r & 3) + 8*(r >> 2) + 4*kg;
                    int row = rb2 + r31;
                    if (row >= M) continue;
                    float v = acc[mi][nj][r] + bv;
                    if (DO_RELU) v = fmaxf(v, 0.f);
                    size_t oo = ftb + (size_t)r31 * 8;
                    ushort hh = f2b_hi(v);
                    Chi[oo] = hh;
                    Clo[oo] = f2b_lo(v, hh);
                }
            } else {
                int sel = (col_b + nj*32) >> 8;   // 0=Q,1=K,2=V (tile-uniform)
                int h = (colf >> 5) & 7;
                int d = colf & 31;
                #pragma unroll
                for (int r = 0; r < 16; ++r) {
                    int r31 = (r & 3) + 8*(r >> 2) + 4*kg;
                    int row = rb2 + r31;
                    if (row >= M) continue;
                    float v = acc[mi][nj][r] + bv;
                    int bl = row / T_SEQ;
                    int tok = row - bl * T_SEQ;
                    size_t bb = (size_t)(bl*8 + h) * 12288;
                    ushort hh = f2b_hi(v);
                    ushort ll = f2b_lo(v, hh);
                    if (sel == 0) {
                        size_t o = bb + (size_t)((tok >> 5)*4 + (d >> 3))*256
                                 + ((tok & 31) << 3) + (d & 7);
                        Wq_h[o] = hh; Wq_l[o] = ll;
                    } else if (sel == 1) {
                        size_t o = bb + (size_t)((tok >> 5)*4 + (d >> 3))*256
                                 + ((tok & 31) << 3) + (d & 7);
                        Wk_h[o] = hh; Wk_l[o] = ll;
                    } else {
                        size_t o = bb + (size_t)(tok >> 3)*256 + d*8 + (tok & 7);
                        Wv_h[o] = hh; Wv_l[o] = ll;
                    }
                }
            }
        }
    }
}

// ------- split-bf16 MFMA GEMM fused with residual add + LayerNorm -------
// Block = 32 rows x 256 cols: wave w owns cols w*64..w*64+63 (1x2 frags of
// 32x32). x (FT hi/lo) is residual input AND LN output (in-place).
__global__ __launch_bounds__(256) void gemm_ln(
    const ushort* __restrict__ Ahi, const ushort* __restrict__ Alo,
    const ushort* __restrict__ Bhi, const ushort* __restrict__ Blo,
    const float* __restrict__ bias,
    ushort* __restrict__ xhi, ushort* __restrict__ xlo,
    const float* __restrict__ g, const float* __restrict__ be,
    int M, int K)
{
    const int N = HDIM;
    const int t = threadIdx.x;
    const int lane = t & 63, wave = t >> 6;
    const int lr = lane & 31, kg = lane >> 5;
    const int row_b = blockIdx.y * 32;
    const int col_w = wave * 64;
    const int KB = K >> 3;

    const ushort *pAh, *pAl, *pBh[2], *pBl[2];
    {
        size_t base = ((size_t)(row_b >> 5) * KB + kg) * 256 + lr * 8;
        pAh = Ahi + base; pAl = Alo + base;
    }
    #pragma unroll
    for (int nj = 0; nj < 2; ++nj) {
        size_t base = ((size_t)((col_w + nj*32) >> 5) * KB + kg) * 256 + lr * 8;
        pBh[nj] = Bhi + base; pBl[nj] = Blo + base;
    }

    f32x16 acc[2];
    #pragma unroll
    for (int j = 0; j < 2; ++j)
        #pragma unroll
        for (int r = 0; r < 16; ++r) acc[j][r] = 0.f;

    bf16x8 a0h, a0l, b0h[2], b0l[2];
    bf16x8 a1h, a1l, b1h[2], b1l[2];

#define LOADF(AH, AL, BH, BL, OFF) do {                                        \
    AH = *reinterpret_cast<const bf16x8*>(pAh + (OFF));                        \
    AL = *reinterpret_cast<const bf16x8*>(pAl + (OFF));                        \
    _Pragma("unroll") for (int nj = 0; nj < 2; ++nj) {                         \
        BH[nj] = *reinterpret_cast<const bf16x8*>(pBh[nj] + (OFF));            \
        BL[nj] = *reinterpret_cast<const bf16x8*>(pBl[nj] + (OFF)); } } while(0)

#define MFMAF(AH, AL, BH, BL) do {                                             \
    _Pragma("unroll") for (int nj = 0; nj < 2; ++nj) {                         \
        acc[nj] = __builtin_amdgcn_mfma_f32_32x32x16_bf16(                     \
            AH, BH[nj], acc[nj], 0, 0, 0);                                     \
        acc[nj] = __builtin_amdgcn_mfma_f32_32x32x16_bf16(                     \
            AH, BL[nj], acc[nj], 0, 0, 0);                                     \
        acc[nj] = __builtin_amdgcn_mfma_f32_32x32x16_bf16(                     \
            AL, BH[nj], acc[nj], 0, 0, 0); } } while(0)

    LOADF(a0h, a0l, b0h, b0l, 0);
    for (int k0 = 0; k0 < K; k0 += 32) {
        size_t o1 = (size_t)((k0 + 16) >> 3) * 256;
        LOADF(a1h, a1l, b1h, b1l, o1);
        MFMAF(a0h, a0l, b0h, b0l);
        size_t o2 = (k0 + 32 < K) ? (size_t)((k0 + 32) >> 3) * 256 : 0;
        LOADF(a0h, a0l, b0h, b0l, o2);
        MFMAF(a1h, a1l, b1h, b1l);
    }
#undef LOADF
#undef MFMAF

    // v = acc + bias + residual; per-row sum/sumsq (this lane: 2 cols/row)
    float s1[16], s2[16];
    #pragma unroll
    for (int nj = 0; nj < 2; ++nj) {
        int col = col_w + nj*32 + lr;
        float bv = bias[col];
        #pragma unroll
        for (int r = 0; r < 16; ++r) {
            int r31 = (r & 3) + 8*(r >> 2) + 4*kg;
            int row = row_b + r31;          // M%32==0 -> always < M
            size_t oo = ((size_t)(row >> 5) * (N >> 3) + (col >> 3)) * 256
                      + ((row & 31) << 3) + (col & 7);
            float v = acc[nj][r] + bv + b2f(xhi[oo]) + b2f(xlo[oo]);
            acc[nj][r] = v;
            if (nj == 0) { s1[r] = v;  s2[r] = v*v; }
            else         { s1[r] += v; s2[r] += v*v; }
        }
    }
    #pragma unroll
    for (int r = 0; r < 16; ++r) {
        #pragma unroll
        for (int off = 1; off <= 16; off <<= 1) {
            s1[r] += __shfl_xor(s1[r], off);
            s2[r] += __shfl_xor(s2[r], off);
        }
    }
    __shared__ float red1[4][32];
    __shared__ float red2[4][32];
    __shared__ float tot1[32];
    __shared__ float tot2[32];
    if (lr == 0) {
        #pragma unroll
        for (int r = 0; r < 16; ++r) {
            int rr = (r & 3) + 8*(r >> 2) + 4*kg;
            red1[wave][rr] = s1[r];
            red2[wave][rr] = s2[r];
        }
    }
    __syncthreads();
    if (t < 32) {
        tot1[t] = red1[0][t] + red1[1][t] + red1[2][t] + red1[3][t];
        tot2[t] = red2[0][t] + red2[1][t] + red2[2][t] + red2[3][t];
    }
    __syncthreads();
    #pragma unroll
    for (int r = 0; r < 16; ++r) {
        int r31 = (r & 3) + 8*(r >> 2) + 4*kg;
        int row = row_b + r31;
        float mu = tot1[r31] * (1.f/256.f);
        float var = fmaf(-mu, mu, tot2[r31] * (1.f/256.f));
        float rs = rsqrtf(var + 1e-5f);
        #pragma unroll
        for (int nj = 0; nj < 2; ++nj) {
            int col = col_w + nj*32 + lr;
            float o = g[col] * (acc[nj][r] - mu) * rs + be[col];
            size_t oo = ((size_t)(row >> 5) * (N >> 3) + (col >> 3)) * 256
                      + ((row & 31) << 3) + (col & 7);
            ushort hh = f2b_hi(o);
            xhi[oo] = hh;
            xlo[oo] = f2b_lo(o, hh);
        }
    }
}

// ------- MFMA attention, one-pass online softmax: 1 wave per (b,h,q-tile) -------
// Swapped QK^T (A=K, B=Q): lane's (m,l) are for q-col = lane&31; oacc rows are
// q = r31, so rescale factors are broadcast via shfl(f, r31).
__global__ __launch_bounds__(256) void attn_mfma(
    const ushort* __restrict__ Qh, const ushort* __restrict__ Ql,
    const ushort* __restrict__ Kh, const ushort* __restrict__ Kl,
    const ushort* __restrict__ Vh, const ushort* __restrict__ Vl,
    ushort* __restrict__ ahi, ushort* __restrict__ alo)
{
    const int bh = blockIdx.y;
    const int wave = threadIdx.x >> 6, lane = threadIdx.x & 63;
    const int qt = blockIdx.x * 4 + wave;   // 0..11
    const int lr = lane & 31, kg = lane >> 5;
    const size_t base = (size_t)bh * 12288;
    const float scale = 0.17677669529663687f; // 1/sqrt(32)

    bf16x8 qfh[2], qfl[2];
    #pragma unroll
    for (int ks = 0; ks < 2; ++ks) {
        size_t o = base + (size_t)(qt*4 + ks*2 + kg)*256 + lr*8;
        qfh[ks] = *reinterpret_cast<const bf16x8*>(Qh + o);
        qfl[ks] = *reinterpret_cast<const bf16x8*>(Ql + o);
    }

    float m = -3e38f, l = 0.f;
    f32x16 oacc;
    #pragma unroll
    for (int r = 0; r < 16; ++r) oacc[r] = 0.f;

    for (int kt = 0; kt < 12; ++kt) {
        f32x16 st;
        #pragma unroll
        for (int r = 0; r < 16; ++r) st[r] = 0.f;
        #pragma unroll
        for (int ks = 0; ks < 2; ++ks) {
            size_t o = base + (size_t)(kt*4 + ks*2 + kg)*256 + lr*8;
            bf16x8 kfh = *reinterpret_cast<const bf16x8*>(Kh + o);
            bf16x8 kfl = *reinterpret_cast<const bf16x8*>(Kl + o);
            st = __builtin_amdgcn_mfma_f32_32x32x16_bf16(kfh, qfh[ks], st, 0,0,0);
            st = __builtin_amdgcn_mfma_f32_32x32x16_bf16(kfh, qfl[ks], st, 0,0,0);
            st = __builtin_amdgcn_mfma_f32_32x32x16_bf16(kfl, qfh[ks], st, 0,0,0);
        }
        float p[16];
        float tm = -3e38f;
        #pragma unroll
        for (int r = 0; r < 16; ++r) {
            int krow = kt*32 + (r & 3) + 8*(r >> 2) + 4*kg;
            p[r] = (krow < T_SEQ) ? st[r] : -3e38f;
            tm = fmaxf(tm, p[r]);
        }
        tm = fmaxf(tm, __shfl_xor(tm, 32));       // combine kg halves per q
        float newm = fmaxf(m, tm);
        float f = __expf((m - newm) * scale);     // first tile: exp(-inf)=0
        m = newm;
        l *= f;
        float sumL = 0.f;
        #pragma unroll
        for (int r = 0; r < 16; ++r) {
            float e = __expf((p[r] - m) * scale); // masked rows -> exp(-inf)=0
            p[r] = e; sumL += e;
        }
        l += sumL;
        // rescale oacc: row q = r31 needs f of lane q (same in both halves)
        #pragma unroll
        for (int r = 0; r < 16; ++r) {
            int r31 = (r & 3) + 8*(r >> 2) + 4*kg;
            float fr = __shfl(f, r31);
            oacc[r] *= fr;
        }
        float pp[16];
        #pragma unroll
        for (int r = 0; r < 16; ++r) pp[r] = __shfl_xor(p[r], 32);
        #pragma unroll
        for (int ks = 0; ks < 2; ++ks) {
            union { u16x8 u; bf16x8 b; } fh, fl;
            #pragma unroll
            for (int j = 0; j < 8; ++j) {
                float e;
                if (ks == 0)
                    e = kg ? ((j < 4) ? pp[4+j] : p[j])
                           : ((j < 4) ? p[j]    : pp[j-4]);
                else
                    e = kg ? ((j < 4) ? pp[12+j] : p[8+j])
                           : ((j < 4) ? p[8+j]   : pp[4+j]);
                ushort hh = f2b_hi(e);
                fh.u[j] = hh;
                fl.u[j] = f2b_lo(e, hh);
            }
            size_t vo = base + (size_t)(kt*4 + ks*2 + kg)*256 + lr*8;
            bf16x8 vfh = *reinterpret_cast<const bf16x8*>(Vh + vo);
            bf16x8 vfl = *reinterpret_cast<const bf16x8*>(Vl + vo);
            oacc = __builtin_amdgcn_mfma_f32_32x32x16_bf16(fh.b, vfh, oacc, 0,0,0);
            oacc = __builtin_amdgcn_mfma_f32_32x32x16_bf16(fh.b, vfl, oacc, 0,0,0);
            oacc = __builtin_amdgcn_mfma_f32_32x32x16_bf16(fl.b, vfh, oacc, 0,0,0);
        }
    }
    l += __shfl_xor(l, 32);
    float il = 1.f / l;

    const int bl = bh >> 3, h = bh & 7;
    #pragma unroll
    for (int r = 0; r < 16; ++r) {
        int q = (r & 3) + 8*(r >> 2) + 4*kg;
        float sc = __shfl(il, q);
        int row_local = qt*32 + q;
        if (row_local < T_SEQ) {
            float v = oacc[r] * sc;
            int grow = bl*T_SEQ + row_local;
            int col = h*32 + lr;
            size_t o = ((size_t)(grow >> 5)*32 + (col >> 3))*256
                     + ((grow & 31) << 3) + (col & 7);
            ushort hh = f2b_hi(v);
            ahi[o] = hh;
            alo[o] = f2b_lo(v, hh);
        }
    }
}

// -------- per-chunk mean-pool over t (chunk-local x -> global pooled) --------
__global__ __launch_bounds__(256) void pool_kernel(
    const ushort* __restrict__ xhi, const ushort* __restrict__ xlo,
    float* __restrict__ pooled)
{
    int b = blockIdx.x, t = threadIdx.x;
    float acc = 0.f;
    for (int tt = 0; tt < T_SEQ; ++tt) {
        size_t row = (size_t)b*T_SEQ + tt;
        size_t o = ((row >> 5) * 32 + (t >> 3)) * 256 + ((row & 31) << 3) + (t & 7);
        acc += b2f(xhi[o]) + b2f(xlo[o]);
    }
    pooled[(size_t)b*HDIM + t] = acc * (1.f/365.f);
}

// -------- output head (reads pooled + sfeat) --------
__global__ __launch_bounds__(256) void head_kernel(
    const float* __restrict__ pooled, const float* __restrict__ sfeat,
    const float* __restrict__ W1, const float* __restrict__ b1,
    const float* __restrict__ W2, const float* __restrict__ b2,
    const float* __restrict__ scale, const float* __restrict__ shift,
    float* __restrict__ out)
{
    __shared__ float p[HDIM];
    __shared__ float h1[HDIM/2];
    int b = blockIdx.x, t = threadIdx.x;
    p[t] = pooled[(size_t)b*HDIM + t] + sfeat[(size_t)b*HDIM + t];
    __syncthreads();
    if (t < HDIM/2) {
        float a = b1[t];
        for (int c = 0; c < HDIM; ++c) a = fmaf(p[c], W1[c*(HDIM/2) + t], a);
        h1[t] = gelu_f(a);
    }
    __syncthreads();
    if (t < 30) {
        float a = b2[t];
        for (int j = 0; j < HDIM/2; ++j) a = fmaf(h1[j], W2[j*30 + t], a);
        out[b*30 + t] = tanhf(a) * scale[0] + shift[0];
    }
}

extern "C" void kernel_launch(void* const* d_in, const int* in_sizes, int n_in,
                              void* d_out, int out_size, void* d_ws, size_t ws_size,
                              hipStream_t stream) {
    const float* p_static = (const float*)d_in[0];
    const float* p_dyn    = (const float*)d_in[1];
    const float* p_lat    = (const float*)d_in[2];
    const float* p_lon    = (const float*)d_in[3];
    const float* p_all    = (const float*)d_in[4];
    const float* p_coords = (const float*)d_in[5];
    const float* p_Wst    = (const float*)d_in[6];
    const float* p_bst    = (const float*)d_in[7];
    const float* p_gst    = (const float*)d_in[8];
    const float* p_best   = (const float*)d_in[9];
    const float* p_Wdy    = (const float*)d_in[10];
    const float* p_bdy    = (const float*)d_in[11];
    const float* p_gdy    = (const float*)d_in[12];
    const float* p_bedy   = (const float*)d_in[13];
    const float* p_Wqkv   = (const float*)d_in[14];
    const float* p_bqkv   = (const float*)d_in[15];
    const float* p_Wo     = (const float*)d_in[16];
    const float* p_bo     = (const float*)d_in[17];
    const float* p_gln1   = (const float*)d_in[18];
    const float* p_beln1  = (const float*)d_in[19];
    const float* p_Wf1    = (const float*)d_in[20];
    const float* p_bf1    = (const float*)d_in[21];
    const float* p_Wf2    = (const float*)d_in[22];
    const float* p_bf2    = (const float*)d_in[23];
    const float* p_gln2   = (const float*)d_in[24];
    const float* p_beln2  = (const float*)d_in[25];
    const float* p_Wo1    = (const float*)d_in[26];
    const float* p_bo1    = (const float*)d_in[27];
    const float* p_Wo2    = (const float*)d_in[28];
    const float* p_bo2    = (const float*)d_in[29];
    const float* p_scale  = (const float*)d_in[30];
    const float* p_shift  = (const float*)d_in[31];
    float* out = (float*)d_out;
    (void)in_sizes; (void)n_in; (void)out_size;

    char* ws = (char*)d_ws;
    size_t off = 0;
    auto alloc = [&](size_t bytes) -> void* {
        void* p = ws + off;
        off += (bytes + 255) & ~(size_t)255;
        return p;
    };
    int*    nbr    = (int*)   alloc((size_t)BATCH*KNB*sizeof(int));
    float*  sfeat  = (float*) alloc((size_t)BATCH*HDIM*sizeof(float));
    float*  pooled = (float*) alloc((size_t)BATCH*HDIM*sizeof(float));
    const size_t SZ_QKV = (size_t)4*768*256, SZ_O = (size_t)4*256*256;
    const size_t SZ_F1  = (size_t)4*1024*256, SZ_F2 = (size_t)4*256*1024;
    ushort* Wqkvt_h = (ushort*)alloc(SZ_QKV*2*sizeof(ushort)); ushort* Wqkvt_l = Wqkvt_h + SZ_QKV;
    ushort* Wot_h   = (ushort*)alloc(SZ_O  *2*sizeof(ushort)); ushort* Wot_l   = Wot_h   + SZ_O;
    ushort* Wf1t_h  = (ushort*)alloc(SZ_F1 *2*sizeof(ushort)); ushort* Wf1t_l  = Wf1t_h  + SZ_F1;
    ushort* Wf2t_h  = (ushort*)alloc(SZ_F2 *2*sizeof(ushort)); ushort* Wf2t_l  = Wf2t_h  + SZ_F2;
    size_t fixed = off;

    // per-chunk: x hi/lo (CH*365*256*2*2B = 373,760 B) + union region:
    //   attn phase: QKV-split 6*(CH*8*12288)*2B = CH*1,179,648 B
    //               + aatt hi/lo CH*373,760 B          = CH*1,553,408 B
    //   FF phase:   hbuf hi/lo CH*365*1024*2*2B        = CH*1,495,040 B  (fits)
    const size_t X_CH   = (size_t)T_SEQ * HDIM * 4;     // 373,760
    const size_t REG_CH = (size_t)1553408;
    const size_t PER_CH = X_CH + REG_CH;                // 1,927,168
    int CH = 32;
    {
        const int tiers[3] = {256, 128, 64};
        for (int i = 0; i < 3; ++i) {
            if (fixed + (size_t)tiers[i]*PER_CH + 8192 <= ws_size) { CH = tiers[i]; break; }
        }
    }
    const int RW = CH * T_SEQ;
    ushort* xh  = (ushort*)alloc((size_t)CH * X_CH);
    ushort* xl  = xh + (size_t)RW * HDIM;
    char*   big = (char*)alloc((size_t)CH * REG_CH);
    const size_t seg = (size_t)CH * 8 * 12288;          // ushorts per QKV buffer
    ushort* Qh  = (ushort*)big;
    ushort* Ql  = Qh  + seg;
    ushort* Kh2 = Ql  + seg;
    ushort* Kl2 = Kh2 + seg;
    ushort* Vth = Kl2 + seg;
    ushort* Vtl = Vth + seg;
    ushort* aatt_h = Vtl + seg;
    ushort* aatt_l = aatt_h + (size_t)RW * HDIM;
    ushort* hbuf_h = (ushort*)big;                      // overlaps dead QKV region
    ushort* hbuf_l = hbuf_h + (size_t)RW * FFDIM;
    const int GY  = (RW + 127) / 128;   // 128-row tiles (guarded)
    const int GY3 = RW / 32;            // 32-row tiles (exact: RW%32==0)

    topk_kernel <<<BATCH, 256, 0, stream>>>(p_lat, p_lon, p_coords, nbr);
    sfeat_kernel<<<BATCH, 256, 0, stream>>>(p_static, p_all, nbr, p_Wst, p_bst, p_gst, p_best, sfeat);
    tsplit_kernel<<<dim3(24, 8, 4), 256, 0, stream>>>(p_Wqkv, Wqkvt_h, Wqkvt_l, 256, 768);
    tsplit_kernel<<<dim3( 8, 8, 4), 256, 0, stream>>>(p_Wo,   Wot_h,   Wot_l,   256, 256);
    tsplit_kernel<<<dim3(32, 8, 4), 256, 0, stream>>>(p_Wf1,  Wf1t_h,  Wf1t_l,  256, 1024);
    tsplit_kernel<<<dim3( 8,32, 4), 256, 0, stream>>>(p_Wf2,  Wf2t_h,  Wf2t_l,  1024, 256);

    const int NCHUNK = BATCH / CH;
    for (int c = 0; c < NCHUNK; ++c) {
        dyn_kernel<<<RW/4, 256, 0, stream>>>(
            p_dyn + (size_t)c*CH*T_SEQ*DDIM, p_Wdy, p_bdy, p_gdy, p_bedy,
            sfeat + (size_t)c*CH*HDIM, xh, xl);
        for (int l = 0; l < 4; ++l) {
            gemm_mfma<0,2><<<dim3(6, GY), 256, 0, stream>>>(
                xh, xl, Wqkvt_h + (size_t)l*768*256, Wqkvt_l + (size_t)l*768*256,
                p_bqkv + l*768, nullptr, nullptr,
                Qh, Ql, Kh2, Kl2, Vth, Vtl, RW, 768, 256);
            attn_mfma<<<dim3(3, CH*8), 256, 0, stream>>>(
                Qh, Ql, Kh2, Kl2, Vth, Vtl, aatt_h, aatt_l);
            gemm_ln<<<dim3(1, GY3), 256, 0, stream>>>(
                aatt_h, aatt_l, Wot_h + (size_t)l*256*256, Wot_l + (size_t)l*256*256,
                p_bo + l*256, xh, xl, p_gln1 + l*256, p_beln1 + l*256, RW, 256);
            gemm_mfma<1,1><<<dim3(8, GY), 256, 0, stream>>>(
                xh, xl, Wf1t_h + (size_t)l*1024*256, Wf1t_l + (size_t)l*1024*256,
                p_bf1 + l*1024, hbuf_h, hbuf_l,
                nullptr, nullptr, nullptr, nullptr, nullptr, nullptr, RW, 1024, 256);
            gemm_ln<<<dim3(1, GY3), 256, 0, stream>>>(
                hbuf_h, hbuf_l, Wf2t_h + (size_t)l*256*1024, Wf2t_l + (size_t)l*256*1024,
                p_bf2 + l*256, xh, xl, p_gln2 + l*256, p_beln2 + l*256, RW, 1024);
        }
        pool_kernel<<<CH, 256, 0, stream>>>(xh, xl, pooled + (size_t)c*CH*HDIM);
    }
    head_kernel<<<BATCH, 256, 0, stream>>>(pooled, sfeat, p_Wo1, p_bo1, p_Wo2, p_bo2, p_scale, p_shift, out);
}